// Round 1
// baseline (2545.952 us; speedup 1.0000x reference)
//
#include <hip/hip_runtime.h>
#include <math.h>

#define HH 64
#define WW 256
#define NPIX (HH*WW)
#define BB 4

// ---------------- Stage 1: cross-frame attentive cost volume ----------------
// one block (128 threads) per (b,n) pixel
__global__ __launch_bounds__(128)
void stage1_kernel(const float* __restrict__ xyz1,   // [B,N,3]
                   const float* __restrict__ xyz2,   // [B,N,3]
                   const float* __restrict__ pts1,   // [B,N,64]
                   const float* __restrict__ pts2,   // [B,N,64]
                   const float* __restrict__ w0, const float* __restrict__ b0,   // 138x128
                   const float* __restrict__ w1, const float* __restrict__ b1,   // 128x64
                   const float* __restrict__ w2, const float* __restrict__ b2,   // 64x64
                   const float* __restrict__ pw, const float* __restrict__ pb,   // 10x64
                   const float* __restrict__ q0w, const float* __restrict__ q0b, // 128x128
                   const float* __restrict__ q1w, const float* __restrict__ q1b, // 128x64
                   float* __restrict__ feat1_new)    // [B,N,64]
{
    const int bn = blockIdx.x;
    const int b  = bn >> 14;        // / 16384
    const int n  = bn & 16383;
    const int h  = n >> 8;          // / 256
    const int w  = n & 255;
    const int t  = threadIdx.x;

    __shared__ float s_d2[75];
    __shared__ int   s_flat[75];
    __shared__ int   s_valid[75];
    __shared__ int   s_selFlat[6];
    __shared__ float s_selMask[6];
    __shared__ float s_in[6][144];     // 138-ch input (padded); later reused for a1[128]
    __shared__ float s_h1[6][128];     // h1; later reused for cat2
    __shared__ float s_h2[6][64];
    __shared__ float s_feat[6][64];
    __shared__ float s_enc[6][64];
    __shared__ float s_att[6][64];

    const float qx = xyz1[(size_t)bn*3+0];
    const float qy = xyz1[(size_t)bn*3+1];
    const float qz = xyz1[(size_t)bn*3+2];

    // ---- candidate distances (5x15 window) ----
    if (t < 75) {
        int dh = t / 15 - 2;
        int dw = t % 15 - 7;
        int ch = h + dh, cw = w + dw;
        bool inb = ((unsigned)ch < HH) && ((unsigned)cw < WW);
        int cch = min(max(ch, 0), HH-1);
        int ccw = min(max(cw, 0), WW-1);
        int flat = cch*WW + ccw;
        float d2 = 3.0e38f; int val = 0;
        if (inb) {
            const float* p = xyz2 + (size_t)(b*NPIX + flat)*3;
            float dx = p[0]-qx, dy = p[1]-qy, dz = p[2]-qz;
            d2 = dx*dx + dy*dy + dz*dz;
            val = (d2 < 100.0f) ? 1 : 0;
        }
        s_d2[t] = d2; s_flat[t] = flat; s_valid[t] = val;
    }
    __syncthreads();

    // ---- top-6 selection (matches lax.top_k semantics: valid asc by (d2,idx), then invalid asc idx) ----
    if (t == 0) {
        unsigned long long used0 = 0, used1 = 0;
        for (int j = 0; j < 6; ++j) {
            float best = INFINITY; int bi = 0;
            for (int c = 0; c < 75; ++c) {
                bool u = (c < 64) ? ((used0 >> c) & 1ull) : ((used1 >> (c-64)) & 1ull);
                if (u) continue;
                float v = s_valid[c] ? s_d2[c] : 3.0e38f;
                if (v < best) { best = v; bi = c; }
            }
            if (bi < 64) used0 |= 1ull << bi; else used1 |= 1ull << (bi-64);
            s_selFlat[j] = s_valid[bi] ? s_flat[bi] : 0;
            s_selMask[j] = s_valid[bi] ? 1.0f : 0.0f;
        }
    }
    __syncthreads();

    // ---- build 138-ch input features ----
    if (t < 6) {
        float m = s_selMask[t];
        const float* p = xyz2 + (size_t)(b*NPIX + s_selFlat[t])*3;
        float ax = p[0]*m, ay = p[1]*m, az = p[2]*m;
        float dx = ax-qx, dy = ay-qy, dz = az-qz;
        float e = sqrtf(dx*dx + dy*dy + dz*dz + 1e-20f);
        s_in[t][0]=qx; s_in[t][1]=qy; s_in[t][2]=qz;
        s_in[t][3]=ax; s_in[t][4]=ay; s_in[t][5]=az;
        s_in[t][6]=dx; s_in[t][7]=dy; s_in[t][8]=dz;
        s_in[t][9]=e;
        s_in[t][138]=0.f; s_in[t][139]=0.f; s_in[t][140]=0.f;
        s_in[t][141]=0.f; s_in[t][142]=0.f; s_in[t][143]=0.f;
    }
    if (t < 64) {
        float p1v = pts1[(size_t)bn*64 + t];
        #pragma unroll
        for (int k = 0; k < 6; ++k) {
            s_in[k][10+t] = p1v;
            s_in[k][74+t] = pts2[(size_t)(b*NPIX + s_selFlat[k])*64 + t] * s_selMask[k];
        }
    }
    __syncthreads();

    // ---- conv1: 138 -> 128, relu ----
    {
        float acc[6];
        float bias = b0[t];
        #pragma unroll
        for (int k = 0; k < 6; ++k) acc[k] = bias;
        for (int c = 0; c < 138; ++c) {
            float wv = w0[c*128 + t];
            #pragma unroll
            for (int k = 0; k < 6; ++k) acc[k] += s_in[k][c] * wv;
        }
        #pragma unroll
        for (int k = 0; k < 6; ++k) s_h1[k][t] = fmaxf(acc[k], 0.0f);
    }
    __syncthreads();

    // ---- conv2: 128 -> 64 relu, and pienc: 10 -> 64 relu ----
    if (t < 64) {
        float acc[6], ae[6];
        float bias = b1[t], be = pb[t];
        #pragma unroll
        for (int k = 0; k < 6; ++k) { acc[k] = bias; ae[k] = be; }
        for (int c = 0; c < 128; ++c) {
            float wv = w1[c*64 + t];
            #pragma unroll
            for (int k = 0; k < 6; ++k) acc[k] += s_h1[k][c] * wv;
        }
        for (int c = 0; c < 10; ++c) {
            float wv = pw[c*64 + t];
            #pragma unroll
            for (int k = 0; k < 6; ++k) ae[k] += s_in[k][c] * wv;
        }
        #pragma unroll
        for (int k = 0; k < 6; ++k) {
            s_h2[k][t]  = fmaxf(acc[k], 0.0f);
            s_enc[k][t] = fmaxf(ae[k], 0.0f);
        }
    }
    __syncthreads();

    // ---- conv3: 64 -> 64 relu -> feat ----
    if (t < 64) {
        float acc[6];
        float bias = b2[t];
        #pragma unroll
        for (int k = 0; k < 6; ++k) acc[k] = bias;
        for (int c = 0; c < 64; ++c) {
            float wv = w2[c*64 + t];
            #pragma unroll
            for (int k = 0; k < 6; ++k) acc[k] += s_h2[k][c] * wv;
        }
        #pragma unroll
        for (int k = 0; k < 6; ++k) s_feat[k][t] = fmaxf(acc[k], 0.0f);
    }
    __syncthreads();

    // ---- cat2 = [enc, feat] into s_h1 ----
    {
        #pragma unroll
        for (int k = 0; k < 6; ++k)
            s_h1[k][t] = (t < 64) ? s_enc[k][t] : s_feat[k][t-64];
    }
    __syncthreads();

    // ---- m2 conv1: 128 -> 128 relu -> a1 (into s_in) ----
    {
        float acc[6];
        float bias = q0b[t];
        #pragma unroll
        for (int k = 0; k < 6; ++k) acc[k] = bias;
        for (int c = 0; c < 128; ++c) {
            float wv = q0w[c*128 + t];
            #pragma unroll
            for (int k = 0; k < 6; ++k) acc[k] += s_h1[k][c] * wv;
        }
        #pragma unroll
        for (int k = 0; k < 6; ++k) s_in[k][t] = fmaxf(acc[k], 0.0f);
    }
    __syncthreads();

    // ---- m2 conv2: 128 -> 64 relu -> att ----
    if (t < 64) {
        float acc[6];
        float bias = q1b[t];
        #pragma unroll
        for (int k = 0; k < 6; ++k) acc[k] = bias;
        for (int c = 0; c < 128; ++c) {
            float wv = q1w[c*64 + t];
            #pragma unroll
            for (int k = 0; k < 6; ++k) acc[k] += s_in[k][c] * wv;
        }
        #pragma unroll
        for (int k = 0; k < 6; ++k) s_att[k][t] = fmaxf(acc[k], 0.0f);
    }
    __syncthreads();

    // ---- masked softmax over K=6 + weighted sum ----
    if (t < 64) {
        float v[6];
        #pragma unroll
        for (int k = 0; k < 6; ++k)
            v[k] = (s_selMask[k] > 0.5f) ? s_att[k][t] : -1e10f;
        float m = v[0];
        #pragma unroll
        for (int k = 1; k < 6; ++k) m = fmaxf(m, v[k]);
        float s = 0.0f, o = 0.0f;
        #pragma unroll
        for (int k = 0; k < 6; ++k) {
            float e = expf(v[k] - m);
            s += e;
            o += e * s_feat[k][t];
        }
        feat1_new[(size_t)bn*64 + t] = o / s;
    }
}

// ---------------- Stage 2: self-aggregation over frame-1 neighbors ----------------
__global__ __launch_bounds__(128)
void stage2_kernel(const float* __restrict__ xyz1,   // [B,N,3]
                   const float* __restrict__ pts1,   // [B,N,64]
                   const float* __restrict__ f1,     // [B,N,64]  (pi_feat1_new)
                   const float* __restrict__ pcw, const float* __restrict__ pcb, // 10x64
                   const float* __restrict__ n0w, const float* __restrict__ n0b, // 192x128
                   const float* __restrict__ n1w, const float* __restrict__ n1b, // 128x64
                   float* __restrict__ out)          // [B,N,64]
{
    const int bn = blockIdx.x;
    const int b  = bn >> 14;
    const int n  = bn & 16383;
    const int h  = n >> 8;
    const int w  = n & 255;
    const int t  = threadIdx.x;

    __shared__ float s_d2[9];
    __shared__ int   s_flat[9];
    __shared__ int   s_valid[9];
    __shared__ int   s_selFlat[4];
    __shared__ float s_selMask[4];
    __shared__ float s_x[4][12];       // xyz_cat2 (10 ch)
    __shared__ float s_cat[4][192];
    __shared__ float s_a1[4][128];
    __shared__ float s_att[4][64];
    __shared__ float s_g[4][64];

    const float qx = xyz1[(size_t)bn*3+0];
    const float qy = xyz1[(size_t)bn*3+1];
    const float qz = xyz1[(size_t)bn*3+2];

    if (t < 9) {
        int dh = t / 3 - 1;
        int dw = t % 3 - 1;
        int ch = h + dh, cw = w + dw;
        bool inb = ((unsigned)ch < HH) && ((unsigned)cw < WW);
        int cch = min(max(ch, 0), HH-1);
        int ccw = min(max(cw, 0), WW-1);
        int flat = cch*WW + ccw;
        float d2 = 3.0e38f; int val = 0;
        if (inb) {
            const float* p = xyz1 + (size_t)(b*NPIX + flat)*3;
            float dx = p[0]-qx, dy = p[1]-qy, dz = p[2]-qz;
            d2 = dx*dx + dy*dy + dz*dz;
            val = (d2 < 10.0f) ? 1 : 0;
        }
        s_d2[t] = d2; s_flat[t] = flat; s_valid[t] = val;
    }
    __syncthreads();

    if (t == 0) {
        unsigned used = 0;
        for (int j = 0; j < 4; ++j) {
            float best = INFINITY; int bi = 0;
            for (int c = 0; c < 9; ++c) {
                if ((used >> c) & 1u) continue;
                float v = s_valid[c] ? s_d2[c] : 3.0e38f;
                if (v < best) { best = v; bi = c; }
            }
            used |= 1u << bi;
            s_selFlat[j] = s_valid[bi] ? s_flat[bi] : 0;
            s_selMask[j] = s_valid[bi] ? 1.0f : 0.0f;
        }
    }
    __syncthreads();

    if (t < 4) {
        float m = s_selMask[t];
        const float* p = xyz1 + (size_t)(b*NPIX + s_selFlat[t])*3;
        float ax = p[0]*m, ay = p[1]*m, az = p[2]*m;
        float dx = ax-qx, dy = ay-qy, dz = az-qz;
        float e = sqrtf(dx*dx + dy*dy + dz*dz + 1e-20f);
        s_x[t][0]=qx; s_x[t][1]=qy; s_x[t][2]=qz;
        s_x[t][3]=ax; s_x[t][4]=ay; s_x[t][5]=az;
        s_x[t][6]=dx; s_x[t][7]=dy; s_x[t][8]=dz;
        s_x[t][9]=e;
    }
    __syncthreads();

    // ---- pcenc: 10 -> 64 relu, then build masked 192-ch cat ----
    if (t < 64) {
        float ae[4];
        float be = pcb[t];
        #pragma unroll
        for (int k = 0; k < 4; ++k) ae[k] = be;
        for (int c = 0; c < 10; ++c) {
            float wv = pcw[c*64 + t];
            #pragma unroll
            for (int k = 0; k < 4; ++k) ae[k] += s_x[k][c] * wv;
        }
        float p1v = pts1[(size_t)bn*64 + t];
        #pragma unroll
        for (int k = 0; k < 4; ++k) {
            float mk = s_selMask[k];
            s_cat[k][t]      = fmaxf(ae[k], 0.0f) * mk;
            s_cat[k][64+t]   = p1v * mk;
            float g = f1[(size_t)(b*NPIX + s_selFlat[k])*64 + t] * mk;
            s_cat[k][128+t]  = g;
            s_g[k][t]        = g;
        }
    }
    __syncthreads();

    // ---- m2n conv1: 192 -> 128 relu ----
    {
        float acc[4];
        float bias = n0b[t];
        #pragma unroll
        for (int k = 0; k < 4; ++k) acc[k] = bias;
        for (int c = 0; c < 192; ++c) {
            float wv = n0w[c*128 + t];
            #pragma unroll
            for (int k = 0; k < 4; ++k) acc[k] += s_cat[k][c] * wv;
        }
        #pragma unroll
        for (int k = 0; k < 4; ++k) s_a1[k][t] = fmaxf(acc[k], 0.0f);
    }
    __syncthreads();

    // ---- m2n conv2: 128 -> 64 relu ----
    if (t < 64) {
        float acc[4];
        float bias = n1b[t];
        #pragma unroll
        for (int k = 0; k < 4; ++k) acc[k] = bias;
        for (int c = 0; c < 128; ++c) {
            float wv = n1w[c*64 + t];
            #pragma unroll
            for (int k = 0; k < 4; ++k) acc[k] += s_a1[k][c] * wv;
        }
        #pragma unroll
        for (int k = 0; k < 4; ++k) s_att[k][t] = fmaxf(acc[k], 0.0f);
    }
    __syncthreads();

    // ---- masked softmax over K=4 + weighted sum ----
    if (t < 64) {
        float v[4];
        #pragma unroll
        for (int k = 0; k < 4; ++k)
            v[k] = (s_selMask[k] > 0.5f) ? s_att[k][t] : -1e10f;
        float m = v[0];
        #pragma unroll
        for (int k = 1; k < 4; ++k) m = fmaxf(m, v[k]);
        float s = 0.0f, o = 0.0f;
        #pragma unroll
        for (int k = 0; k < 4; ++k) {
            float e = expf(v[k] - m);
            s += e;
            o += e * s_g[k][t];
        }
        out[(size_t)bn*64 + t] = o / s;
    }
}

extern "C" void kernel_launch(void* const* d_in, const int* in_sizes, int n_in,
                              void* d_out, int out_size, void* d_ws, size_t ws_size,
                              hipStream_t stream) {
    const float* xyz1 = (const float*)d_in[0];
    const float* xyz2 = (const float*)d_in[1];
    const float* pts1 = (const float*)d_in[2];
    const float* pts2 = (const float*)d_in[3];
    const float* m1w0 = (const float*)d_in[4];
    const float* m1b0 = (const float*)d_in[5];
    const float* m1w1 = (const float*)d_in[6];
    const float* m1b1 = (const float*)d_in[7];
    const float* m1w2 = (const float*)d_in[8];
    const float* m1b2 = (const float*)d_in[9];
    const float* piw  = (const float*)d_in[10];
    const float* pib  = (const float*)d_in[11];
    const float* m2w0 = (const float*)d_in[12];
    const float* m2b0 = (const float*)d_in[13];
    const float* m2w1 = (const float*)d_in[14];
    const float* m2b1 = (const float*)d_in[15];
    const float* pcw  = (const float*)d_in[16];
    const float* pcb  = (const float*)d_in[17];
    const float* n0w  = (const float*)d_in[18];
    const float* n0b  = (const float*)d_in[19];
    const float* n1w  = (const float*)d_in[20];
    const float* n1b  = (const float*)d_in[21];

    float* f1  = (float*)d_ws;           // [B,N,64] intermediate
    float* out = (float*)d_out;

    dim3 grid(BB * NPIX);
    dim3 block(128);

    hipLaunchKernelGGL(stage1_kernel, grid, block, 0, stream,
                       xyz1, xyz2, pts1, pts2,
                       m1w0, m1b0, m1w1, m1b1, m1w2, m1b2,
                       piw, pib, m2w0, m2b0, m2w1, m2b1,
                       f1);
    hipLaunchKernelGGL(stage2_kernel, grid, block, 0, stream,
                       xyz1, pts1, f1,
                       pcw, pcb, n0w, n0b, n1w, n1b,
                       out);
}

// Round 2
// 1403.577 us; speedup vs baseline: 1.8139x; 1.8139x over previous
//
#include <hip/hip_runtime.h>
#include <math.h>

#define HH 64
#define WW 256
#define NPIX (HH*WW)

#define RELU(x) fmaxf((x), 0.0f)

// 64-lane min-reduce of a packed u64 key via xor shuffles
__device__ __forceinline__ unsigned long long wave_min64(unsigned long long m){
  #pragma unroll
  for (int off = 1; off < 64; off <<= 1){
    unsigned lo = __shfl_xor((unsigned)m, off, 64);
    unsigned hi = __shfl_xor((unsigned)(m >> 32), off, 64);
    unsigned long long o = ((unsigned long long)hi << 32) | lo;
    if (o < m) m = o;
  }
  return m;
}

// store one element into a dual-plane [R][4]+[R][2] c-major LDS tile
template<int R>
__device__ __forceinline__ void st_e(float* S, int off4, int off2, int p, int c, int k, float v){
  if (k < 4) S[off4 + ((p*R + c)<<2) + k]       = v;
  else       S[off2 + ((p*R + c)<<1) + (k - 4)] = v;
}

// ---------------- stage 1 LDS layout (float offsets) ----------------
#define S1_A4  0       // act  [2][144][4]   (aliased later by a1 rows 0..127)
#define S1_A2  1152    // act  [2][144][2]
#define S1_H14 1728    // h1   [2][128][4]
#define S1_H12 2752    // h1   [2][128][2]
#define S1_H24 3264    // h2   [2][64][4]    (aliased later by att)
#define S1_H22 3776    // h2   [2][64][2]
#define S1_C4  4032    // cat  [2][128][4]   (enc rows 0..63, feat rows 64..127)
#define S1_C2  5056    // cat  [2][128][2]
#define S1_TOT 5568

__global__ __launch_bounds__(128)
void stage1_kernel(const float* __restrict__ xyz1, const float* __restrict__ xyz2,
                   const float* __restrict__ pts1, const float* __restrict__ pts2,
                   const float* __restrict__ w0, const float* __restrict__ b0,   // 138x128
                   const float* __restrict__ w1, const float* __restrict__ b1,   // 128x64
                   const float* __restrict__ w2, const float* __restrict__ b2,   // 64x64
                   const float* __restrict__ pw, const float* __restrict__ pb,   // 10x64
                   const float* __restrict__ q0w, const float* __restrict__ q0b, // 128x128
                   const float* __restrict__ q1w, const float* __restrict__ q1b, // 128x64
                   float* __restrict__ f1out)
{
  __shared__ __align__(16) float S[S1_TOT];
  __shared__ int   selFlat[2][6];
  __shared__ float selMask[2][6];

  const int t  = threadIdx.x;
  const int wv = t >> 6;        // wave id (0,1)
  const int l  = t & 63;        // lane
  const int pC = l >> 5;        // compute-pixel (lane half)
  const int oB = l & 31;
  const int bn0 = blockIdx.x << 1;

  // ---------- selection: wave wv owns pixel bn0+wv ----------
  const int bnS = bn0 + wv;
  const int bS = bnS >> 14, nS = bnS & 16383, hS = nS >> 8, wS = nS & 255;
  const float qSx = xyz1[bnS*3+0], qSy = xyz1[bnS*3+1], qSz = xyz1[bnS*3+2];

  unsigned long long key[2];
  #pragma unroll
  for (int i = 0; i < 2; ++i){
    int c = l + (i << 6);
    unsigned long long kk = ~0ull;
    if (c < 75){
      int dh = c/15 - 2, dw = c%15 - 7;
      int ch = hS + dh, cw = wS + dw;
      bool inb = ((unsigned)ch < HH) && ((unsigned)cw < WW);
      unsigned hi = 0x7f800000u;                 // +inf bits: invalid sorts after all valid
      if (inb){
        int fl = ch*WW + cw;
        const float* p = xyz2 + ((size_t)bS*NPIX + fl)*3;
        float dx = p[0]-qSx, dy = p[1]-qSy, dz = p[2]-qSz;
        float d2 = dx*dx + dy*dy + dz*dz;
        if (d2 < 100.0f) hi = __float_as_uint(d2);
      }
      kk = ((unsigned long long)hi << 32) | (unsigned)c;
    }
    key[i] = kk;
  }
  for (int j = 0; j < 6; ++j){
    unsigned long long m = key[0] < key[1] ? key[0] : key[1];
    m = wave_min64(m);
    if (l == 0){
      int c = (int)(m & 0xffffffffull);
      bool val = (unsigned)(m >> 32) < 0x7f800000u;
      int dh = c/15 - 2, dw = c%15 - 7;
      int cch = min(max(hS+dh, 0), HH-1), ccw = min(max(wS+dw, 0), WW-1);
      selFlat[wv][j] = val ? (cch*WW + ccw) : 0;
      selMask[wv][j] = val ? 1.0f : 0.0f;
    }
    if (key[0] == m) key[0] = ~0ull;
    if (key[1] == m) key[1] = ~0ull;
  }
  __syncthreads();

  // ---------- build 138-ch inputs (c-major dual-plane) ----------
  const int bnC = bn0 + pC;
  const int bC  = bnC >> 14;
  if (l < 6){                       // xyz rows 0..9 for pixel wv, neighbor k=l
    int k = l;
    float mk = selMask[wv][k];
    const float* p = xyz2 + ((size_t)bS*NPIX + selFlat[wv][k])*3;
    float ax = p[0]*mk, ay = p[1]*mk, az = p[2]*mk;
    float dx = ax - qSx, dy = ay - qSy, dz = az - qSz;
    float e = sqrtf(dx*dx + dy*dy + dz*dz + 1e-20f);
    st_e<144>(S, S1_A4, S1_A2, wv, 0, k, qSx);
    st_e<144>(S, S1_A4, S1_A2, wv, 1, k, qSy);
    st_e<144>(S, S1_A4, S1_A2, wv, 2, k, qSz);
    st_e<144>(S, S1_A4, S1_A2, wv, 3, k, ax);
    st_e<144>(S, S1_A4, S1_A2, wv, 4, k, ay);
    st_e<144>(S, S1_A4, S1_A2, wv, 5, k, az);
    st_e<144>(S, S1_A4, S1_A2, wv, 6, k, dx);
    st_e<144>(S, S1_A4, S1_A2, wv, 7, k, dy);
    st_e<144>(S, S1_A4, S1_A2, wv, 8, k, dz);
    st_e<144>(S, S1_A4, S1_A2, wv, 9, k, e);
  }
  {
    int ch = (wv << 5) + oB;        // 64 channels x 2 pixels = 128 tasks
    float p1v = pts1[(size_t)bnC*64 + ch];
    #pragma unroll
    for (int k = 0; k < 6; ++k) st_e<144>(S, S1_A4, S1_A2, pC, 10 + ch, k, p1v);
    #pragma unroll
    for (int k = 0; k < 6; ++k){
      float v = pts2[((size_t)bC*NPIX + selFlat[pC][k])*64 + ch] * selMask[pC][k];
      st_e<144>(S, S1_A4, S1_A2, pC, 74 + ch, k, v);
    }
  }
  __syncthreads();

  // ---------- conv1: 138 -> 128 relu ----------
  {
    const int o2 = (wv << 6) + (oB << 1);       // output pair
    float a0[6], a1r[6];
    const float bx = b0[o2], by = b0[o2+1];
    #pragma unroll
    for (int k = 0; k < 6; ++k){ a0[k] = bx; a1r[k] = by; }
    #pragma unroll 2
    for (int c = 0; c < 138; ++c){
      const float2 wp = *(const float2*)(w0 + c*128 + o2);
      const float4 x4 = *(const float4*)(S + S1_A4 + ((pC*144 + c)<<2));
      const float2 x2 = *(const float2*)(S + S1_A2 + ((pC*144 + c)<<1));
      a0[0]=fmaf(x4.x,wp.x,a0[0]); a0[1]=fmaf(x4.y,wp.x,a0[1]);
      a0[2]=fmaf(x4.z,wp.x,a0[2]); a0[3]=fmaf(x4.w,wp.x,a0[3]);
      a0[4]=fmaf(x2.x,wp.x,a0[4]); a0[5]=fmaf(x2.y,wp.x,a0[5]);
      a1r[0]=fmaf(x4.x,wp.y,a1r[0]); a1r[1]=fmaf(x4.y,wp.y,a1r[1]);
      a1r[2]=fmaf(x4.z,wp.y,a1r[2]); a1r[3]=fmaf(x4.w,wp.y,a1r[3]);
      a1r[4]=fmaf(x2.x,wp.y,a1r[4]); a1r[5]=fmaf(x2.y,wp.y,a1r[5]);
    }
    #pragma unroll
    for (int k = 0; k < 6; ++k){
      st_e<128>(S, S1_H14, S1_H12, pC, o2,   k, RELU(a0[k]));
      st_e<128>(S, S1_H14, S1_H12, pC, o2+1, k, RELU(a1r[k]));
    }
  }
  __syncthreads();

  // ---------- conv2: 128 -> 64 relu  +  pienc: 10 -> 64 relu ----------
  {
    const int o = (wv << 5) + oB;
    float acc[6], ae[6];
    const float bb = b1[o], be = pb[o];
    #pragma unroll
    for (int k = 0; k < 6; ++k){ acc[k] = bb; ae[k] = be; }
    #pragma unroll 4
    for (int c = 0; c < 128; ++c){
      const float wvv = w1[c*64 + o];
      const float4 x4 = *(const float4*)(S + S1_H14 + ((pC*128 + c)<<2));
      const float2 x2 = *(const float2*)(S + S1_H12 + ((pC*128 + c)<<1));
      acc[0]=fmaf(x4.x,wvv,acc[0]); acc[1]=fmaf(x4.y,wvv,acc[1]);
      acc[2]=fmaf(x4.z,wvv,acc[2]); acc[3]=fmaf(x4.w,wvv,acc[3]);
      acc[4]=fmaf(x2.x,wvv,acc[4]); acc[5]=fmaf(x2.y,wvv,acc[5]);
    }
    #pragma unroll
    for (int c = 0; c < 10; ++c){
      const float wvv = pw[c*64 + o];
      const float4 x4 = *(const float4*)(S + S1_A4 + ((pC*144 + c)<<2));
      const float2 x2 = *(const float2*)(S + S1_A2 + ((pC*144 + c)<<1));
      ae[0]=fmaf(x4.x,wvv,ae[0]); ae[1]=fmaf(x4.y,wvv,ae[1]);
      ae[2]=fmaf(x4.z,wvv,ae[2]); ae[3]=fmaf(x4.w,wvv,ae[3]);
      ae[4]=fmaf(x2.x,wvv,ae[4]); ae[5]=fmaf(x2.y,wvv,ae[5]);
    }
    #pragma unroll
    for (int k = 0; k < 6; ++k){
      st_e<64> (S, S1_H24, S1_H22, pC, o, k, RELU(acc[k]));   // h2
      st_e<128>(S, S1_C4,  S1_C2,  pC, o, k, RELU(ae[k]));    // enc -> cat rows 0..63
    }
  }
  __syncthreads();

  // ---------- conv3: 64 -> 64 relu -> feat (cat rows 64..127) ----------
  {
    const int o = (wv << 5) + oB;
    float acc[6];
    const float bb = b2[o];
    #pragma unroll
    for (int k = 0; k < 6; ++k) acc[k] = bb;
    #pragma unroll 4
    for (int c = 0; c < 64; ++c){
      const float wvv = w2[c*64 + o];
      const float4 x4 = *(const float4*)(S + S1_H24 + ((pC*64 + c)<<2));
      const float2 x2 = *(const float2*)(S + S1_H22 + ((pC*64 + c)<<1));
      acc[0]=fmaf(x4.x,wvv,acc[0]); acc[1]=fmaf(x4.y,wvv,acc[1]);
      acc[2]=fmaf(x4.z,wvv,acc[2]); acc[3]=fmaf(x4.w,wvv,acc[3]);
      acc[4]=fmaf(x2.x,wvv,acc[4]); acc[5]=fmaf(x2.y,wvv,acc[5]);
    }
    #pragma unroll
    for (int k = 0; k < 6; ++k)
      st_e<128>(S, S1_C4, S1_C2, pC, 64 + o, k, RELU(acc[k]));
  }
  __syncthreads();

  // ---------- m2 conv1: 128 -> 128 relu -> a1 (aliases act rows 0..127) ----------
  {
    const int o2 = (wv << 6) + (oB << 1);
    float a0[6], a1r[6];
    const float bx = q0b[o2], by = q0b[o2+1];
    #pragma unroll
    for (int k = 0; k < 6; ++k){ a0[k] = bx; a1r[k] = by; }
    #pragma unroll 4
    for (int c = 0; c < 128; ++c){
      const float2 wp = *(const float2*)(q0w + c*128 + o2);
      const float4 x4 = *(const float4*)(S + S1_C4 + ((pC*128 + c)<<2));
      const float2 x2 = *(const float2*)(S + S1_C2 + ((pC*128 + c)<<1));
      a0[0]=fmaf(x4.x,wp.x,a0[0]); a0[1]=fmaf(x4.y,wp.x,a0[1]);
      a0[2]=fmaf(x4.z,wp.x,a0[2]); a0[3]=fmaf(x4.w,wp.x,a0[3]);
      a0[4]=fmaf(x2.x,wp.x,a0[4]); a0[5]=fmaf(x2.y,wp.x,a0[5]);
      a1r[0]=fmaf(x4.x,wp.y,a1r[0]); a1r[1]=fmaf(x4.y,wp.y,a1r[1]);
      a1r[2]=fmaf(x4.z,wp.y,a1r[2]); a1r[3]=fmaf(x4.w,wp.y,a1r[3]);
      a1r[4]=fmaf(x2.x,wp.y,a1r[4]); a1r[5]=fmaf(x2.y,wp.y,a1r[5]);
    }
    #pragma unroll
    for (int k = 0; k < 6; ++k){
      st_e<144>(S, S1_A4, S1_A2, pC, o2,   k, RELU(a0[k]));
      st_e<144>(S, S1_A4, S1_A2, pC, o2+1, k, RELU(a1r[k]));
    }
  }
  __syncthreads();

  // ---------- m2 conv2: 128 -> 64 relu -> att (aliases h2) ----------
  {
    const int o = (wv << 5) + oB;
    float acc[6];
    const float bb = q1b[o];
    #pragma unroll
    for (int k = 0; k < 6; ++k) acc[k] = bb;
    #pragma unroll 4
    for (int c = 0; c < 128; ++c){
      const float wvv = q1w[c*64 + o];
      const float4 x4 = *(const float4*)(S + S1_A4 + ((pC*144 + c)<<2));
      const float2 x2 = *(const float2*)(S + S1_A2 + ((pC*144 + c)<<1));
      acc[0]=fmaf(x4.x,wvv,acc[0]); acc[1]=fmaf(x4.y,wvv,acc[1]);
      acc[2]=fmaf(x4.z,wvv,acc[2]); acc[3]=fmaf(x4.w,wvv,acc[3]);
      acc[4]=fmaf(x2.x,wvv,acc[4]); acc[5]=fmaf(x2.y,wvv,acc[5]);
    }
    #pragma unroll
    for (int k = 0; k < 6; ++k)
      st_e<64>(S, S1_H24, S1_H22, pC, o, k, RELU(acc[k]));
  }
  __syncthreads();

  // ---------- masked softmax over K=6 + weighted sum ----------
  {
    const int o = (wv << 5) + oB;
    const float4 at4 = *(const float4*)(S + S1_H24 + ((pC*64 + o)<<2));
    const float2 at2 = *(const float2*)(S + S1_H22 + ((pC*64 + o)<<1));
    const float4 f4  = *(const float4*)(S + S1_C4 + ((pC*128 + 64 + o)<<2));
    const float2 f2  = *(const float2*)(S + S1_C2 + ((pC*128 + 64 + o)<<1));
    float att[6] = {at4.x, at4.y, at4.z, at4.w, at2.x, at2.y};
    float ft[6]  = {f4.x, f4.y, f4.z, f4.w, f2.x, f2.y};
    float v[6];
    #pragma unroll
    for (int k = 0; k < 6; ++k)
      v[k] = (selMask[pC][k] > 0.5f) ? att[k] : -1e10f;
    float mx = v[0];
    #pragma unroll
    for (int k = 1; k < 6; ++k) mx = fmaxf(mx, v[k]);
    float s = 0.0f, ws = 0.0f;
    #pragma unroll
    for (int k = 0; k < 6; ++k){
      float e = expf(v[k] - mx);
      s += e; ws = fmaf(e, ft[k], ws);
    }
    f1out[(size_t)bnC*64 + o] = ws / s;
  }
}

// ---------------- stage 2 LDS layout (float offsets) ----------------
#define S2_X4  0      // xyz_cat2 [2][12][4] (rows 0..9 used)
#define S2_C4  96     // cat      [2][192][4]
#define S2_A4  1632   // a1       [2][128][4]
#define S2_T4  2656   // att      [2][64][4]
#define S2_TOT 3168

__global__ __launch_bounds__(128)
void stage2_kernel(const float* __restrict__ xyz1, const float* __restrict__ pts1,
                   const float* __restrict__ f1,
                   const float* __restrict__ pcw, const float* __restrict__ pcb, // 10x64
                   const float* __restrict__ n0w, const float* __restrict__ n0b, // 192x128
                   const float* __restrict__ n1w, const float* __restrict__ n1b, // 128x64
                   float* __restrict__ out)
{
  __shared__ __align__(16) float S[S2_TOT];
  __shared__ int   selFlat[2][4];
  __shared__ float selMask[2][4];

  const int t  = threadIdx.x;
  const int wv = t >> 6;
  const int l  = t & 63;
  const int pC = l >> 5;
  const int oB = l & 31;
  const int bn0 = blockIdx.x << 1;

  // ---------- selection (3x3 window, top-4) ----------
  const int bnS = bn0 + wv;
  const int bS = bnS >> 14, nS = bnS & 16383, hS = nS >> 8, wS = nS & 255;
  const float qSx = xyz1[bnS*3+0], qSy = xyz1[bnS*3+1], qSz = xyz1[bnS*3+2];

  unsigned long long key = ~0ull;
  if (l < 9){
    int c = l;
    int dh = c/3 - 1, dw = c%3 - 1;
    int ch = hS + dh, cw = wS + dw;
    bool inb = ((unsigned)ch < HH) && ((unsigned)cw < WW);
    unsigned hi = 0x7f800000u;
    if (inb){
      int fl = ch*WW + cw;
      const float* p = xyz1 + ((size_t)bS*NPIX + fl)*3;
      float dx = p[0]-qSx, dy = p[1]-qSy, dz = p[2]-qSz;
      float d2 = dx*dx + dy*dy + dz*dz;
      if (d2 < 10.0f) hi = __float_as_uint(d2);
    }
    key = ((unsigned long long)hi << 32) | (unsigned)c;
  }
  for (int j = 0; j < 4; ++j){
    unsigned long long m = wave_min64(key);
    if (l == 0){
      int c = (int)(m & 0xffffffffull);
      bool val = (unsigned)(m >> 32) < 0x7f800000u;
      int dh = c/3 - 1, dw = c%3 - 1;
      int cch = min(max(hS+dh, 0), HH-1), ccw = min(max(wS+dw, 0), WW-1);
      selFlat[wv][j] = val ? (cch*WW + ccw) : 0;
      selMask[wv][j] = val ? 1.0f : 0.0f;
    }
    if (key == m) key = ~0ull;
  }
  __syncthreads();

  // ---------- build ----------
  const int bnC = bn0 + pC;
  const int bC  = bnC >> 14;
  if (l < 4){                      // xyz_cat2 rows for pixel wv, neighbor k=l
    int k = l;
    float mk = selMask[wv][k];
    const float* p = xyz1 + ((size_t)bS*NPIX + selFlat[wv][k])*3;
    float ax = p[0]*mk, ay = p[1]*mk, az = p[2]*mk;
    float dx = ax - qSx, dy = ay - qSy, dz = az - qSz;
    float e = sqrtf(dx*dx + dy*dy + dz*dz + 1e-20f);
    float vals[10] = {qSx, qSy, qSz, ax, ay, az, dx, dy, dz, e};
    #pragma unroll
    for (int c = 0; c < 10; ++c)
      S[S2_X4 + ((wv*12 + c)<<2) + k] = vals[c];
  }
  {
    int ch = (wv << 5) + oB;
    float p1v = pts1[(size_t)bnC*64 + ch];
    #pragma unroll
    for (int k = 0; k < 4; ++k){
      float mk = selMask[pC][k];
      S[S2_C4 + ((pC*192 + 64 + ch)<<2) + k] = p1v * mk;
      float g = f1[((size_t)bC*NPIX + selFlat[pC][k])*64 + ch] * mk;
      S[S2_C4 + ((pC*192 + 128 + ch)<<2) + k] = g;
    }
  }
  __syncthreads();

  // ---------- pcenc: 10 -> 64 relu (masked into cat rows 0..63) ----------
  {
    const int o = (wv << 5) + oB;
    float ae[4];
    const float be = pcb[o];
    #pragma unroll
    for (int k = 0; k < 4; ++k) ae[k] = be;
    #pragma unroll
    for (int c = 0; c < 10; ++c){
      const float wvv = pcw[c*64 + o];
      const float4 x4 = *(const float4*)(S + S2_X4 + ((pC*12 + c)<<2));
      ae[0]=fmaf(x4.x,wvv,ae[0]); ae[1]=fmaf(x4.y,wvv,ae[1]);
      ae[2]=fmaf(x4.z,wvv,ae[2]); ae[3]=fmaf(x4.w,wvv,ae[3]);
    }
    #pragma unroll
    for (int k = 0; k < 4; ++k)
      S[S2_C4 + ((pC*192 + o)<<2) + k] = RELU(ae[k]) * selMask[pC][k];
  }
  __syncthreads();

  // ---------- m2n conv1: 192 -> 128 relu ----------
  {
    const int o2 = (wv << 6) + (oB << 1);
    float a0[4], a1r[4];
    const float bx = n0b[o2], by = n0b[o2+1];
    #pragma unroll
    for (int k = 0; k < 4; ++k){ a0[k] = bx; a1r[k] = by; }
    #pragma unroll 4
    for (int c = 0; c < 192; ++c){
      const float2 wp = *(const float2*)(n0w + c*128 + o2);
      const float4 x4 = *(const float4*)(S + S2_C4 + ((pC*192 + c)<<2));
      a0[0]=fmaf(x4.x,wp.x,a0[0]); a0[1]=fmaf(x4.y,wp.x,a0[1]);
      a0[2]=fmaf(x4.z,wp.x,a0[2]); a0[3]=fmaf(x4.w,wp.x,a0[3]);
      a1r[0]=fmaf(x4.x,wp.y,a1r[0]); a1r[1]=fmaf(x4.y,wp.y,a1r[1]);
      a1r[2]=fmaf(x4.z,wp.y,a1r[2]); a1r[3]=fmaf(x4.w,wp.y,a1r[3]);
    }
    #pragma unroll
    for (int k = 0; k < 4; ++k){
      S[S2_A4 + ((pC*128 + o2  )<<2) + k] = RELU(a0[k]);
      S[S2_A4 + ((pC*128 + o2+1)<<2) + k] = RELU(a1r[k]);
    }
  }
  __syncthreads();

  // ---------- m2n conv2: 128 -> 64 relu ----------
  {
    const int o = (wv << 5) + oB;
    float acc[4];
    const float bb = n1b[o];
    #pragma unroll
    for (int k = 0; k < 4; ++k) acc[k] = bb;
    #pragma unroll 4
    for (int c = 0; c < 128; ++c){
      const float wvv = n1w[c*64 + o];
      const float4 x4 = *(const float4*)(S + S2_A4 + ((pC*128 + c)<<2));
      acc[0]=fmaf(x4.x,wvv,acc[0]); acc[1]=fmaf(x4.y,wvv,acc[1]);
      acc[2]=fmaf(x4.z,wvv,acc[2]); acc[3]=fmaf(x4.w,wvv,acc[3]);
    }
    #pragma unroll
    for (int k = 0; k < 4; ++k)
      S[S2_T4 + ((pC*64 + o)<<2) + k] = RELU(acc[k]);
  }
  __syncthreads();

  // ---------- masked softmax over K=4 + weighted sum ----------
  {
    const int o = (wv << 5) + oB;
    const float4 at4 = *(const float4*)(S + S2_T4 + ((pC*64 + o)<<2));
    const float4 g4  = *(const float4*)(S + S2_C4 + ((pC*192 + 128 + o)<<2));
    float att[4] = {at4.x, at4.y, at4.z, at4.w};
    float gt[4]  = {g4.x, g4.y, g4.z, g4.w};
    float v[4];
    #pragma unroll
    for (int k = 0; k < 4; ++k)
      v[k] = (selMask[pC][k] > 0.5f) ? att[k] : -1e10f;
    float mx = fmaxf(fmaxf(v[0], v[1]), fmaxf(v[2], v[3]));
    float s = 0.0f, ws = 0.0f;
    #pragma unroll
    for (int k = 0; k < 4; ++k){
      float e = expf(v[k] - mx);
      s += e; ws = fmaf(e, gt[k], ws);
    }
    out[(size_t)bnC*64 + o] = ws / s;
  }
}

extern "C" void kernel_launch(void* const* d_in, const int* in_sizes, int n_in,
                              void* d_out, int out_size, void* d_ws, size_t ws_size,
                              hipStream_t stream) {
    const float* xyz1 = (const float*)d_in[0];
    const float* xyz2 = (const float*)d_in[1];
    const float* pts1 = (const float*)d_in[2];
    const float* pts2 = (const float*)d_in[3];
    const float* m1w0 = (const float*)d_in[4];
    const float* m1b0 = (const float*)d_in[5];
    const float* m1w1 = (const float*)d_in[6];
    const float* m1b1 = (const float*)d_in[7];
    const float* m1w2 = (const float*)d_in[8];
    const float* m1b2 = (const float*)d_in[9];
    const float* piw  = (const float*)d_in[10];
    const float* pib  = (const float*)d_in[11];
    const float* m2w0 = (const float*)d_in[12];
    const float* m2b0 = (const float*)d_in[13];
    const float* m2w1 = (const float*)d_in[14];
    const float* m2b1 = (const float*)d_in[15];
    const float* pcw  = (const float*)d_in[16];
    const float* pcb  = (const float*)d_in[17];
    const float* n0w  = (const float*)d_in[18];
    const float* n0b  = (const float*)d_in[19];
    const float* n1w  = (const float*)d_in[20];
    const float* n1b  = (const float*)d_in[21];

    const int B = in_sizes[0] / (NPIX * 3);
    float* f1  = (float*)d_ws;          // [B,N,64] intermediate
    float* out = (float*)d_out;

    dim3 grid((B * NPIX) / 2);
    dim3 block(128);

    hipLaunchKernelGGL(stage1_kernel, grid, block, 0, stream,
                       xyz1, xyz2, pts1, pts2,
                       m1w0, m1b0, m1w1, m1b1, m1w2, m1b2,
                       piw, pib, m2w0, m2b0, m2w1, m2b1,
                       f1);
    hipLaunchKernelGGL(stage2_kernel, grid, block, 0, stream,
                       xyz1, pts1, f1,
                       pcw, pcb, n0w, n0b, n1w, n1b,
                       out);
}

// Round 3
// 597.822 us; speedup vs baseline: 4.2587x; 2.3478x over previous
//
#include <hip/hip_runtime.h>
#include <math.h>

#define HH 64
#define WW 256
#define NPIX (HH*WW)

typedef unsigned short u16;
typedef __attribute__((ext_vector_type(8))) short s16x8;
typedef __attribute__((ext_vector_type(4))) float f32x4;

// ---------------- bf16 split helpers ----------------
__device__ __forceinline__ u16 f2bf(float x){
  union { float f; unsigned u; } v; v.f = x;
  unsigned r = v.u + 0x7fffu + ((v.u >> 16) & 1u);
  return (u16)(r >> 16);
}
__device__ __forceinline__ float bf2f(u16 h){
  union { unsigned u; float f; } v; v.u = ((unsigned)h) << 16;
  return v.f;
}
__device__ __forceinline__ void splitbf(float x, u16& h, u16& l){
  h = f2bf(x); l = f2bf(x - bf2f(h));
}

// A-fragment LDS layout: [mtile][kstep][lane64][8] bf16 (hi plane, then lo plane)
__device__ __forceinline__ int fragByte(int KS, int row, int kcol){
  int frag = ((row >> 4) * KS + (kcol >> 5)) * 64 + ((row & 15) | (((kcol >> 3) & 3) << 4));
  return frag * 16 + ((kcol & 7) << 1);
}
__device__ __forceinline__ void stPl(char* S, int off, int planeB, int KS, int row, int kcol, u16 h, u16 l){
  int bo = fragByte(KS, row, kcol);
  *(u16*)(S + off + bo) = h;
  *(u16*)(S + off + planeB + bo) = l;
}
__device__ __forceinline__ s16x8 ldPl(const char* S, int off, int KS, int mt, int ks, int l){
  return *(const s16x8*)(S + off + ((mt * KS + ks) * 64 + l) * 16);
}
__device__ __forceinline__ s16x8 ldWf(const u16* wp, int base, int KS, int nt, int ks, int l){
  return *(const s16x8*)(wp + base + (size_t)((nt * KS + ks) * 64 + l) * 8);
}

// weight-plane bases (u16 elems) in d_ws
#define WB_W0 0
#define WS_W0 20480
#define WB_W1 40960
#define WS_W1 8192
#define WB_W2 57344
#define WS_W2 4096
#define WB_PW 65536
#define WS_PW 2048
#define WB_Q0 69632
#define WS_Q0 16384
#define WB_Q1 102400
#define WS_Q1 8192
#define WB_PC 118784
#define WS_PC 2048
#define WB_N0 122880
#define WS_N0 24576
#define WB_N1 172032
#define WS_N1 8192
#define F1_OFFSET (512*1024)

// generic split-precision MFMA layer: MT mtiles, KS ksteps, NTW ntiles per wave
template<int MT, int KS, int NTW>
__device__ __forceinline__ void mfmaLayer(const char* S, int offA, int planeA,
                                          const u16* wp, int wbase, int wsz,
                                          int wv, int l, f32x4 (&acc)[MT][NTW])
{
  #pragma unroll
  for (int ks = 0; ks < KS; ++ks){
    s16x8 bh[NTW], bl[NTW];
    #pragma unroll
    for (int j = 0; j < NTW; ++j){
      int nt = wv * NTW + j;
      bh[j] = ldWf(wp, wbase,       KS, nt, ks, l);
      bl[j] = ldWf(wp, wbase + wsz, KS, nt, ks, l);
    }
    #pragma unroll
    for (int mt = 0; mt < MT; ++mt){
      s16x8 ah = ldPl(S, offA,          KS, mt, ks, l);
      s16x8 al = ldPl(S, offA + planeA, KS, mt, ks, l);
      #pragma unroll
      for (int j = 0; j < NTW; ++j){
        acc[mt][j] = __builtin_amdgcn_mfma_f32_16x16x32_bf16(ah, bh[j], acc[mt][j], 0, 0, 0);
        acc[mt][j] = __builtin_amdgcn_mfma_f32_16x16x32_bf16(ah, bl[j], acc[mt][j], 0, 0, 0);
        acc[mt][j] = __builtin_amdgcn_mfma_f32_16x16x32_bf16(al, bh[j], acc[mt][j], 0, 0, 0);
      }
    }
  }
}

__device__ __forceinline__ unsigned long long wave_min64(unsigned long long m){
  #pragma unroll
  for (int off = 1; off < 64; off <<= 1){
    unsigned lo = __shfl_xor((unsigned)m, off, 64);
    unsigned hi = __shfl_xor((unsigned)(m >> 32), off, 64);
    unsigned long long o = ((unsigned long long)hi << 32) | lo;
    if (o < m) m = o;
  }
  return m;
}

// ---------------- weight prep: fp32 -> B-fragment hi/lo bf16 planes ----------------
__global__ __launch_bounds__(256)
void prep_weights(const float* __restrict__ w0, const float* __restrict__ w1,
                  const float* __restrict__ w2, const float* __restrict__ pw,
                  const float* __restrict__ q0, const float* __restrict__ q1,
                  const float* __restrict__ pcw, const float* __restrict__ n0,
                  const float* __restrict__ n1, u16* __restrict__ wp)
{
  int id = blockIdx.x * 256 + threadIdx.x;
  const float* src; int Kdim, KS, N, base, sz, tau;
  if      (id <  2560){ src=w0;  Kdim=138; KS=5; N=128; base=WB_W0; sz=WS_W0; tau=id;        }
  else if (id <  3584){ src=w1;  Kdim=128; KS=4; N=64;  base=WB_W1; sz=WS_W1; tau=id-2560;   }
  else if (id <  4096){ src=w2;  Kdim=64;  KS=2; N=64;  base=WB_W2; sz=WS_W2; tau=id-3584;   }
  else if (id <  4352){ src=pw;  Kdim=10;  KS=1; N=64;  base=WB_PW; sz=WS_PW; tau=id-4096;   }
  else if (id <  6400){ src=q0;  Kdim=128; KS=4; N=128; base=WB_Q0; sz=WS_Q0; tau=id-4352;   }
  else if (id <  7424){ src=q1;  Kdim=128; KS=4; N=64;  base=WB_Q1; sz=WS_Q1; tau=id-6400;   }
  else if (id <  7680){ src=pcw; Kdim=10;  KS=1; N=64;  base=WB_PC; sz=WS_PC; tau=id-7424;   }
  else if (id < 10752){ src=n0;  Kdim=192; KS=6; N=128; base=WB_N0; sz=WS_N0; tau=id-7680;   }
  else if (id < 11776){ src=n1;  Kdim=128; KS=4; N=64;  base=WB_N1; sz=WS_N1; tau=id-10752;  }
  else return;
  int nt = tau / (KS * 64); int rem = tau % (KS * 64); int ks = rem >> 6; int l = rem & 63;
  s16x8 vh, vl;
  #pragma unroll
  for (int i = 0; i < 8; ++i){
    int k = ks * 32 + ((l >> 4) << 3) + i;
    int n = nt * 16 + (l & 15);
    float v = (k < Kdim) ? src[(size_t)k * N + n] : 0.0f;
    u16 h, lo; splitbf(v, h, lo);
    vh[i] = (short)h; vl[i] = (short)lo;
  }
  *(s16x8*)(wp + base + (size_t)tau * 8) = vh;
  *(s16x8*)(wp + base + sz + (size_t)tau * 8) = vl;
}

// ---------------- stage 1: 8 px/block, 48 rows = 3 mtiles, 256 threads ----------------
#define OFF_A    0        // A planes: max K=160 (KS=5): 15360/plane
#define PL_A0    15360
#define PL_A1    12288    // K=128
#define PL_A2    6144     // K=64
#define OFF_XYZ  30720    // K=32 (KS=1): 3072/plane
#define PL_XYZ   3072
#define OFF_CAT  36864    // K=128: 12288/plane
#define PL_CAT   12288
#define OFF_ATT  61440    // fp32 [48][64]
#define SM1_TOT  73728

__global__ __launch_bounds__(256)
void stage1_mfma(const float* __restrict__ xyz1, const float* __restrict__ xyz2,
                 const float* __restrict__ pts1, const float* __restrict__ pts2,
                 const float* __restrict__ b0, const float* __restrict__ b1,
                 const float* __restrict__ b2, const float* __restrict__ pb,
                 const float* __restrict__ q0b, const float* __restrict__ q1b,
                 const u16* __restrict__ wp, float* __restrict__ f1out)
{
  __shared__ __align__(16) char S[SM1_TOT];
  __shared__ int   selFlat[8][6];
  __shared__ float selMask[8][6];

  const int t = threadIdx.x, wv = t >> 6, l = t & 63;
  const int bn0 = blockIdx.x << 3;

  // ---- selection: wave wv owns pixels wv*2, wv*2+1 (5x15 window, top-6) ----
  for (int rep = 0; rep < 2; ++rep){
    const int pxl = (wv << 1) | rep;
    const int bn = bn0 + pxl;
    const int b = bn >> 14, n = bn & 16383, h = n >> 8, w = n & 255;
    const float qx = xyz1[bn*3], qy = xyz1[bn*3+1], qz = xyz1[bn*3+2];
    unsigned long long key[2];
    #pragma unroll
    for (int i = 0; i < 2; ++i){
      int c = l + (i << 6);
      unsigned long long kk = ~0ull;
      if (c < 75){
        int dh = c/15 - 2, dw = c%15 - 7;
        int ch = h + dh, cw = w + dw;
        bool inb = ((unsigned)ch < HH) && ((unsigned)cw < WW);
        unsigned hi = 0x7f800000u;
        if (inb){
          int fl = ch*WW + cw;
          const float* p = xyz2 + ((size_t)b*NPIX + fl)*3;
          float dx = p[0]-qx, dy = p[1]-qy, dz = p[2]-qz;
          float d2 = dx*dx + dy*dy + dz*dz;
          if (d2 < 100.0f) hi = __float_as_uint(d2);
        }
        kk = ((unsigned long long)hi << 32) | (unsigned)c;
      }
      key[i] = kk;
    }
    for (int j = 0; j < 6; ++j){
      unsigned long long m = key[0] < key[1] ? key[0] : key[1];
      m = wave_min64(m);
      if (l == 0){
        int c = (int)(m & 0xffffffffull);
        bool val = (unsigned)(m >> 32) < 0x7f800000u;
        int dh = c/15 - 2, dw = c%15 - 7;
        int cch = min(max(h+dh, 0), HH-1), ccw = min(max(w+dw, 0), WW-1);
        selFlat[pxl][j] = val ? (cch*WW + ccw) : 0;
        selMask[pxl][j] = val ? 1.0f : 0.0f;
      }
      if (key[0] == m) key[0] = ~0ull;
      if (key[1] == m) key[1] = ~0ull;
    }
  }
  __syncthreads();

  // ---- build A0 [48][160] + XYZ [48][32] (hi/lo planes, frag layout) ----
  for (int j = t; j < 1056; j += 256){ int row = j/22, k = 138 + j%22; stPl(S, OFF_A,   PL_A0,  5, row, k, 0, 0); }
  for (int j = t; j < 1056; j += 256){ int row = j/22, k = 10  + j%22; stPl(S, OFF_XYZ, PL_XYZ, 1, row, k, 0, 0); }
  if (t < 48){
    int row = t, px = row/6, k = row%6;
    int bn = bn0 + px, b = bn >> 14;
    float qx = xyz1[bn*3], qy = xyz1[bn*3+1], qz = xyz1[bn*3+2];
    float mk = selMask[px][k];
    const float* p = xyz2 + ((size_t)b*NPIX + selFlat[px][k])*3;
    float ax = p[0]*mk, ay = p[1]*mk, az = p[2]*mk;
    float dx = ax-qx, dy = ay-qy, dz = az-qz;
    float e = sqrtf(dx*dx + dy*dy + dz*dz + 1e-20f);
    float vals[10] = {qx, qy, qz, ax, ay, az, dx, dy, dz, e};
    #pragma unroll
    for (int c = 0; c < 10; ++c){
      u16 hh, ll; splitbf(vals[c], hh, ll);
      stPl(S, OFF_A,   PL_A0,  5, row, c, hh, ll);
      stPl(S, OFF_XYZ, PL_XYZ, 1, row, c, hh, ll);
    }
  }
  for (int j = t; j < 512; j += 256){
    int px = j >> 6, ch = j & 63; int bn = bn0 + px;
    float v = pts1[(size_t)bn*64 + ch];
    u16 hh, ll; splitbf(v, hh, ll);
    #pragma unroll
    for (int k = 0; k < 6; ++k) stPl(S, OFF_A, PL_A0, 5, px*6 + k, 10 + ch, hh, ll);
  }
  for (int j = t; j < 3072; j += 256){
    int row = j >> 6, ch = j & 63; int px = row/6, k = row%6;
    int bn = bn0 + px, b = bn >> 14;
    float v = pts2[((size_t)b*NPIX + selFlat[px][k])*64 + ch] * selMask[px][k];
    u16 hh, ll; splitbf(v, hh, ll);
    stPl(S, OFF_A, PL_A0, 5, row, 74 + ch, hh, ll);
  }
  __syncthreads();

  // ---- L1: 160 -> 128 relu ----
  {
    f32x4 acc[3][2];
    #pragma unroll
    for (int mt = 0; mt < 3; ++mt)
      #pragma unroll
      for (int j = 0; j < 2; ++j) acc[mt][j] = (f32x4){0.f,0.f,0.f,0.f};
    mfmaLayer<3,5,2>(S, OFF_A, PL_A0, wp, WB_W0, WS_W0, wv, l, acc);
    __syncthreads();
    #pragma unroll
    for (int j = 0; j < 2; ++j){
      int colN = (wv*2 + j)*16 + (l & 15);
      float bias = b0[colN];
      #pragma unroll
      for (int mt = 0; mt < 3; ++mt)
        #pragma unroll
        for (int r = 0; r < 4; ++r){
          int row = mt*16 + ((l>>4)<<2) + r;
          float v = fmaxf(acc[mt][j][r] + bias, 0.f);
          u16 hh, ll; splitbf(v, hh, ll);
          stPl(S, OFF_A, PL_A1, 4, row, colN, hh, ll);
        }
    }
    __syncthreads();
  }

  // ---- L2: 128 -> 64 relu  +  pienc: 32 -> 64 relu ----
  {
    f32x4 acc[3][1], ae[3][1];
    #pragma unroll
    for (int mt = 0; mt < 3; ++mt){ acc[mt][0] = (f32x4){0.f,0.f,0.f,0.f}; ae[mt][0] = (f32x4){0.f,0.f,0.f,0.f}; }
    mfmaLayer<3,4,1>(S, OFF_A,   PL_A1,  wp, WB_W1, WS_W1, wv, l, acc);
    mfmaLayer<3,1,1>(S, OFF_XYZ, PL_XYZ, wp, WB_PW, WS_PW, wv, l, ae);
    __syncthreads();
    int colN = wv*16 + (l & 15);
    float bb = b1[colN], be = pb[colN];
    #pragma unroll
    for (int mt = 0; mt < 3; ++mt)
      #pragma unroll
      for (int r = 0; r < 4; ++r){
        int row = mt*16 + ((l>>4)<<2) + r;
        float v  = fmaxf(acc[mt][0][r] + bb, 0.f);
        float ve = fmaxf(ae[mt][0][r] + be, 0.f);
        u16 hh, ll; splitbf(v, hh, ll);
        stPl(S, OFF_A, PL_A2, 2, row, colN, hh, ll);
        splitbf(ve, hh, ll);
        stPl(S, OFF_CAT, PL_CAT, 4, row, colN, hh, ll);
      }
    __syncthreads();
  }

  // ---- L3: 64 -> 64 relu -> feat (cat cols 64..127) ----
  {
    f32x4 acc[3][1];
    #pragma unroll
    for (int mt = 0; mt < 3; ++mt) acc[mt][0] = (f32x4){0.f,0.f,0.f,0.f};
    mfmaLayer<3,2,1>(S, OFF_A, PL_A2, wp, WB_W2, WS_W2, wv, l, acc);
    int colN = wv*16 + (l & 15);
    float bb = b2[colN];
    #pragma unroll
    for (int mt = 0; mt < 3; ++mt)
      #pragma unroll
      for (int r = 0; r < 4; ++r){
        int row = mt*16 + ((l>>4)<<2) + r;
        float v = fmaxf(acc[mt][0][r] + bb, 0.f);
        u16 hh, ll; splitbf(v, hh, ll);
        stPl(S, OFF_CAT, PL_CAT, 4, row, 64 + colN, hh, ll);
      }
    __syncthreads();
  }

  // ---- m2c1: cat(128) -> 128 relu -> a1 ----
  {
    f32x4 acc[3][2];
    #pragma unroll
    for (int mt = 0; mt < 3; ++mt)
      #pragma unroll
      for (int j = 0; j < 2; ++j) acc[mt][j] = (f32x4){0.f,0.f,0.f,0.f};
    mfmaLayer<3,4,2>(S, OFF_CAT, PL_CAT, wp, WB_Q0, WS_Q0, wv, l, acc);
    #pragma unroll
    for (int j = 0; j < 2; ++j){
      int colN = (wv*2 + j)*16 + (l & 15);
      float bias = q0b[colN];
      #pragma unroll
      for (int mt = 0; mt < 3; ++mt)
        #pragma unroll
        for (int r = 0; r < 4; ++r){
          int row = mt*16 + ((l>>4)<<2) + r;
          float v = fmaxf(acc[mt][j][r] + bias, 0.f);
          u16 hh, ll; splitbf(v, hh, ll);
          stPl(S, OFF_A, PL_A1, 4, row, colN, hh, ll);
        }
    }
    __syncthreads();
  }

  // ---- m2c2: 128 -> 64 relu -> att (fp32) ----
  {
    f32x4 acc[3][1];
    #pragma unroll
    for (int mt = 0; mt < 3; ++mt) acc[mt][0] = (f32x4){0.f,0.f,0.f,0.f};
    mfmaLayer<3,4,1>(S, OFF_A, PL_A1, wp, WB_Q1, WS_Q1, wv, l, acc);
    int colN = wv*16 + (l & 15);
    float bb = q1b[colN];
    #pragma unroll
    for (int mt = 0; mt < 3; ++mt)
      #pragma unroll
      for (int r = 0; r < 4; ++r){
        int row = mt*16 + ((l>>4)<<2) + r;
        float v = fmaxf(acc[mt][0][r] + bb, 0.f);
        *(float*)(S + OFF_ATT + (row*64 + colN)*4) = v;
      }
    __syncthreads();
  }

  // ---- masked softmax over K=6 + weighted sum ----
  for (int j = t; j < 512; j += 256){
    int px = j >> 6, ch = j & 63; int bn = bn0 + px;
    float vv[6], ff[6];
    #pragma unroll
    for (int k = 0; k < 6; ++k){
      int row = px*6 + k;
      float a = *(const float*)(S + OFF_ATT + (row*64 + ch)*4);
      vv[k] = (selMask[px][k] > 0.5f) ? a : -1e10f;
      int bo = fragByte(4, row, 64 + ch);
      u16 hh = *(const u16*)(S + OFF_CAT + bo);
      u16 ll = *(const u16*)(S + OFF_CAT + PL_CAT + bo);
      ff[k] = bf2f(hh) + bf2f(ll);
    }
    float mx = vv[0];
    #pragma unroll
    for (int k = 1; k < 6; ++k) mx = fmaxf(mx, vv[k]);
    float s = 0.f, ws = 0.f;
    #pragma unroll
    for (int k = 0; k < 6; ++k){
      float e = expf(vv[k] - mx);
      s += e; ws = fmaf(e, ff[k], ws);
    }
    f1out[(size_t)bn*64 + ch] = ws / s;
  }
}

// ---------------- stage 2: 8 px/block, 32 rows = 2 mtiles, 256 threads ----------------
#define OFF2_CAT 0        // K=192 (KS=6): 12288/plane
#define PL2_CAT  12288
#define OFF2_XYZ 24576    // K=32: 2048/plane
#define PL2_XYZ  2048
#define OFF2_A1  28672    // K=128: 8192/plane
#define PL2_A1   8192
#define OFF2_ATT 45056    // fp32 [32][64]
#define SM2_TOT  53248

__global__ __launch_bounds__(256)
void stage2_mfma(const float* __restrict__ xyz1, const float* __restrict__ pts1,
                 const float* __restrict__ f1,
                 const float* __restrict__ pcb, const float* __restrict__ n0b,
                 const float* __restrict__ n1b,
                 const u16* __restrict__ wp, float* __restrict__ out)
{
  __shared__ __align__(16) char S[SM2_TOT];
  __shared__ int   selFlat[8][4];
  __shared__ float selMask[8][4];

  const int t = threadIdx.x, wv = t >> 6, l = t & 63;
  const int bn0 = blockIdx.x << 3;

  // ---- selection: 3x3 window, top-4 ----
  for (int rep = 0; rep < 2; ++rep){
    const int pxl = (wv << 1) | rep;
    const int bn = bn0 + pxl;
    const int b = bn >> 14, n = bn & 16383, h = n >> 8, w = n & 255;
    const float qx = xyz1[bn*3], qy = xyz1[bn*3+1], qz = xyz1[bn*3+2];
    unsigned long long key = ~0ull;
    if (l < 9){
      int dh = l/3 - 1, dw = l%3 - 1;
      int ch = h + dh, cw = w + dw;
      bool inb = ((unsigned)ch < HH) && ((unsigned)cw < WW);
      unsigned hi = 0x7f800000u;
      if (inb){
        int fl = ch*WW + cw;
        const float* p = xyz1 + ((size_t)b*NPIX + fl)*3;
        float dx = p[0]-qx, dy = p[1]-qy, dz = p[2]-qz;
        float d2 = dx*dx + dy*dy + dz*dz;
        if (d2 < 10.0f) hi = __float_as_uint(d2);
      }
      key = ((unsigned long long)hi << 32) | (unsigned)l;
    }
    for (int j = 0; j < 4; ++j){
      unsigned long long m = wave_min64(key);
      if (l == 0){
        int c = (int)(m & 0xffffffffull);
        bool val = (unsigned)(m >> 32) < 0x7f800000u;
        int dh = c/3 - 1, dw = c%3 - 1;
        int cch = min(max(h+dh, 0), HH-1), ccw = min(max(w+dw, 0), WW-1);
        selFlat[pxl][j] = val ? (cch*WW + ccw) : 0;
        selMask[pxl][j] = val ? 1.0f : 0.0f;
      }
      if (key == m) key = ~0ull;
    }
  }
  __syncthreads();

  // ---- build XYZ [32][32] + CAT cols 64..191 ----
  for (int j = t; j < 704; j += 256){ int row = j/22, k = 10 + j%22; stPl(S, OFF2_XYZ, PL2_XYZ, 1, row, k, 0, 0); }
  if (t < 32){
    int row = t, px = row >> 2, k = row & 3;
    int bn = bn0 + px, b = bn >> 14;
    float qx = xyz1[bn*3], qy = xyz1[bn*3+1], qz = xyz1[bn*3+2];
    float mk = selMask[px][k];
    const float* p = xyz1 + ((size_t)b*NPIX + selFlat[px][k])*3;
    float ax = p[0]*mk, ay = p[1]*mk, az = p[2]*mk;
    float dx = ax-qx, dy = ay-qy, dz = az-qz;
    float e = sqrtf(dx*dx + dy*dy + dz*dz + 1e-20f);
    float vals[10] = {qx, qy, qz, ax, ay, az, dx, dy, dz, e};
    #pragma unroll
    for (int c = 0; c < 10; ++c){
      u16 hh, ll; splitbf(vals[c], hh, ll);
      stPl(S, OFF2_XYZ, PL2_XYZ, 1, row, c, hh, ll);
    }
  }
  for (int j = t; j < 512; j += 256){
    int px = j >> 6, ch = j & 63; int bn = bn0 + px;
    float v0 = pts1[(size_t)bn*64 + ch];
    #pragma unroll
    for (int k = 0; k < 4; ++k){
      float v = v0 * selMask[px][k];
      u16 hh, ll; splitbf(v, hh, ll);
      stPl(S, OFF2_CAT, PL2_CAT, 6, px*4 + k, 64 + ch, hh, ll);
    }
  }
  for (int j = t; j < 2048; j += 256){
    int row = j >> 6, ch = j & 63; int px = row >> 2, k = row & 3;
    int bn = bn0 + px, b = bn >> 14;
    float v = f1[((size_t)b*NPIX + selFlat[px][k])*64 + ch] * selMask[px][k];
    u16 hh, ll; splitbf(v, hh, ll);
    stPl(S, OFF2_CAT, PL2_CAT, 6, row, 128 + ch, hh, ll);
  }
  __syncthreads();

  // ---- pcenc: 32 -> 64 relu, * mask -> cat cols 0..63 ----
  {
    f32x4 acc[2][1];
    acc[0][0] = (f32x4){0.f,0.f,0.f,0.f}; acc[1][0] = (f32x4){0.f,0.f,0.f,0.f};
    mfmaLayer<2,1,1>(S, OFF2_XYZ, PL2_XYZ, wp, WB_PC, WS_PC, wv, l, acc);
    int colN = wv*16 + (l & 15);
    float bb = pcb[colN];
    #pragma unroll
    for (int mt = 0; mt < 2; ++mt)
      #pragma unroll
      for (int r = 0; r < 4; ++r){
        int row = mt*16 + ((l>>4)<<2) + r;
        int px = row >> 2, k = row & 3;
        float v = fmaxf(acc[mt][0][r] + bb, 0.f) * selMask[px][k];
        u16 hh, ll; splitbf(v, hh, ll);
        stPl(S, OFF2_CAT, PL2_CAT, 6, row, colN, hh, ll);
      }
    __syncthreads();
  }

  // ---- m2n1: 192 -> 128 relu -> a1 ----
  {
    f32x4 acc[2][2];
    #pragma unroll
    for (int mt = 0; mt < 2; ++mt)
      #pragma unroll
      for (int j = 0; j < 2; ++j) acc[mt][j] = (f32x4){0.f,0.f,0.f,0.f};
    mfmaLayer<2,6,2>(S, OFF2_CAT, PL2_CAT, wp, WB_N0, WS_N0, wv, l, acc);
    #pragma unroll
    for (int j = 0; j < 2; ++j){
      int colN = (wv*2 + j)*16 + (l & 15);
      float bias = n0b[colN];
      #pragma unroll
      for (int mt = 0; mt < 2; ++mt)
        #pragma unroll
        for (int r = 0; r < 4; ++r){
          int row = mt*16 + ((l>>4)<<2) + r;
          float v = fmaxf(acc[mt][j][r] + bias, 0.f);
          u16 hh, ll; splitbf(v, hh, ll);
          stPl(S, OFF2_A1, PL2_A1, 4, row, colN, hh, ll);
        }
    }
    __syncthreads();
  }

  // ---- m2n2: 128 -> 64 relu -> att (fp32) ----
  {
    f32x4 acc[2][1];
    acc[0][0] = (f32x4){0.f,0.f,0.f,0.f}; acc[1][0] = (f32x4){0.f,0.f,0.f,0.f};
    mfmaLayer<2,4,1>(S, OFF2_A1, PL2_A1, wp, WB_N1, WS_N1, wv, l, acc);
    int colN = wv*16 + (l & 15);
    float bb = n1b[colN];
    #pragma unroll
    for (int mt = 0; mt < 2; ++mt)
      #pragma unroll
      for (int r = 0; r < 4; ++r){
        int row = mt*16 + ((l>>4)<<2) + r;
        float v = fmaxf(acc[mt][0][r] + bb, 0.f);
        *(float*)(S + OFF2_ATT + (row*64 + colN)*4) = v;
      }
    __syncthreads();
  }

  // ---- masked softmax over K=4 + weighted sum of f1 gathered ----
  for (int j = t; j < 512; j += 256){
    int px = j >> 6, ch = j & 63; int bn = bn0 + px;
    float vv[4], gg[4];
    #pragma unroll
    for (int k = 0; k < 4; ++k){
      int row = px*4 + k;
      float a = *(const float*)(S + OFF2_ATT + (row*64 + ch)*4);
      vv[k] = (selMask[px][k] > 0.5f) ? a : -1e10f;
      int bo = fragByte(6, row, 128 + ch);
      u16 hh = *(const u16*)(S + OFF2_CAT + bo);
      u16 ll = *(const u16*)(S + OFF2_CAT + PL2_CAT + bo);
      gg[k] = bf2f(hh) + bf2f(ll);
    }
    float mx = fmaxf(fmaxf(vv[0], vv[1]), fmaxf(vv[2], vv[3]));
    float s = 0.f, ws = 0.f;
    #pragma unroll
    for (int k = 0; k < 4; ++k){
      float e = expf(vv[k] - mx);
      s += e; ws = fmaf(e, gg[k], ws);
    }
    out[(size_t)bn*64 + ch] = ws / s;
  }
}

extern "C" void kernel_launch(void* const* d_in, const int* in_sizes, int n_in,
                              void* d_out, int out_size, void* d_ws, size_t ws_size,
                              hipStream_t stream) {
    const float* xyz1 = (const float*)d_in[0];
    const float* xyz2 = (const float*)d_in[1];
    const float* pts1 = (const float*)d_in[2];
    const float* pts2 = (const float*)d_in[3];
    const float* m1w0 = (const float*)d_in[4];
    const float* m1b0 = (const float*)d_in[5];
    const float* m1w1 = (const float*)d_in[6];
    const float* m1b1 = (const float*)d_in[7];
    const float* m1w2 = (const float*)d_in[8];
    const float* m1b2 = (const float*)d_in[9];
    const float* piw  = (const float*)d_in[10];
    const float* pib  = (const float*)d_in[11];
    const float* m2w0 = (const float*)d_in[12];
    const float* m2b0 = (const float*)d_in[13];
    const float* m2w1 = (const float*)d_in[14];
    const float* m2b1 = (const float*)d_in[15];
    const float* pcw  = (const float*)d_in[16];
    const float* pcb  = (const float*)d_in[17];
    const float* n0w  = (const float*)d_in[18];
    const float* n0b  = (const float*)d_in[19];
    const float* n1w  = (const float*)d_in[20];
    const float* n1b  = (const float*)d_in[21];

    const int B = in_sizes[0] / (NPIX * 3);
    u16*   wplanes = (u16*)d_ws;
    float* f1      = (float*)((char*)d_ws + F1_OFFSET);
    float* out     = (float*)d_out;

    hipLaunchKernelGGL(prep_weights, dim3(46), dim3(256), 0, stream,
                       m1w0, m1w1, m1w2, piw, m2w0, m2w1, pcw, n0w, n1w, wplanes);
    hipLaunchKernelGGL(stage1_mfma, dim3((B*NPIX)/8), dim3(256), 0, stream,
                       xyz1, xyz2, pts1, pts2,
                       m1b0, m1b1, m1b2, pib, m2b0, m2b1,
                       wplanes, f1);
    hipLaunchKernelGGL(stage2_mfma, dim3((B*NPIX)/8), dim3(256), 0, stream,
                       xyz1, pts1, f1, pcb, n0b, n1b,
                       wplanes, out);
}

// Round 4
// 349.113 us; speedup vs baseline: 7.2926x; 1.7124x over previous
//
#include <hip/hip_runtime.h>
#include <math.h>

#define HH 64
#define WW 256
#define NPIX (HH*WW)

typedef unsigned short u16;
typedef __attribute__((ext_vector_type(8))) short s16x8;
typedef __attribute__((ext_vector_type(8))) _Float16 h16x8;
typedef __attribute__((ext_vector_type(4))) float f32x4;
typedef __attribute__((ext_vector_type(2))) float f32x2;

// ---------------- f16 helpers (RTN) ----------------
__device__ __forceinline__ u16 f2h_(float x){
  _Float16 h = (_Float16)x;
  union { _Float16 h; u16 u; } v; v.h = h; return v.u;
}
__device__ __forceinline__ float h2f_(u16 b){
  union { u16 u; _Float16 h; } v; v.u = b; return (float)v.h;
}
__device__ __forceinline__ unsigned pack2(float a, float b){
  return (unsigned)f2h_(a) | ((unsigned)f2h_(b) << 16);
}
__device__ __forceinline__ void splith(float x, u16& h, u16& l){
  h = f2h_(x); l = f2h_(x - h2f_(h));
}

// A-fragment LDS layout: [mtile][kstep][lane64][8] f16
__device__ __forceinline__ int fragByte(int KS, int row, int kcol){
  int frag = ((row >> 4) * KS + (kcol >> 5)) * 64 + ((row & 15) | (((kcol >> 3) & 3) << 4));
  return frag * 16 + ((kcol & 7) << 1);
}
__device__ __forceinline__ void stH(char* S, int off, int KS, int row, int kcol, u16 v){
  *(u16*)(S + off + fragByte(KS, row, kcol)) = v;
}
__device__ __forceinline__ void stH2(char* S, int off, int KS, int row, int kcol, unsigned v2){
  *(unsigned*)(S + off + fragByte(KS, row, kcol)) = v2;   // kcol must be even
}
__device__ __forceinline__ h16x8 ldPl(const char* S, int off, int KS, int mt, int ks, int l){
  return *(const h16x8*)(S + off + ((mt * KS + ks) * 64 + l) * 16);
}
__device__ __forceinline__ h16x8 ldWf(const u16* wp, int base, int KS, int nt, int ks, int l){
  return *(const h16x8*)(wp + base + (size_t)((nt * KS + ks) * 64 + l) * 8);
}

// weight-plane bases (u16 elems) in d_ws
#define WB_W0 0
#define WS_W0 20480
#define WB_W1 40960
#define WS_W1 8192
#define WB_W2 57344
#define WS_W2 4096
#define WB_PW 65536
#define WS_PW 2048
#define WB_Q0 69632
#define WS_Q0 16384
#define WB_Q1 102400
#define WS_Q1 8192
#define WB_PC 118784
#define WS_PC 2048
#define WB_N0 122880
#define WS_N0 24576
#define WB_N1 172032
#define WS_N1 8192
#define F1_OFFSET (512*1024)

// 2-term split-precision MFMA layer: a(f16) x (wh + wl)
template<int MT, int KS, int NTW>
__device__ __forceinline__ void mfmaLayer(const char* S, int offA,
                                          const u16* wp, int wbase, int wsz,
                                          int wv, int l, f32x4 (&acc)[MT][NTW])
{
  #pragma unroll
  for (int ks = 0; ks < KS; ++ks){
    h16x8 bh[NTW], bl[NTW];
    #pragma unroll
    for (int j = 0; j < NTW; ++j){
      int nt = wv * NTW + j;
      bh[j] = ldWf(wp, wbase,       KS, nt, ks, l);
      bl[j] = ldWf(wp, wbase + wsz, KS, nt, ks, l);
    }
    #pragma unroll
    for (int mt = 0; mt < MT; ++mt){
      h16x8 a = ldPl(S, offA, KS, mt, ks, l);
      #pragma unroll
      for (int j = 0; j < NTW; ++j){
        acc[mt][j] = __builtin_amdgcn_mfma_f32_16x16x32_f16(a, bh[j], acc[mt][j], 0, 0, 0);
        acc[mt][j] = __builtin_amdgcn_mfma_f32_16x16x32_f16(a, bl[j], acc[mt][j], 0, 0, 0);
      }
    }
  }
}

__device__ __forceinline__ unsigned long long wave_min64(unsigned long long m){
  #pragma unroll
  for (int off = 1; off < 64; off <<= 1){
    unsigned lo = __shfl_xor((unsigned)m, off, 64);
    unsigned hi = __shfl_xor((unsigned)(m >> 32), off, 64);
    unsigned long long o = ((unsigned long long)hi << 32) | lo;
    if (o < m) m = o;
  }
  return m;
}

// ---------------- weight prep: fp32 -> B-fragment hi/lo f16 planes ----------------
__global__ __launch_bounds__(256)
void prep_weights(const float* __restrict__ w0, const float* __restrict__ w1,
                  const float* __restrict__ w2, const float* __restrict__ pw,
                  const float* __restrict__ q0, const float* __restrict__ q1,
                  const float* __restrict__ pcw, const float* __restrict__ n0,
                  const float* __restrict__ n1, u16* __restrict__ wp)
{
  int id = blockIdx.x * 256 + threadIdx.x;
  const float* src; int Kdim, KS, N, base, sz, tau;
  if      (id <  2560){ src=w0;  Kdim=138; KS=5; N=128; base=WB_W0; sz=WS_W0; tau=id;        }
  else if (id <  3584){ src=w1;  Kdim=128; KS=4; N=64;  base=WB_W1; sz=WS_W1; tau=id-2560;   }
  else if (id <  4096){ src=w2;  Kdim=64;  KS=2; N=64;  base=WB_W2; sz=WS_W2; tau=id-3584;   }
  else if (id <  4352){ src=pw;  Kdim=10;  KS=1; N=64;  base=WB_PW; sz=WS_PW; tau=id-4096;   }
  else if (id <  6400){ src=q0;  Kdim=128; KS=4; N=128; base=WB_Q0; sz=WS_Q0; tau=id-4352;   }
  else if (id <  7424){ src=q1;  Kdim=128; KS=4; N=64;  base=WB_Q1; sz=WS_Q1; tau=id-6400;   }
  else if (id <  7680){ src=pcw; Kdim=10;  KS=1; N=64;  base=WB_PC; sz=WS_PC; tau=id-7424;   }
  else if (id < 10752){ src=n0;  Kdim=192; KS=6; N=128; base=WB_N0; sz=WS_N0; tau=id-7680;   }
  else if (id < 11776){ src=n1;  Kdim=128; KS=4; N=64;  base=WB_N1; sz=WS_N1; tau=id-10752;  }
  else return;
  int nt = tau / (KS * 64); int rem = tau % (KS * 64); int ks = rem >> 6; int l = rem & 63;
  s16x8 vh, vl;
  #pragma unroll
  for (int i = 0; i < 8; ++i){
    int k = ks * 32 + ((l >> 4) << 3) + i;
    int n = nt * 16 + (l & 15);
    float v = (k < Kdim) ? src[(size_t)k * N + n] : 0.0f;
    u16 h, lo; splith(v, h, lo);
    vh[i] = (short)h; vl[i] = (short)lo;
  }
  *(s16x8*)(wp + base + (size_t)tau * 8) = vh;
  *(s16x8*)(wp + base + sz + (size_t)tau * 8) = vl;
}

// ---------------- stage 1: 8 px/block, 48 rows = 3 mtiles, 256 threads ----------------
// R0 (OFF_A, 15360B): A0 K160 -> A1 K128 -> h2 K64 -> a1 K128 -> att fp32 [48][64]
#define OFF_A    0
#define OFF_XYZ  15360   // K=32: 3072B
#define OFF_CAT  18432   // K=128: 12288B (enc cols0-63, feat cols64-127)
#define SM1_TOT  30720

__global__ __launch_bounds__(256)
void stage1_mfma(const float* __restrict__ xyz1, const float* __restrict__ xyz2,
                 const float* __restrict__ pts1, const float* __restrict__ pts2,
                 const float* __restrict__ b0, const float* __restrict__ b1,
                 const float* __restrict__ b2, const float* __restrict__ pb,
                 const float* __restrict__ q0b, const float* __restrict__ q1b,
                 const u16* __restrict__ wp, float* __restrict__ f1out)
{
  __shared__ __align__(16) char S[SM1_TOT];
  __shared__ int   selFlat[8][6];
  __shared__ float selMask[8][6];

  const int t = threadIdx.x, wv = t >> 6, l = t & 63;
  const int bn0 = blockIdx.x << 3;

  // ---- selection: wave wv owns pixels wv*2, wv*2+1 (5x15 window, top-6) ----
  for (int rep = 0; rep < 2; ++rep){
    const int pxl = (wv << 1) | rep;
    const int bn = bn0 + pxl;
    const int b = bn >> 14, n = bn & 16383, h = n >> 8, w = n & 255;
    const float qx = xyz1[bn*3], qy = xyz1[bn*3+1], qz = xyz1[bn*3+2];
    unsigned long long key[2];
    #pragma unroll
    for (int i = 0; i < 2; ++i){
      int c = l + (i << 6);
      unsigned long long kk = ~0ull;
      if (c < 75){
        int dh = c/15 - 2, dw = c%15 - 7;
        int ch = h + dh, cw = w + dw;
        bool inb = ((unsigned)ch < HH) && ((unsigned)cw < WW);
        unsigned hi = 0x7f800000u;
        if (inb){
          int fl = ch*WW + cw;
          const float* p = xyz2 + ((size_t)b*NPIX + fl)*3;
          float dx = p[0]-qx, dy = p[1]-qy, dz = p[2]-qz;
          float d2 = dx*dx + dy*dy + dz*dz;
          if (d2 < 100.0f) hi = __float_as_uint(d2);
        }
        kk = ((unsigned long long)hi << 32) | (unsigned)c;
      }
      key[i] = kk;
    }
    for (int j = 0; j < 6; ++j){
      unsigned long long m = key[0] < key[1] ? key[0] : key[1];
      m = wave_min64(m);
      if (l == 0){
        int c = (int)(m & 0xffffffffull);
        bool val = (unsigned)(m >> 32) < 0x7f800000u;
        int dh = c/15 - 2, dw = c%15 - 7;
        int cch = min(max(h+dh, 0), HH-1), ccw = min(max(w+dw, 0), WW-1);
        selFlat[pxl][j] = val ? (cch*WW + ccw) : 0;
        selMask[pxl][j] = val ? 1.0f : 0.0f;
      }
      if (key[0] == m) key[0] = ~0ull;
      if (key[1] == m) key[1] = ~0ull;
    }
  }
  __syncthreads();

  // ---- build A0 [48][160] + XYZ [48][32] (single f16 plane, frag layout) ----
  for (int j = t; j < 528; j += 256){ int row = j/11, c = 138 + 2*(j%11); stH2(S, OFF_A,   5, row, c, 0u); }
  for (int j = t; j < 528; j += 256){ int row = j/11, c = 10  + 2*(j%11); stH2(S, OFF_XYZ, 1, row, c, 0u); }
  if (t < 48){
    int row = t, px = row/6, k = row%6;
    int bn = bn0 + px, b = bn >> 14;
    float qx = xyz1[bn*3], qy = xyz1[bn*3+1], qz = xyz1[bn*3+2];
    float mk = selMask[px][k];
    const float* p = xyz2 + ((size_t)b*NPIX + selFlat[px][k])*3;
    float ax = p[0]*mk, ay = p[1]*mk, az = p[2]*mk;
    float dx = ax-qx, dy = ay-qy, dz = az-qz;
    float e = sqrtf(dx*dx + dy*dy + dz*dz + 1e-20f);
    float vals[10] = {qx, qy, qz, ax, ay, az, dx, dy, dz, e};
    #pragma unroll
    for (int c = 0; c < 5; ++c){
      unsigned pk = pack2(vals[2*c], vals[2*c+1]);
      stH2(S, OFF_A,   5, row, 2*c, pk);
      stH2(S, OFF_XYZ, 1, row, 2*c, pk);
    }
  }
  {
    int px = t >> 5, ch = (t & 31) << 1;     // 256 tasks: pts1 float2
    int bn = bn0 + px;
    f32x2 v = *(const f32x2*)(pts1 + (size_t)bn*64 + ch);
    unsigned pk = pack2(v.x, v.y);
    #pragma unroll
    for (int k = 0; k < 6; ++k) stH2(S, OFF_A, 5, px*6 + k, 10 + ch, pk);
  }
  for (int j = t; j < 1536; j += 256){       // pts2 gather float2
    int row = j >> 5, ch = (j & 31) << 1;
    int px = row/6, k = row%6;
    int bn = bn0 + px, b = bn >> 14;
    f32x2 v = *(const f32x2*)(pts2 + ((size_t)b*NPIX + selFlat[px][k])*64 + ch);
    float mk = selMask[px][k];
    stH2(S, OFF_A, 5, row, 74 + ch, pack2(v.x*mk, v.y*mk));
  }
  __syncthreads();

  // ---- L1: 160 -> 128 relu -> A1 (aliases A0) ----
  {
    f32x4 acc[3][2];
    #pragma unroll
    for (int mt = 0; mt < 3; ++mt)
      #pragma unroll
      for (int j = 0; j < 2; ++j) acc[mt][j] = (f32x4){0.f,0.f,0.f,0.f};
    mfmaLayer<3,5,2>(S, OFF_A, wp, WB_W0, WS_W0, wv, l, acc);
    __syncthreads();
    #pragma unroll
    for (int j = 0; j < 2; ++j){
      int colN = (wv*2 + j)*16 + (l & 15);
      float bias = b0[colN];
      #pragma unroll
      for (int mt = 0; mt < 3; ++mt)
        #pragma unroll
        for (int r = 0; r < 4; ++r){
          int row = mt*16 + ((l>>4)<<2) + r;
          stH(S, OFF_A, 4, row, colN, f2h_(fmaxf(acc[mt][j][r] + bias, 0.f)));
        }
    }
    __syncthreads();
  }

  // ---- L2: 128 -> 64 relu -> h2 (aliases)  +  pienc: 32 -> 64 relu -> enc (cat 0..63) ----
  {
    f32x4 acc[3][1], ae[3][1];
    #pragma unroll
    for (int mt = 0; mt < 3; ++mt){ acc[mt][0] = (f32x4){0.f,0.f,0.f,0.f}; ae[mt][0] = (f32x4){0.f,0.f,0.f,0.f}; }
    mfmaLayer<3,4,1>(S, OFF_A,   wp, WB_W1, WS_W1, wv, l, acc);
    mfmaLayer<3,1,1>(S, OFF_XYZ, wp, WB_PW, WS_PW, wv, l, ae);
    __syncthreads();
    int colN = wv*16 + (l & 15);
    float bb = b1[colN], be = pb[colN];
    #pragma unroll
    for (int mt = 0; mt < 3; ++mt)
      #pragma unroll
      for (int r = 0; r < 4; ++r){
        int row = mt*16 + ((l>>4)<<2) + r;
        stH(S, OFF_A,   2, row, colN, f2h_(fmaxf(acc[mt][0][r] + bb, 0.f)));
        stH(S, OFF_CAT, 4, row, colN, f2h_(fmaxf(ae[mt][0][r]  + be, 0.f)));
      }
    __syncthreads();
  }

  // ---- L3: 64 -> 64 relu -> feat (cat cols 64..127) ----
  {
    f32x4 acc[3][1];
    #pragma unroll
    for (int mt = 0; mt < 3; ++mt) acc[mt][0] = (f32x4){0.f,0.f,0.f,0.f};
    mfmaLayer<3,2,1>(S, OFF_A, wp, WB_W2, WS_W2, wv, l, acc);
    int colN = wv*16 + (l & 15);
    float bb = b2[colN];
    #pragma unroll
    for (int mt = 0; mt < 3; ++mt)
      #pragma unroll
      for (int r = 0; r < 4; ++r){
        int row = mt*16 + ((l>>4)<<2) + r;
        stH(S, OFF_CAT, 4, row, 64 + colN, f2h_(fmaxf(acc[mt][0][r] + bb, 0.f)));
      }
    __syncthreads();
  }

  // ---- m2c1: cat(128) -> 128 relu -> a1 (aliases) ----
  {
    f32x4 acc[3][2];
    #pragma unroll
    for (int mt = 0; mt < 3; ++mt)
      #pragma unroll
      for (int j = 0; j < 2; ++j) acc[mt][j] = (f32x4){0.f,0.f,0.f,0.f};
    mfmaLayer<3,4,2>(S, OFF_CAT, wp, WB_Q0, WS_Q0, wv, l, acc);
    #pragma unroll
    for (int j = 0; j < 2; ++j){
      int colN = (wv*2 + j)*16 + (l & 15);
      float bias = q0b[colN];
      #pragma unroll
      for (int mt = 0; mt < 3; ++mt)
        #pragma unroll
        for (int r = 0; r < 4; ++r){
          int row = mt*16 + ((l>>4)<<2) + r;
          stH(S, OFF_A, 4, row, colN, f2h_(fmaxf(acc[mt][j][r] + bias, 0.f)));
        }
    }
    __syncthreads();
  }

  // ---- m2c2: 128 -> 64 relu -> att fp32 (aliases a1 region) ----
  {
    f32x4 acc[3][1];
    #pragma unroll
    for (int mt = 0; mt < 3; ++mt) acc[mt][0] = (f32x4){0.f,0.f,0.f,0.f};
    mfmaLayer<3,4,1>(S, OFF_A, wp, WB_Q1, WS_Q1, wv, l, acc);
    __syncthreads();                        // all a1 reads done before overwrite
    int colN = wv*16 + (l & 15);
    float bb = q1b[colN];
    #pragma unroll
    for (int mt = 0; mt < 3; ++mt)
      #pragma unroll
      for (int r = 0; r < 4; ++r){
        int row = mt*16 + ((l>>4)<<2) + r;
        *(float*)(S + OFF_A + (row*64 + colN)*4) = fmaxf(acc[mt][0][r] + bb, 0.f);
      }
    __syncthreads();
  }

  // ---- masked softmax over K=6 + weighted sum ----
  for (int j = t; j < 512; j += 256){
    int px = j >> 6, ch = j & 63; int bn = bn0 + px;
    float vv[6], ff[6];
    #pragma unroll
    for (int k = 0; k < 6; ++k){
      int row = px*6 + k;
      float a = *(const float*)(S + OFF_A + (row*64 + ch)*4);
      vv[k] = (selMask[px][k] > 0.5f) ? a : -1e10f;
      ff[k] = h2f_(*(const u16*)(S + OFF_CAT + fragByte(4, row, 64 + ch)));
    }
    float mx = vv[0];
    #pragma unroll
    for (int k = 1; k < 6; ++k) mx = fmaxf(mx, vv[k]);
    float s = 0.f, ws = 0.f;
    #pragma unroll
    for (int k = 0; k < 6; ++k){
      float e = expf(vv[k] - mx);
      s += e; ws = fmaf(e, ff[k], ws);
    }
    f1out[(size_t)bn*64 + ch] = ws / s;
  }
}

// ---------------- stage 2: 8 px/block, 32 rows = 2 mtiles, 256 threads ----------------
#define OFF2_CAT 0       // K=192: 12288B
#define OFF2_XYZ 12288   // K=32: 2048B
#define OFF2_A1  14336   // K=128: 8192B; aliases att fp32 [32][64]
#define SM2_TOT  22528

__global__ __launch_bounds__(256)
void stage2_mfma(const float* __restrict__ xyz1, const float* __restrict__ pts1,
                 const float* __restrict__ f1,
                 const float* __restrict__ pcb, const float* __restrict__ n0b,
                 const float* __restrict__ n1b,
                 const u16* __restrict__ wp, float* __restrict__ out)
{
  __shared__ __align__(16) char S[SM2_TOT];
  __shared__ int   selFlat[8][4];
  __shared__ float selMask[8][4];

  const int t = threadIdx.x, wv = t >> 6, l = t & 63;
  const int bn0 = blockIdx.x << 3;

  // ---- selection: 3x3 window, top-4 ----
  for (int rep = 0; rep < 2; ++rep){
    const int pxl = (wv << 1) | rep;
    const int bn = bn0 + pxl;
    const int b = bn >> 14, n = bn & 16383, h = n >> 8, w = n & 255;
    const float qx = xyz1[bn*3], qy = xyz1[bn*3+1], qz = xyz1[bn*3+2];
    unsigned long long key = ~0ull;
    if (l < 9){
      int dh = l/3 - 1, dw = l%3 - 1;
      int ch = h + dh, cw = w + dw;
      bool inb = ((unsigned)ch < HH) && ((unsigned)cw < WW);
      unsigned hi = 0x7f800000u;
      if (inb){
        int fl = ch*WW + cw;
        const float* p = xyz1 + ((size_t)b*NPIX + fl)*3;
        float dx = p[0]-qx, dy = p[1]-qy, dz = p[2]-qz;
        float d2 = dx*dx + dy*dy + dz*dz;
        if (d2 < 10.0f) hi = __float_as_uint(d2);
      }
      key = ((unsigned long long)hi << 32) | (unsigned)l;
    }
    for (int j = 0; j < 4; ++j){
      unsigned long long m = wave_min64(key);
      if (l == 0){
        int c = (int)(m & 0xffffffffull);
        bool val = (unsigned)(m >> 32) < 0x7f800000u;
        int dh = c/3 - 1, dw = c%3 - 1;
        int cch = min(max(h+dh, 0), HH-1), ccw = min(max(w+dw, 0), WW-1);
        selFlat[pxl][j] = val ? (cch*WW + ccw) : 0;
        selMask[pxl][j] = val ? 1.0f : 0.0f;
      }
      if (key == m) key = ~0ull;
    }
  }
  __syncthreads();

  // ---- build XYZ [32][32] + CAT cols 64..191 ----
  for (int j = t; j < 352; j += 256){ int row = j/11, c = 10 + 2*(j%11); stH2(S, OFF2_XYZ, 1, row, c, 0u); }
  if (t < 32){
    int row = t, px = row >> 2, k = row & 3;
    int bn = bn0 + px, b = bn >> 14;
    float qx = xyz1[bn*3], qy = xyz1[bn*3+1], qz = xyz1[bn*3+2];
    float mk = selMask[px][k];
    const float* p = xyz1 + ((size_t)b*NPIX + selFlat[px][k])*3;
    float ax = p[0]*mk, ay = p[1]*mk, az = p[2]*mk;
    float dx = ax-qx, dy = ay-qy, dz = az-qz;
    float e = sqrtf(dx*dx + dy*dy + dz*dz + 1e-20f);
    float vals[10] = {qx, qy, qz, ax, ay, az, dx, dy, dz, e};
    #pragma unroll
    for (int c = 0; c < 5; ++c)
      stH2(S, OFF2_XYZ, 1, row, 2*c, pack2(vals[2*c], vals[2*c+1]));
  }
  {
    int px = t >> 5, ch = (t & 31) << 1;     // 256 tasks: pts1 float2
    int bn = bn0 + px;
    f32x2 v = *(const f32x2*)(pts1 + (size_t)bn*64 + ch);
    #pragma unroll
    for (int k = 0; k < 4; ++k){
      float mk = selMask[px][k];
      stH2(S, OFF2_CAT, 6, px*4 + k, 64 + ch, pack2(v.x*mk, v.y*mk));
    }
  }
  for (int j = t; j < 1024; j += 256){       // f1 gather float2
    int row = j >> 5, ch = (j & 31) << 1;
    int px = row >> 2, k = row & 3;
    int bn = bn0 + px, b = bn >> 14;
    f32x2 v = *(const f32x2*)(f1 + ((size_t)b*NPIX + selFlat[px][k])*64 + ch);
    float mk = selMask[px][k];
    stH2(S, OFF2_CAT, 6, row, 128 + ch, pack2(v.x*mk, v.y*mk));
  }
  __syncthreads();

  // ---- pcenc: 32 -> 64 relu, * mask -> cat cols 0..63 ----
  {
    f32x4 acc[2][1];
    acc[0][0] = (f32x4){0.f,0.f,0.f,0.f}; acc[1][0] = (f32x4){0.f,0.f,0.f,0.f};
    mfmaLayer<2,1,1>(S, OFF2_XYZ, wp, WB_PC, WS_PC, wv, l, acc);
    int colN = wv*16 + (l & 15);
    float bb = pcb[colN];
    #pragma unroll
    for (int mt = 0; mt < 2; ++mt)
      #pragma unroll
      for (int r = 0; r < 4; ++r){
        int row = mt*16 + ((l>>4)<<2) + r;
        int px = row >> 2, k = row & 3;
        stH(S, OFF2_CAT, 6, row, colN, f2h_(fmaxf(acc[mt][0][r] + bb, 0.f) * selMask[px][k]));
      }
    __syncthreads();
  }

  // ---- m2n1: 192 -> 128 relu -> a1 ----
  {
    f32x4 acc[2][2];
    #pragma unroll
    for (int mt = 0; mt < 2; ++mt)
      #pragma unroll
      for (int j = 0; j < 2; ++j) acc[mt][j] = (f32x4){0.f,0.f,0.f,0.f};
    mfmaLayer<2,6,2>(S, OFF2_CAT, wp, WB_N0, WS_N0, wv, l, acc);
    #pragma unroll
    for (int j = 0; j < 2; ++j){
      int colN = (wv*2 + j)*16 + (l & 15);
      float bias = n0b[colN];
      #pragma unroll
      for (int mt = 0; mt < 2; ++mt)
        #pragma unroll
        for (int r = 0; r < 4; ++r){
          int row = mt*16 + ((l>>4)<<2) + r;
          stH(S, OFF2_A1, 4, row, colN, f2h_(fmaxf(acc[mt][j][r] + bias, 0.f)));
        }
    }
    __syncthreads();
  }

  // ---- m2n2: 128 -> 64 relu -> att fp32 (aliases a1) ----
  {
    f32x4 acc[2][1];
    acc[0][0] = (f32x4){0.f,0.f,0.f,0.f}; acc[1][0] = (f32x4){0.f,0.f,0.f,0.f};
    mfmaLayer<2,4,1>(S, OFF2_A1, wp, WB_N1, WS_N1, wv, l, acc);
    __syncthreads();                        // all a1 reads done before overwrite
    int colN = wv*16 + (l & 15);
    float bb = n1b[colN];
    #pragma unroll
    for (int mt = 0; mt < 2; ++mt)
      #pragma unroll
      for (int r = 0; r < 4; ++r){
        int row = mt*16 + ((l>>4)<<2) + r;
        *(float*)(S + OFF2_A1 + (row*64 + colN)*4) = fmaxf(acc[mt][0][r] + bb, 0.f);
      }
    __syncthreads();
  }

  // ---- masked softmax over K=4 + weighted sum ----
  for (int j = t; j < 512; j += 256){
    int px = j >> 6, ch = j & 63; int bn = bn0 + px;
    float vv[4], gg[4];
    #pragma unroll
    for (int k = 0; k < 4; ++k){
      int row = px*4 + k;
      float a = *(const float*)(S + OFF2_A1 + (row*64 + ch)*4);
      vv[k] = (selMask[px][k] > 0.5f) ? a : -1e10f;
      gg[k] = h2f_(*(const u16*)(S + OFF2_CAT + fragByte(6, row, 128 + ch)));
    }
    float mx = fmaxf(fmaxf(vv[0], vv[1]), fmaxf(vv[2], vv[3]));
    float s = 0.f, ws = 0.f;
    #pragma unroll
    for (int k = 0; k < 4; ++k){
      float e = expf(vv[k] - mx);
      s += e; ws = fmaf(e, gg[k], ws);
    }
    out[(size_t)bn*64 + ch] = ws / s;
  }
}

extern "C" void kernel_launch(void* const* d_in, const int* in_sizes, int n_in,
                              void* d_out, int out_size, void* d_ws, size_t ws_size,
                              hipStream_t stream) {
    const float* xyz1 = (const float*)d_in[0];
    const float* xyz2 = (const float*)d_in[1];
    const float* pts1 = (const float*)d_in[2];
    const float* pts2 = (const float*)d_in[3];
    const float* m1w0 = (const float*)d_in[4];
    const float* m1b0 = (const float*)d_in[5];
    const float* m1w1 = (const float*)d_in[6];
    const float* m1b1 = (const float*)d_in[7];
    const float* m1w2 = (const float*)d_in[8];
    const float* m1b2 = (const float*)d_in[9];
    const float* piw  = (const float*)d_in[10];
    const float* pib  = (const float*)d_in[11];
    const float* m2w0 = (const float*)d_in[12];
    const float* m2b0 = (const float*)d_in[13];
    const float* m2w1 = (const float*)d_in[14];
    const float* m2b1 = (const float*)d_in[15];
    const float* pcw  = (const float*)d_in[16];
    const float* pcb  = (const float*)d_in[17];
    const float* n0w  = (const float*)d_in[18];
    const float* n0b  = (const float*)d_in[19];
    const float* n1w  = (const float*)d_in[20];
    const float* n1b  = (const float*)d_in[21];

    const int B = in_sizes[0] / (NPIX * 3);
    u16*   wplanes = (u16*)d_ws;
    float* f1      = (float*)((char*)d_ws + F1_OFFSET);
    float* out     = (float*)d_out;

    hipLaunchKernelGGL(prep_weights, dim3(46), dim3(256), 0, stream,
                       m1w0, m1w1, m1w2, piw, m2w0, m2w1, pcw, n0w, n1w, wplanes);
    hipLaunchKernelGGL(stage1_mfma, dim3((B*NPIX)/8), dim3(256), 0, stream,
                       xyz1, xyz2, pts1, pts2,
                       m1b0, m1b1, m1b2, pib, m2b0, m2b1,
                       wplanes, f1);
    hipLaunchKernelGGL(stage2_mfma, dim3((B*NPIX)/8), dim3(256), 0, stream,
                       xyz1, pts1, f1, pcb, n0b, n1b,
                       wplanes, out);
}

// Round 7
// 307.277 us; speedup vs baseline: 8.2855x; 1.1362x over previous
//
#include <hip/hip_runtime.h>
#include <math.h>

#define HH 64
#define WW 256
#define NPIX (HH*WW)

typedef unsigned short u16;
typedef __attribute__((ext_vector_type(8))) short s16x8;
typedef __attribute__((ext_vector_type(8))) _Float16 h16x8;
typedef __attribute__((ext_vector_type(2))) __fp16 fp16x2;
typedef __attribute__((ext_vector_type(4))) float f32x4;
typedef __attribute__((ext_vector_type(2))) float f32x2;
typedef __attribute__((ext_vector_type(2))) unsigned u32x2;

// ---------------- f16 helpers ----------------
__device__ __forceinline__ u16 f2h_(float x){
  union { _Float16 h; u16 u; } v; v.h = (_Float16)x; return v.u;   // RTN
}
__device__ __forceinline__ float h2f_(u16 b){
  union { u16 u; _Float16 h; } v; v.u = b; return (float)v.h;
}
__device__ __forceinline__ unsigned pack2(float a, float b){        // RTZ, 1 instr
  union { fp16x2 h; unsigned u; } v; v.h = __builtin_amdgcn_cvt_pkrtz(a, b); return v.u;
}
__device__ __forceinline__ void splith(float x, u16& h, u16& l){    // RTN split (weights)
  h = f2h_(x); l = f2h_(x - h2f_(h));
}

// A-fragment LDS layout with bank swizzle: intra-tile frag = ((row&15)^kg) | (kg<<4), kg=(kcol>>3)&3
__device__ __forceinline__ int fragByte(int KS, int row, int kcol){
  int kg = (kcol >> 3) & 3;
  int frag = ((row >> 4) * KS + (kcol >> 5)) * 64 + (((row & 15) ^ kg) | (kg << 4));
  return frag * 16 + ((kcol & 7) << 1);
}
__device__ __forceinline__ void stH(char* S, int off, int KS, int row, int kcol, u16 v){
  *(u16*)(S + off + fragByte(KS, row, kcol)) = v;
}
__device__ __forceinline__ void stH2(char* S, int off, int KS, int row, int kcol, unsigned v2){
  *(unsigned*)(S + off + fragByte(KS, row, kcol)) = v2;   // kcol even
}
__device__ __forceinline__ void stH4(char* S, int off, int KS, int row, int kcol, unsigned a, unsigned b){
  *(u32x2*)(S + off + fragByte(KS, row, kcol)) = (u32x2){a, b};   // kcol % 4 == 0
}
__device__ __forceinline__ h16x8 ldWf(const u16* wp, int base, int KS, int nt, int ks, int l){
  return *(const h16x8*)(wp + base + (size_t)((nt * KS + ks) * 64 + l) * 8);
}

// weight-plane bases (u16 elems) in d_ws
#define WB_W0 0
#define WS_W0 20480
#define WB_W1 40960
#define WS_W1 8192
#define WB_W2 57344
#define WS_W2 4096
#define WB_PW 65536
#define WS_PW 2048
#define WB_Q0 69632
#define WS_Q0 16384
#define WB_Q1 102400
#define WS_Q1 8192
#define WB_PC 118784
#define WS_PC 2048
#define WB_N0 122880
#define WS_N0 24576
#define WB_N1 172032
#define WS_N1 8192
#define F1_OFFSET (512*1024)

// 2-term split-precision MFMA layer; KSL = weight ksteps (loop), KSTR = A-tile kstep stride
template<int MT, int KSL, int KSTR, int NTW>
__device__ __forceinline__ void mfmaLayer(const char* S, int offA,
                                          const u16* wp, int wbase, int wsz,
                                          int wv, int lswz, int l, f32x4 (&acc)[MT][NTW])
{
  #pragma unroll
  for (int ks = 0; ks < KSL; ++ks){
    h16x8 bh[NTW], bl[NTW];
    #pragma unroll
    for (int j = 0; j < NTW; ++j){
      int nt = wv * NTW + j;
      bh[j] = ldWf(wp, wbase,       KSL, nt, ks, l);
      bl[j] = ldWf(wp, wbase + wsz, KSL, nt, ks, l);
    }
    #pragma unroll
    for (int mt = 0; mt < MT; ++mt){
      h16x8 a = *(const h16x8*)(S + offA + ((mt * KSTR + ks) * 64 + lswz) * 16);
      #pragma unroll
      for (int j = 0; j < NTW; ++j){
        acc[mt][j] = __builtin_amdgcn_mfma_f32_16x16x32_f16(a, bh[j], acc[mt][j], 0, 0, 0);
        acc[mt][j] = __builtin_amdgcn_mfma_f32_16x16x32_f16(a, bl[j], acc[mt][j], 0, 0, 0);
      }
    }
  }
}

// ---------------- weight prep: fp32 -> B-fragment hi/lo f16 planes ----------------
__global__ __launch_bounds__(256)
void prep_weights(const float* __restrict__ w0, const float* __restrict__ w1,
                  const float* __restrict__ w2, const float* __restrict__ pw,
                  const float* __restrict__ q0, const float* __restrict__ q1,
                  const float* __restrict__ pcw, const float* __restrict__ n0,
                  const float* __restrict__ n1, u16* __restrict__ wp)
{
  int id = blockIdx.x * 256 + threadIdx.x;
  const float* src; int Kdim, KS, N, base, sz, tau;
  if      (id <  2560){ src=w0;  Kdim=138; KS=5; N=128; base=WB_W0; sz=WS_W0; tau=id;        }
  else if (id <  3584){ src=w1;  Kdim=128; KS=4; N=64;  base=WB_W1; sz=WS_W1; tau=id-2560;   }
  else if (id <  4096){ src=w2;  Kdim=64;  KS=2; N=64;  base=WB_W2; sz=WS_W2; tau=id-3584;   }
  else if (id <  4352){ src=pw;  Kdim=10;  KS=1; N=64;  base=WB_PW; sz=WS_PW; tau=id-4096;   }
  else if (id <  6400){ src=q0;  Kdim=128; KS=4; N=128; base=WB_Q0; sz=WS_Q0; tau=id-4352;   }
  else if (id <  7424){ src=q1;  Kdim=128; KS=4; N=64;  base=WB_Q1; sz=WS_Q1; tau=id-6400;   }
  else if (id <  7680){ src=pcw; Kdim=10;  KS=1; N=64;  base=WB_PC; sz=WS_PC; tau=id-7424;   }
  else if (id < 10752){ src=n0;  Kdim=192; KS=6; N=128; base=WB_N0; sz=WS_N0; tau=id-7680;   }
  else if (id < 11776){ src=n1;  Kdim=128; KS=4; N=64;  base=WB_N1; sz=WS_N1; tau=id-10752;  }
  else return;
  int nt = tau / (KS * 64); int rem = tau % (KS * 64); int ks = rem >> 6; int l = rem & 63;
  s16x8 vh, vl;
  #pragma unroll
  for (int i = 0; i < 8; ++i){
    int k = ks * 32 + ((l >> 4) << 3) + i;
    int n = nt * 16 + (l & 15);
    float v = (k < Kdim) ? src[(size_t)k * N + n] : 0.0f;
    u16 h, lo; splith(v, h, lo);
    vh[i] = (short)h; vl[i] = (short)lo;
  }
  *(s16x8*)(wp + base + (size_t)tau * 8) = vh;
  *(s16x8*)(wp + base + sz + (size_t)tau * 8) = vl;
}

#define ATTS 66   // fp32 att tile row stride (floats), breaks bank periodicity

// ---------------- stage 1: 8 px/block, 48 rows = 3 mtiles, 256 threads ----------------
// OFF_A (15360B): A0 K160 -> A1 K128 -> h2 K64 -> a1 K128 -> att fp32 [48][ATTS]
#define OFF_A    0
#define OFF_CAT  15360   // K=128: 12288B (enc cols0-63, feat cols64-127)
#define SM1_TOT  27648

__global__ __launch_bounds__(256)
void stage1_mfma(const float* __restrict__ xyz1, const float* __restrict__ xyz2,
                 const float* __restrict__ pts1, const float* __restrict__ pts2,
                 const float* __restrict__ b0, const float* __restrict__ b1,
                 const float* __restrict__ b2, const float* __restrict__ pb,
                 const float* __restrict__ q0b, const float* __restrict__ q1b,
                 const u16* __restrict__ wp, float* __restrict__ f1out)
{
  __shared__ __align__(16) char S[SM1_TOT];
  __shared__ int   selFlat[8][6];
  __shared__ float selMask[8][6];

  const int t = threadIdx.x, wv = t >> 6, l = t & 63;
  const int lswz = l ^ ((l >> 4) & 3);
  const int bn0 = blockIdx.x << 3;

  // ---- selection: half-wave per pixel (p = l>>5), 3 candidates/sublane, top-6 ----
  {
    const int p = l >> 5, sub = l & 31;
    const int pxl = (wv << 1) | p;
    const int bn = bn0 + pxl;
    const int b = bn >> 14, n = bn & 16383, h = n >> 8, w = n & 255;
    const float qx = xyz1[bn*3], qy = xyz1[bn*3+1], qz = xyz1[bn*3+2];
    unsigned long long key[3];
    #pragma unroll
    for (int i = 0; i < 3; ++i){
      int c = sub + (i << 5);
      unsigned long long kk = ~0ull;
      if (c < 75){
        int dh = c/15 - 2, dw = c%15 - 7;
        int ch = h + dh, cw = w + dw;
        bool inb = ((unsigned)ch < HH) && ((unsigned)cw < WW);
        unsigned hi = 0x7f800000u;
        if (inb){
          int fl = ch*WW + cw;
          const float* p2 = xyz2 + ((size_t)b*NPIX + fl)*3;
          float dx = p2[0]-qx, dy = p2[1]-qy, dz = p2[2]-qz;
          float d2 = dx*dx + dy*dy + dz*dz;
          if (d2 < 100.0f) hi = __float_as_uint(d2);
        }
        kk = ((unsigned long long)hi << 32) | (unsigned)c;
      }
      key[i] = kk;
    }
    for (int j = 0; j < 6; ++j){
      unsigned long long m = key[0] < key[1] ? key[0] : key[1];
      if (key[2] < m) m = key[2];
      #pragma unroll
      for (int off = 1; off < 32; off <<= 1){
        unsigned lo  = __shfl_xor((unsigned)m, off, 64);
        unsigned hi2 = __shfl_xor((unsigned)(m >> 32), off, 64);
        unsigned long long o = ((unsigned long long)hi2 << 32) | lo;
        if (o < m) m = o;
      }
      if (sub == 0){
        int c = (int)(m & 0xffffffffull);
        bool val = (unsigned)(m >> 32) < 0x7f800000u;
        int dh = c/15 - 2, dw = c%15 - 7;
        int cch = min(max(h+dh, 0), HH-1), ccw = min(max(w+dw, 0), WW-1);
        selFlat[pxl][j] = val ? (cch*WW + ccw) : 0;
        selMask[pxl][j] = val ? 1.0f : 0.0f;
      }
      if (key[0] == m) key[0] = ~0ull;
      if (key[1] == m) key[1] = ~0ull;
      if (key[2] == m) key[2] = ~0ull;
    }
  }
  __syncthreads();

  // ---- build A0 [48][160] (f16 frag layout; no XYZ tile — pienc reads A0 ks0) ----
  for (int j = t; j < 528; j += 256){ int row = j/11, c = 138 + 2*(j%11); stH2(S, OFF_A, 5, row, c, 0u); }
  if (t < 48){
    int row = t, px = row/6, k = row%6;
    int bn = bn0 + px, b = bn >> 14;
    float qx = xyz1[bn*3], qy = xyz1[bn*3+1], qz = xyz1[bn*3+2];
    float mk = selMask[px][k];
    const float* p = xyz2 + ((size_t)b*NPIX + selFlat[px][k])*3;
    float ax = p[0]*mk, ay = p[1]*mk, az = p[2]*mk;
    float dx = ax-qx, dy = ay-qy, dz = az-qz;
    float e = sqrtf(dx*dx + dy*dy + dz*dz + 1e-20f);
    stH4(S, OFF_A, 5, row, 0, pack2(qx,qy), pack2(qz,ax));
    stH4(S, OFF_A, 5, row, 4, pack2(ay,az), pack2(dx,dy));
    stH2(S, OFF_A, 5, row, 8, pack2(dz,e));
  }
  {
    int px = t >> 5, ch = (t & 31) << 1;     // pts1 cols 10..73
    int bn = bn0 + px;
    f32x2 v = *(const f32x2*)(pts1 + (size_t)bn*64 + ch);
    unsigned pk = pack2(v.x, v.y);
    #pragma unroll
    for (int k = 0; k < 6; ++k) stH2(S, OFF_A, 5, px*6 + k, 10 + ch, pk);
  }
  for (int j = t; j < 768; j += 256){        // pts2 gather cols 74..137 (float4 loads)
    int row = j >> 4, ch = (j & 15) << 2;
    int px = row/6, k = row%6;
    int b = (bn0 + px) >> 14;
    f32x4 v = *(const f32x4*)(pts2 + ((size_t)b*NPIX + selFlat[px][k])*64 + ch);
    float mk = selMask[px][k];
    stH2(S, OFF_A, 5, row, 74 + ch, pack2(v.x*mk, v.y*mk));
    stH2(S, OFF_A, 5, row, 76 + ch, pack2(v.z*mk, v.w*mk));
  }
  __syncthreads();

  // ---- L1: 160 -> 128 relu -> A1  +  pienc: A0 ks0 -> 64 relu -> enc (CAT 0..63) ----
  {
    f32x4 acc[3][2], ae[3][1];
    #pragma unroll
    for (int mt = 0; mt < 3; ++mt){
      acc[mt][0] = (f32x4){0.f,0.f,0.f,0.f}; acc[mt][1] = (f32x4){0.f,0.f,0.f,0.f};
      ae[mt][0]  = (f32x4){0.f,0.f,0.f,0.f};
    }
    mfmaLayer<3,5,5,2>(S, OFF_A, wp, WB_W0, WS_W0, wv, lswz, l, acc);
    mfmaLayer<3,1,5,1>(S, OFF_A, wp, WB_PW, WS_PW, wv, lswz, l, ae);
    {
      int colN = wv*16 + (l & 15);
      float be = pb[colN];
      #pragma unroll
      for (int mt = 0; mt < 3; ++mt)
        #pragma unroll
        for (int r = 0; r < 4; ++r){
          int row = mt*16 + ((l>>4)<<2) + r;
          stH(S, OFF_CAT, 4, row, colN, f2h_(fmaxf(ae[mt][0][r] + be, 0.f)));
        }
    }
    __syncthreads();   // all A0 reads complete
    #pragma unroll
    for (int j = 0; j < 2; ++j){
      int colN = (wv*2 + j)*16 + (l & 15);
      float bias = b0[colN];
      #pragma unroll
      for (int mt = 0; mt < 3; ++mt)
        #pragma unroll
        for (int r = 0; r < 4; ++r){
          int row = mt*16 + ((l>>4)<<2) + r;
          stH(S, OFF_A, 4, row, colN, f2h_(fmaxf(acc[mt][j][r] + bias, 0.f)));
        }
    }
    __syncthreads();
  }

  // ---- L2: 128 -> 64 relu -> h2 ----
  {
    f32x4 acc[3][1];
    #pragma unroll
    for (int mt = 0; mt < 3; ++mt) acc[mt][0] = (f32x4){0.f,0.f,0.f,0.f};
    mfmaLayer<3,4,4,1>(S, OFF_A, wp, WB_W1, WS_W1, wv, lswz, l, acc);
    __syncthreads();   // A1 reads done
    int colN = wv*16 + (l & 15);
    float bb = b1[colN];
    #pragma unroll
    for (int mt = 0; mt < 3; ++mt)
      #pragma unroll
      for (int r = 0; r < 4; ++r){
        int row = mt*16 + ((l>>4)<<2) + r;
        stH(S, OFF_A, 2, row, colN, f2h_(fmaxf(acc[mt][0][r] + bb, 0.f)));
      }
    __syncthreads();
  }

  // ---- L3: 64 -> 64 relu -> feat (CAT cols 64..127) ----
  {
    f32x4 acc[3][1];
    #pragma unroll
    for (int mt = 0; mt < 3; ++mt) acc[mt][0] = (f32x4){0.f,0.f,0.f,0.f};
    mfmaLayer<3,2,2,1>(S, OFF_A, wp, WB_W2, WS_W2, wv, lswz, l, acc);
    int colN = wv*16 + (l & 15);
    float bb = b2[colN];
    #pragma unroll
    for (int mt = 0; mt < 3; ++mt)
      #pragma unroll
      for (int r = 0; r < 4; ++r){
        int row = mt*16 + ((l>>4)<<2) + r;
        stH(S, OFF_CAT, 4, row, 64 + colN, f2h_(fmaxf(acc[mt][0][r] + bb, 0.f)));
      }
    __syncthreads();   // h2 reads done + feat visible
  }

  // ---- m2c1: cat(128) -> 128 relu -> a1 (OFF_A) ----
  {
    f32x4 acc[3][2];
    #pragma unroll
    for (int mt = 0; mt < 3; ++mt){
      acc[mt][0] = (f32x4){0.f,0.f,0.f,0.f}; acc[mt][1] = (f32x4){0.f,0.f,0.f,0.f};
    }
    mfmaLayer<3,4,4,2>(S, OFF_CAT, wp, WB_Q0, WS_Q0, wv, lswz, l, acc);
    #pragma unroll
    for (int j = 0; j < 2; ++j){
      int colN = (wv*2 + j)*16 + (l & 15);
      float bias = q0b[colN];
      #pragma unroll
      for (int mt = 0; mt < 3; ++mt)
        #pragma unroll
        for (int r = 0; r < 4; ++r){
          int row = mt*16 + ((l>>4)<<2) + r;
          stH(S, OFF_A, 4, row, colN, f2h_(fmaxf(acc[mt][j][r] + bias, 0.f)));
        }
    }
    __syncthreads();
  }

  // ---- m2c2: 128 -> 64 relu -> att fp32 (aliases a1 region) ----
  {
    f32x4 acc[3][1];
    #pragma unroll
    for (int mt = 0; mt < 3; ++mt) acc[mt][0] = (f32x4){0.f,0.f,0.f,0.f};
    mfmaLayer<3,4,4,1>(S, OFF_A, wp, WB_Q1, WS_Q1, wv, lswz, l, acc);
    __syncthreads();   // a1 reads done
    int colN = wv*16 + (l & 15);
    float bb = q1b[colN];
    #pragma unroll
    for (int mt = 0; mt < 3; ++mt)
      #pragma unroll
      for (int r = 0; r < 4; ++r){
        int row = mt*16 + ((l>>4)<<2) + r;
        *(float*)(S + OFF_A + (row*ATTS + colN)*4) = fmaxf(acc[mt][0][r] + bb, 0.f);
      }
    __syncthreads();
  }

  // ---- masked softmax over K=6 + weighted sum ----
  for (int j = t; j < 512; j += 256){
    int px = j >> 6, ch = j & 63; int bn = bn0 + px;
    float vv[6], ff[6];
    #pragma unroll
    for (int k = 0; k < 6; ++k){
      int row = px*6 + k;
      float a = *(const float*)(S + OFF_A + (row*ATTS + ch)*4);
      vv[k] = (selMask[px][k] > 0.5f) ? a : -1e10f;
      ff[k] = h2f_(*(const u16*)(S + OFF_CAT + fragByte(4, row, 64 + ch)));
    }
    float mx = vv[0];
    #pragma unroll
    for (int k = 1; k < 6; ++k) mx = fmaxf(mx, vv[k]);
    float s = 0.f, ws = 0.f;
    #pragma unroll
    for (int k = 0; k < 6; ++k){
      float e = expf(vv[k] - mx);
      s += e; ws = fmaf(e, ff[k], ws);
    }
    f1out[(size_t)bn*64 + ch] = ws / s;
  }
}

// ---------------- stage 2: 8 px/block, 32 rows = 2 mtiles, 256 threads ----------------
#define OFF2_CAT 0       // K=192: 12288B
#define OFF2_XYZ 12288   // K=32: 2048B
#define OFF2_A1  14336   // a1 K=128: 8192B; aliases att fp32 [32][ATTS] (8448B)
#define SM2_TOT  22784

__global__ __launch_bounds__(256)
void stage2_mfma(const float* __restrict__ xyz1, const float* __restrict__ pts1,
                 const float* __restrict__ f1,
                 const float* __restrict__ pcb, const float* __restrict__ n0b,
                 const float* __restrict__ n1b,
                 const u16* __restrict__ wp, float* __restrict__ out)
{
  __shared__ __align__(16) char S[SM2_TOT];
  __shared__ int   selFlat[8][4];
  __shared__ float selMask[8][4];

  const int t = threadIdx.x, wv = t >> 6, l = t & 63;
  const int lswz = l ^ ((l >> 4) & 3);
  const int bn0 = blockIdx.x << 3;

  // ---- selection: half-wave per pixel, 3x3 window, top-4 ----
  {
    const int p = l >> 5, sub = l & 31;
    const int pxl = (wv << 1) | p;
    const int bn = bn0 + pxl;
    const int b = bn >> 14, n = bn & 16383, h = n >> 8, w = n & 255;
    const float qx = xyz1[bn*3], qy = xyz1[bn*3+1], qz = xyz1[bn*3+2];
    unsigned long long key = ~0ull;
    if (sub < 9){
      int dh = sub/3 - 1, dw = sub%3 - 1;
      int ch = h + dh, cw = w + dw;
      bool inb = ((unsigned)ch < HH) && ((unsigned)cw < WW);
      unsigned hi = 0x7f800000u;
      if (inb){
        int fl = ch*WW + cw;
        const float* p2 = xyz1 + ((size_t)b*NPIX + fl)*3;
        float dx = p2[0]-qx, dy = p2[1]-qy, dz = p2[2]-qz;
        float d2 = dx*dx + dy*dy + dz*dz;
        if (d2 < 10.0f) hi = __float_as_uint(d2);
      }
      key = ((unsigned long long)hi << 32) | (unsigned)sub;
    }
    for (int j = 0; j < 4; ++j){
      unsigned long long m = key;
      #pragma unroll
      for (int off = 1; off < 32; off <<= 1){
        unsigned lo  = __shfl_xor((unsigned)m, off, 64);
        unsigned hi2 = __shfl_xor((unsigned)(m >> 32), off, 64);
        unsigned long long o = ((unsigned long long)hi2 << 32) | lo;
        if (o < m) m = o;
      }
      if (sub == 0){
        int c = (int)(m & 0xffffffffull);
        bool val = (unsigned)(m >> 32) < 0x7f800000u;
        int dh = c/3 - 1, dw = c%3 - 1;
        int cch = min(max(h+dh, 0), HH-1), ccw = min(max(w+dw, 0), WW-1);
        selFlat[pxl][j] = val ? (cch*WW + ccw) : 0;
        selMask[pxl][j] = val ? 1.0f : 0.0f;
      }
      if (key == m) key = ~0ull;
    }
  }
  __syncthreads();

  // ---- build XYZ [32][32] + CAT cols 64..191 ----
  for (int j = t; j < 352; j += 256){ int row = j/11, c = 10 + 2*(j%11); stH2(S, OFF2_XYZ, 1, row, c, 0u); }
  if (t < 32){
    int row = t, px = row >> 2, k = row & 3;
    int bn = bn0 + px, b = bn >> 14;
    float qx = xyz1[bn*3], qy = xyz1[bn*3+1], qz = xyz1[bn*3+2];
    float mk = selMask[px][k];
    const float* p = xyz1 + ((size_t)b*NPIX + selFlat[px][k])*3;
    float ax = p[0]*mk, ay = p[1]*mk, az = p[2]*mk;
    float dx = ax-qx, dy = ay-qy, dz = az-qz;
    float e = sqrtf(dx*dx + dy*dy + dz*dz + 1e-20f);
    stH4(S, OFF2_XYZ, 1, row, 0, pack2(qx,qy), pack2(qz,ax));
    stH4(S, OFF2_XYZ, 1, row, 4, pack2(ay,az), pack2(dx,dy));
    stH2(S, OFF2_XYZ, 1, row, 8, pack2(dz,e));
  }
  if (t < 128){                              // pts1 -> CAT cols 64..127 (float4)
    int px = t >> 4, ch = (t & 15) << 2;
    int bn = bn0 + px;
    f32x4 v = *(const f32x4*)(pts1 + (size_t)bn*64 + ch);
    #pragma unroll
    for (int k = 0; k < 4; ++k){
      float mk = selMask[px][k];
      stH4(S, OFF2_CAT, 6, px*4 + k, 64 + ch, pack2(v.x*mk, v.y*mk), pack2(v.z*mk, v.w*mk));
    }
  }
  for (int j = t; j < 512; j += 256){        // f1 gather -> CAT cols 128..191 (float4)
    int row = j >> 4, ch = (j & 15) << 2;
    int px = row >> 2, k = row & 3;
    int b = (bn0 + px) >> 14;
    f32x4 v = *(const f32x4*)(f1 + ((size_t)b*NPIX + selFlat[px][k])*64 + ch);
    float mk = selMask[px][k];
    stH4(S, OFF2_CAT, 6, row, 128 + ch, pack2(v.x*mk, v.y*mk), pack2(v.z*mk, v.w*mk));
  }
  __syncthreads();

  // ---- pcenc: 32 -> 64 relu, * mask -> CAT cols 0..63 ----
  {
    f32x4 acc[2][1];
    acc[0][0] = (f32x4){0.f,0.f,0.f,0.f}; acc[1][0] = (f32x4){0.f,0.f,0.f,0.f};
    mfmaLayer<2,1,1,1>(S, OFF2_XYZ, wp, WB_PC, WS_PC, wv, lswz, l, acc);
    int colN = wv*16 + (l & 15);
    float bb = pcb[colN];
    #pragma unroll
    for (int mt = 0; mt < 2; ++mt)
      #pragma unroll
      for (int r = 0; r < 4; ++r){
        int row = mt*16 + ((l>>4)<<2) + r;
        int px = row >> 2, k = row & 3;
        stH(S, OFF2_CAT, 6, row, colN, f2h_(fmaxf(acc[mt][0][r] + bb, 0.f) * selMask[px][k]));
      }
    __syncthreads();
  }

  // ---- m2n1: 192 -> 128 relu -> a1 ----
  {
    f32x4 acc[2][2];
    #pragma unroll
    for (int mt = 0; mt < 2; ++mt){
      acc[mt][0] = (f32x4){0.f,0.f,0.f,0.f}; acc[mt][1] = (f32x4){0.f,0.f,0.f,0.f};
    }
    mfmaLayer<2,6,6,2>(S, OFF2_CAT, wp, WB_N0, WS_N0, wv, lswz, l, acc);
    #pragma unroll
    for (int j = 0; j < 2; ++j){
      int colN = (wv*2 + j)*16 + (l & 15);
      float bias = n0b[colN];
      #pragma unroll
      for (int mt = 0; mt < 2; ++mt)
        #pragma unroll
        for (int r = 0; r < 4; ++r){
          int row = mt*16 + ((l>>4)<<2) + r;
          stH(S, OFF2_A1, 4, row, colN, f2h_(fmaxf(acc[mt][j][r] + bias, 0.f)));
        }
    }
    __syncthreads();
  }

  // ---- m2n2: 128 -> 64 relu -> att fp32 (aliases a1) ----
  {
    f32x4 acc[2][1];
    acc[0][0] = (f32x4){0.f,0.f,0.f,0.f}; acc[1][0] = (f32x4){0.f,0.f,0.f,0.f};
    mfmaLayer<2,4,4,1>(S, OFF2_A1, wp, WB_N1, WS_N1, wv, lswz, l, acc);
    __syncthreads();   // a1 reads done
    int colN = wv*16 + (l & 15);
    float bb = n1b[colN];
    #pragma unroll
    for (int mt = 0; mt < 2; ++mt)
      #pragma unroll
      for (int r = 0; r < 4; ++r){
        int row = mt*16 + ((l>>4)<<2) + r;
        *(float*)(S + OFF2_A1 + (row*ATTS + colN)*4) = fmaxf(acc[mt][0][r] + bb, 0.f);
      }
    __syncthreads();
  }

  // ---- masked softmax over K=4 + weighted sum ----
  for (int j = t; j < 512; j += 256){
    int px = j >> 6, ch = j & 63; int bn = bn0 + px;
    float vv[4], gg[4];
    #pragma unroll
    for (int k = 0; k < 4; ++k){
      int row = px*4 + k;
      float a = *(const float*)(S + OFF2_A1 + (row*ATTS + ch)*4);
      vv[k] = (selMask[px][k] > 0.5f) ? a : -1e10f;
      gg[k] = h2f_(*(const u16*)(S + OFF2_CAT + fragByte(6, row, 128 + ch)));
    }
    float mx = fmaxf(fmaxf(vv[0], vv[1]), fmaxf(vv[2], vv[3]));
    float s = 0.f, ws = 0.f;
    #pragma unroll
    for (int k = 0; k < 4; ++k){
      float e = expf(vv[k] - mx);
      s += e; ws = fmaf(e, gg[k], ws);
    }
    out[(size_t)bn*64 + ch] = ws / s;
  }
}

extern "C" void kernel_launch(void* const* d_in, const int* in_sizes, int n_in,
                              void* d_out, int out_size, void* d_ws, size_t ws_size,
                              hipStream_t stream) {
    const float* xyz1 = (const float*)d_in[0];
    const float* xyz2 = (const float*)d_in[1];
    const float* pts1 = (const float*)d_in[2];
    const float* pts2 = (const float*)d_in[3];
    const float* m1w0 = (const float*)d_in[4];
    const float* m1b0 = (const float*)d_in[5];
    const float* m1w1 = (const float*)d_in[6];
    const float* m1b1 = (const float*)d_in[7];
    const float* m1w2 = (const float*)d_in[8];
    const float* m1b2 = (const float*)d_in[9];
    const float* piw  = (const float*)d_in[10];
    const float* pib  = (const float*)d_in[11];
    const float* m2w0 = (const float*)d_in[12];
    const float* m2b0 = (const float*)d_in[13];
    const float* m2w1 = (const float*)d_in[14];
    const float* m2b1 = (const float*)d_in[15];
    const float* pcw  = (const float*)d_in[16];
    const float* pcb  = (const float*)d_in[17];
    const float* n0w  = (const float*)d_in[18];
    const float* n0b  = (const float*)d_in[19];
    const float* n1w  = (const float*)d_in[20];
    const float* n1b  = (const float*)d_in[21];

    const int B = in_sizes[0] / (NPIX * 3);
    u16*   wplanes = (u16*)d_ws;
    float* f1      = (float*)((char*)d_ws + F1_OFFSET);
    float* out     = (float*)d_out;

    hipLaunchKernelGGL(prep_weights, dim3(46), dim3(256), 0, stream,
                       m1w0, m1w1, m1w2, piw, m2w0, m2w1, pcw, n0w, n1w, wplanes);
    hipLaunchKernelGGL(stage1_mfma, dim3((B*NPIX)/8), dim3(256), 0, stream,
                       xyz1, xyz2, pts1, pts2,
                       m1b0, m1b1, m1b2, pib, m2b0, m2b1,
                       wplanes, f1);
    hipLaunchKernelGGL(stage2_mfma, dim3((B*NPIX)/8), dim3(256), 0, stream,
                       xyz1, pts1, f1, pcb, n0b, n1b,
                       wplanes, out);
}

// Round 8
// 298.897 us; speedup vs baseline: 8.5178x; 1.0280x over previous
//
#include <hip/hip_runtime.h>
#include <math.h>

#define HH 64
#define WW 256
#define NPIX (HH*WW)

typedef unsigned short u16;
typedef __attribute__((ext_vector_type(8))) short s16x8;
typedef __attribute__((ext_vector_type(8))) _Float16 h16x8;
typedef __attribute__((ext_vector_type(2))) __fp16 fp16x2;
typedef __attribute__((ext_vector_type(4))) float f32x4;
typedef __attribute__((ext_vector_type(2))) float f32x2;
typedef __attribute__((ext_vector_type(2))) unsigned u32x2;

// ---------------- f16 helpers ----------------
__device__ __forceinline__ u16 f2h_(float x){
  union { _Float16 h; u16 u; } v; v.h = (_Float16)x; return v.u;   // RTN
}
__device__ __forceinline__ float h2f_(u16 b){
  union { u16 u; _Float16 h; } v; v.u = b; return (float)v.h;
}
__device__ __forceinline__ unsigned pack2(float a, float b){        // RTZ, 1 instr
  union { fp16x2 h; unsigned u; } v; v.h = __builtin_amdgcn_cvt_pkrtz(a, b); return v.u;
}
__device__ __forceinline__ void splith(float x, u16& h, u16& l){    // RTN split (weights)
  h = f2h_(x); l = f2h_(x - h2f_(h));
}

// A-fragment LDS layout with bank swizzle: intra-tile frag = ((row&15)^kg) | (kg<<4), kg=(kcol>>3)&3
__device__ __forceinline__ int fragByte(int KS, int row, int kcol){
  int kg = (kcol >> 3) & 3;
  int frag = ((row >> 4) * KS + (kcol >> 5)) * 64 + (((row & 15) ^ kg) | (kg << 4));
  return frag * 16 + ((kcol & 7) << 1);
}
__device__ __forceinline__ void stH(char* S, int off, int KS, int row, int kcol, u16 v){
  *(u16*)(S + off + fragByte(KS, row, kcol)) = v;
}
__device__ __forceinline__ void stH2(char* S, int off, int KS, int row, int kcol, unsigned v2){
  *(unsigned*)(S + off + fragByte(KS, row, kcol)) = v2;   // kcol even
}
__device__ __forceinline__ void stH4(char* S, int off, int KS, int row, int kcol, unsigned a, unsigned b){
  *(u32x2*)(S + off + fragByte(KS, row, kcol)) = (u32x2){a, b};   // kcol % 4 == 0
}
// relu + packed-cvt epilogue for a row pair (row0, row0+1), same kcol
__device__ __forceinline__ void epiPair(char* S, int off, int KS, int row0, int kcol, float a0, float a1){
  unsigned pk = pack2(fmaxf(a0, 0.f), fmaxf(a1, 0.f));
  stH(S, off, KS, row0,     kcol, (u16)pk);
  stH(S, off, KS, row0 + 1, kcol, (u16)(pk >> 16));
}
__device__ __forceinline__ h16x8 ldWf(const u16* wp, int base, int KS, int nt, int ks, int l){
  return *(const h16x8*)(wp + base + (size_t)((nt * KS + ks) * 64 + l) * 8);
}

// weight-plane bases (u16 elems) in d_ws
#define WB_W0 0
#define WS_W0 20480
#define WB_W1 40960
#define WS_W1 8192
#define WB_W2 57344
#define WS_W2 4096
#define WB_PW 65536
#define WS_PW 2048
#define WB_Q0 69632
#define WS_Q0 16384
#define WB_Q1 102400
#define WS_Q1 8192
#define WB_PC 118784
#define WS_PC 2048
#define WB_N0 122880
#define WS_N0 24576
#define WB_N1 172032
#define WS_N1 8192
#define F1_OFFSET (512*1024)

// 2-term split-precision MFMA layer; KSL = weight ksteps (loop), KSTR = A-tile kstep stride
template<int MT, int KSL, int KSTR, int NTW>
__device__ __forceinline__ void mfmaLayer(const char* S, int offA,
                                          const u16* wp, int wbase, int wsz,
                                          int wv, int lswz, int l, f32x4 (&acc)[MT][NTW])
{
  #pragma unroll
  for (int ks = 0; ks < KSL; ++ks){
    h16x8 bh[NTW], bl[NTW];
    #pragma unroll
    for (int j = 0; j < NTW; ++j){
      int nt = wv * NTW + j;
      bh[j] = ldWf(wp, wbase,       KSL, nt, ks, l);
      bl[j] = ldWf(wp, wbase + wsz, KSL, nt, ks, l);
    }
    #pragma unroll
    for (int mt = 0; mt < MT; ++mt){
      h16x8 a = *(const h16x8*)(S + offA + ((mt * KSTR + ks) * 64 + lswz) * 16);
      #pragma unroll
      for (int j = 0; j < NTW; ++j){
        acc[mt][j] = __builtin_amdgcn_mfma_f32_16x16x32_f16(a, bh[j], acc[mt][j], 0, 0, 0);
        acc[mt][j] = __builtin_amdgcn_mfma_f32_16x16x32_f16(a, bl[j], acc[mt][j], 0, 0, 0);
      }
    }
  }
}

// ---------------- weight prep: fp32 -> B-fragment hi/lo f16 planes ----------------
__global__ __launch_bounds__(256)
void prep_weights(const float* __restrict__ w0, const float* __restrict__ w1,
                  const float* __restrict__ w2, const float* __restrict__ pw,
                  const float* __restrict__ q0, const float* __restrict__ q1,
                  const float* __restrict__ pcw, const float* __restrict__ n0,
                  const float* __restrict__ n1, u16* __restrict__ wp)
{
  int id = blockIdx.x * 256 + threadIdx.x;
  const float* src; int Kdim, KS, N, base, sz, tau;
  if      (id <  2560){ src=w0;  Kdim=138; KS=5; N=128; base=WB_W0; sz=WS_W0; tau=id;        }
  else if (id <  3584){ src=w1;  Kdim=128; KS=4; N=64;  base=WB_W1; sz=WS_W1; tau=id-2560;   }
  else if (id <  4096){ src=w2;  Kdim=64;  KS=2; N=64;  base=WB_W2; sz=WS_W2; tau=id-3584;   }
  else if (id <  4352){ src=pw;  Kdim=10;  KS=1; N=64;  base=WB_PW; sz=WS_PW; tau=id-4096;   }
  else if (id <  6400){ src=q0;  Kdim=128; KS=4; N=128; base=WB_Q0; sz=WS_Q0; tau=id-4352;   }
  else if (id <  7424){ src=q1;  Kdim=128; KS=4; N=64;  base=WB_Q1; sz=WS_Q1; tau=id-6400;   }
  else if (id <  7680){ src=pcw; Kdim=10;  KS=1; N=64;  base=WB_PC; sz=WS_PC; tau=id-7424;   }
  else if (id < 10752){ src=n0;  Kdim=192; KS=6; N=128; base=WB_N0; sz=WS_N0; tau=id-7680;   }
  else if (id < 11776){ src=n1;  Kdim=128; KS=4; N=64;  base=WB_N1; sz=WS_N1; tau=id-10752;  }
  else return;
  int nt = tau / (KS * 64); int rem = tau % (KS * 64); int ks = rem >> 6; int l = rem & 63;
  s16x8 vh, vl;
  #pragma unroll
  for (int i = 0; i < 8; ++i){
    int k = ks * 32 + ((l >> 4) << 3) + i;
    int n = nt * 16 + (l & 15);
    float v = (k < Kdim) ? src[(size_t)k * N + n] : 0.0f;
    u16 h, lo; splith(v, h, lo);
    vh[i] = (short)h; vl[i] = (short)lo;
  }
  *(s16x8*)(wp + base + (size_t)tau * 8) = vh;
  *(s16x8*)(wp + base + sz + (size_t)tau * 8) = vl;
}

#define ATTS 66   // fp32 att tile row stride (floats), breaks bank periodicity

// ---------------- stage 1: 8 px/block, 48 rows = 3 mtiles, 256 threads ----------------
// OFF_A (15360B): A0 K160 -> A1 K128 -> h2 K64 -> a1 K128 -> att fp32 [48][ATTS]
#define OFF_A    0
#define OFF_CAT  15360   // K=128: 12288B (enc cols0-63, feat cols64-127)
#define SM1_TOT  27648

__global__ __launch_bounds__(256)
void stage1_mfma(const float* __restrict__ xyz1, const float* __restrict__ xyz2,
                 const float* __restrict__ pts1, const float* __restrict__ pts2,
                 const float* __restrict__ b0, const float* __restrict__ b1,
                 const float* __restrict__ b2, const float* __restrict__ pb,
                 const float* __restrict__ q0b, const float* __restrict__ q1b,
                 const u16* __restrict__ wp, float* __restrict__ f1out)
{
  __shared__ __align__(16) char S[SM1_TOT];
  __shared__ int   selFlat[8][6];
  __shared__ float selMask[8][6];

  const int t = threadIdx.x, wv = t >> 6, l = t & 63;
  const int lswz = l ^ ((l >> 4) & 3);
  const int bn0 = blockIdx.x << 3;

  // ---- selection: half-wave per pixel (p = l>>5), 3 candidates/sublane, top-6 ----
  {
    const int p = l >> 5, sub = l & 31;
    const int pxl = (wv << 1) | p;
    const int bn = bn0 + pxl;
    const int b = bn >> 14, n = bn & 16383, h = n >> 8, w = n & 255;
    const float qx = xyz1[bn*3], qy = xyz1[bn*3+1], qz = xyz1[bn*3+2];
    unsigned long long key[3];
    #pragma unroll
    for (int i = 0; i < 3; ++i){
      int c = sub + (i << 5);
      unsigned long long kk = ~0ull;
      if (c < 75){
        int dh = c/15 - 2, dw = c%15 - 7;
        int ch = h + dh, cw = w + dw;
        bool inb = ((unsigned)ch < HH) && ((unsigned)cw < WW);
        unsigned hi = 0x7f800000u;
        if (inb){
          int fl = ch*WW + cw;
          const float* p2 = xyz2 + ((size_t)b*NPIX + fl)*3;
          float dx = p2[0]-qx, dy = p2[1]-qy, dz = p2[2]-qz;
          float d2 = dx*dx + dy*dy + dz*dz;
          if (d2 < 100.0f) hi = __float_as_uint(d2);
        }
        kk = ((unsigned long long)hi << 32) | (unsigned)c;
      }
      key[i] = kk;
    }
    for (int j = 0; j < 6; ++j){
      unsigned long long m = key[0] < key[1] ? key[0] : key[1];
      if (key[2] < m) m = key[2];
      #pragma unroll
      for (int off = 1; off < 32; off <<= 1){
        unsigned lo  = __shfl_xor((unsigned)m, off, 64);
        unsigned hi2 = __shfl_xor((unsigned)(m >> 32), off, 64);
        unsigned long long o = ((unsigned long long)hi2 << 32) | lo;
        if (o < m) m = o;
      }
      if (sub == 0){
        int c = (int)(m & 0xffffffffull);
        bool val = (unsigned)(m >> 32) < 0x7f800000u;
        int dh = c/15 - 2, dw = c%15 - 7;
        int cch = min(max(h+dh, 0), HH-1), ccw = min(max(w+dw, 0), WW-1);
        selFlat[pxl][j] = val ? (cch*WW + ccw) : 0;
        selMask[pxl][j] = val ? 1.0f : 0.0f;
      }
      unsigned midx = (unsigned)m;          // window index is unique -> 32-bit invalidation
      if ((unsigned)key[0] == midx) key[0] = ~0ull;
      if ((unsigned)key[1] == midx) key[1] = ~0ull;
      if ((unsigned)key[2] == midx) key[2] = ~0ull;
    }
  }
  __syncthreads();

  // ---- build A0 [48][160] (f16 frag layout; no XYZ tile — pienc reads A0 ks0) ----
  for (int j = t; j < 528; j += 256){ int row = j/11, c = 138 + 2*(j%11); stH2(S, OFF_A, 5, row, c, 0u); }
  if (t < 48){
    int row = t, px = row/6, k = row%6;
    int bn = bn0 + px, b = bn >> 14;
    float qx = xyz1[bn*3], qy = xyz1[bn*3+1], qz = xyz1[bn*3+2];
    float mk = selMask[px][k];
    const float* p = xyz2 + ((size_t)b*NPIX + selFlat[px][k])*3;
    float ax = p[0]*mk, ay = p[1]*mk, az = p[2]*mk;
    float dx = ax-qx, dy = ay-qy, dz = az-qz;
    float e = sqrtf(dx*dx + dy*dy + dz*dz + 1e-20f);
    stH4(S, OFF_A, 5, row, 0, pack2(qx,qy), pack2(qz,ax));
    stH4(S, OFF_A, 5, row, 4, pack2(ay,az), pack2(dx,dy));
    stH2(S, OFF_A, 5, row, 8, pack2(dz,e));
  }
  {
    int px = t >> 5, ch = (t & 31) << 1;     // pts1 cols 10..73
    int bn = bn0 + px;
    f32x2 v = *(const f32x2*)(pts1 + (size_t)bn*64 + ch);
    unsigned pk = pack2(v.x, v.y);
    #pragma unroll
    for (int k = 0; k < 6; ++k) stH2(S, OFF_A, 5, px*6 + k, 10 + ch, pk);
  }
  for (int j = t; j < 768; j += 256){        // pts2 gather cols 74..137 (float4 loads)
    int row = j >> 4, ch = (j & 15) << 2;
    int px = row/6, k = row%6;
    int b = (bn0 + px) >> 14;
    f32x4 v = *(const f32x4*)(pts2 + ((size_t)b*NPIX + selFlat[px][k])*64 + ch);
    float mk = selMask[px][k];
    stH2(S, OFF_A, 5, row, 74 + ch, pack2(v.x*mk, v.y*mk));
    stH2(S, OFF_A, 5, row, 76 + ch, pack2(v.z*mk, v.w*mk));
  }
  __syncthreads();

  // ---- L1: 160 -> 128 relu -> A1  +  pienc: A0 ks0 -> 64 relu -> enc (CAT 0..63) ----
  {
    const int colN0 = (wv*2)*16 + (l & 15), colN1 = (wv*2+1)*16 + (l & 15);
    const int colNe = wv*16 + (l & 15);
    const float bb0 = b0[colN0], bb1 = b0[colN1], be = pb[colNe];
    f32x4 acc[3][2], ae[3][1];
    #pragma unroll
    for (int mt = 0; mt < 3; ++mt){
      acc[mt][0] = (f32x4){bb0,bb0,bb0,bb0}; acc[mt][1] = (f32x4){bb1,bb1,bb1,bb1};
      ae[mt][0]  = (f32x4){be,be,be,be};
    }
    mfmaLayer<3,5,5,2>(S, OFF_A, wp, WB_W0, WS_W0, wv, lswz, l, acc);
    mfmaLayer<3,1,5,1>(S, OFF_A, wp, WB_PW, WS_PW, wv, lswz, l, ae);
    #pragma unroll
    for (int mt = 0; mt < 3; ++mt){
      int row = mt*16 + ((l>>4)<<2);
      epiPair(S, OFF_CAT, 4, row,   colNe, ae[mt][0][0], ae[mt][0][1]);
      epiPair(S, OFF_CAT, 4, row+2, colNe, ae[mt][0][2], ae[mt][0][3]);
    }
    __syncthreads();   // all A0 reads complete
    #pragma unroll
    for (int mt = 0; mt < 3; ++mt){
      int row = mt*16 + ((l>>4)<<2);
      epiPair(S, OFF_A, 4, row,   colN0, acc[mt][0][0], acc[mt][0][1]);
      epiPair(S, OFF_A, 4, row+2, colN0, acc[mt][0][2], acc[mt][0][3]);
      epiPair(S, OFF_A, 4, row,   colN1, acc[mt][1][0], acc[mt][1][1]);
      epiPair(S, OFF_A, 4, row+2, colN1, acc[mt][1][2], acc[mt][1][3]);
    }
    __syncthreads();
  }

  // ---- L2: 128 -> 64 relu -> h2 ----
  {
    const int colN = wv*16 + (l & 15);
    const float bb = b1[colN];
    f32x4 acc[3][1];
    #pragma unroll
    for (int mt = 0; mt < 3; ++mt) acc[mt][0] = (f32x4){bb,bb,bb,bb};
    mfmaLayer<3,4,4,1>(S, OFF_A, wp, WB_W1, WS_W1, wv, lswz, l, acc);
    __syncthreads();   // A1 reads done
    #pragma unroll
    for (int mt = 0; mt < 3; ++mt){
      int row = mt*16 + ((l>>4)<<2);
      epiPair(S, OFF_A, 2, row,   colN, acc[mt][0][0], acc[mt][0][1]);
      epiPair(S, OFF_A, 2, row+2, colN, acc[mt][0][2], acc[mt][0][3]);
    }
    __syncthreads();
  }

  // ---- L3: 64 -> 64 relu -> feat (CAT cols 64..127) ----
  {
    const int colN = wv*16 + (l & 15);
    const float bb = b2[colN];
    f32x4 acc[3][1];
    #pragma unroll
    for (int mt = 0; mt < 3; ++mt) acc[mt][0] = (f32x4){bb,bb,bb,bb};
    mfmaLayer<3,2,2,1>(S, OFF_A, wp, WB_W2, WS_W2, wv, lswz, l, acc);
    #pragma unroll
    for (int mt = 0; mt < 3; ++mt){
      int row = mt*16 + ((l>>4)<<2);
      epiPair(S, OFF_CAT, 4, row,   64 + colN, acc[mt][0][0], acc[mt][0][1]);
      epiPair(S, OFF_CAT, 4, row+2, 64 + colN, acc[mt][0][2], acc[mt][0][3]);
    }
    __syncthreads();   // h2 reads done + feat visible
  }

  // ---- m2c1: cat(128) -> 128 relu -> a1 (OFF_A) ----
  {
    const int colN0 = (wv*2)*16 + (l & 15), colN1 = (wv*2+1)*16 + (l & 15);
    const float bb0 = q0b[colN0], bb1 = q0b[colN1];
    f32x4 acc[3][2];
    #pragma unroll
    for (int mt = 0; mt < 3; ++mt){
      acc[mt][0] = (f32x4){bb0,bb0,bb0,bb0}; acc[mt][1] = (f32x4){bb1,bb1,bb1,bb1};
    }
    mfmaLayer<3,4,4,2>(S, OFF_CAT, wp, WB_Q0, WS_Q0, wv, lswz, l, acc);
    #pragma unroll
    for (int mt = 0; mt < 3; ++mt){
      int row = mt*16 + ((l>>4)<<2);
      epiPair(S, OFF_A, 4, row,   colN0, acc[mt][0][0], acc[mt][0][1]);
      epiPair(S, OFF_A, 4, row+2, colN0, acc[mt][0][2], acc[mt][0][3]);
      epiPair(S, OFF_A, 4, row,   colN1, acc[mt][1][0], acc[mt][1][1]);
      epiPair(S, OFF_A, 4, row+2, colN1, acc[mt][1][2], acc[mt][1][3]);
    }
    __syncthreads();
  }

  // ---- m2c2: 128 -> 64 relu -> att fp32 (aliases a1 region) ----
  {
    const int colN = wv*16 + (l & 15);
    const float bb = q1b[colN];
    f32x4 acc[3][1];
    #pragma unroll
    for (int mt = 0; mt < 3; ++mt) acc[mt][0] = (f32x4){bb,bb,bb,bb};
    mfmaLayer<3,4,4,1>(S, OFF_A, wp, WB_Q1, WS_Q1, wv, lswz, l, acc);
    __syncthreads();   // a1 reads done
    #pragma unroll
    for (int mt = 0; mt < 3; ++mt)
      #pragma unroll
      for (int r = 0; r < 4; ++r){
        int row = mt*16 + ((l>>4)<<2) + r;
        *(float*)(S + OFF_A + (row*ATTS + colN)*4) = fmaxf(acc[mt][0][r], 0.f);
      }
    __syncthreads();
  }

  // ---- masked softmax over K=6 + weighted sum ----
  for (int j = t; j < 512; j += 256){
    int px = j >> 6, ch = j & 63; int bn = bn0 + px;
    float vv[6], ff[6];
    #pragma unroll
    for (int k = 0; k < 6; ++k){
      int row = px*6 + k;
      float a = *(const float*)(S + OFF_A + (row*ATTS + ch)*4);
      vv[k] = (selMask[px][k] > 0.5f) ? a : -1e10f;
      ff[k] = h2f_(*(const u16*)(S + OFF_CAT + fragByte(4, row, 64 + ch)));
    }
    float mx = vv[0];
    #pragma unroll
    for (int k = 1; k < 6; ++k) mx = fmaxf(mx, vv[k]);
    float s = 0.f, ws = 0.f;
    #pragma unroll
    for (int k = 0; k < 6; ++k){
      float e = __expf(vv[k] - mx);
      s += e; ws = fmaf(e, ff[k], ws);
    }
    f1out[(size_t)bn*64 + ch] = __fdividef(ws, s);
  }
}

// ---------------- stage 2: 8 px/block, 32 rows = 2 mtiles, 256 threads ----------------
#define OFF2_CAT 0       // K=192: 12288B
#define OFF2_XYZ 12288   // K=32: 2048B
#define OFF2_A1  14336   // a1 K=128: 8192B; aliases att fp32 [32][ATTS] (8448B)
#define SM2_TOT  22784

__global__ __launch_bounds__(256)
void stage2_mfma(const float* __restrict__ xyz1, const float* __restrict__ pts1,
                 const float* __restrict__ f1,
                 const float* __restrict__ pcb, const float* __restrict__ n0b,
                 const float* __restrict__ n1b,
                 const u16* __restrict__ wp, float* __restrict__ out)
{
  __shared__ __align__(16) char S[SM2_TOT];
  __shared__ int   selFlat[8][4];
  __shared__ float selMask[8][4];

  const int t = threadIdx.x, wv = t >> 6, l = t & 63;
  const int lswz = l ^ ((l >> 4) & 3);
  const int bn0 = blockIdx.x << 3;

  // ---- selection: half-wave per pixel, 3x3 window, top-4 ----
  {
    const int p = l >> 5, sub = l & 31;
    const int pxl = (wv << 1) | p;
    const int bn = bn0 + pxl;
    const int b = bn >> 14, n = bn & 16383, h = n >> 8, w = n & 255;
    const float qx = xyz1[bn*3], qy = xyz1[bn*3+1], qz = xyz1[bn*3+2];
    unsigned long long key = ~0ull;
    if (sub < 9){
      int dh = sub/3 - 1, dw = sub%3 - 1;
      int ch = h + dh, cw = w + dw;
      bool inb = ((unsigned)ch < HH) && ((unsigned)cw < WW);
      unsigned hi = 0x7f800000u;
      if (inb){
        int fl = ch*WW + cw;
        const float* p2 = xyz1 + ((size_t)b*NPIX + fl)*3;
        float dx = p2[0]-qx, dy = p2[1]-qy, dz = p2[2]-qz;
        float d2 = dx*dx + dy*dy + dz*dz;
        if (d2 < 10.0f) hi = __float_as_uint(d2);
      }
      key = ((unsigned long long)hi << 32) | (unsigned)sub;
    }
    for (int j = 0; j < 4; ++j){
      unsigned long long m = key;
      #pragma unroll
      for (int off = 1; off < 32; off <<= 1){
        unsigned lo  = __shfl_xor((unsigned)m, off, 64);
        unsigned hi2 = __shfl_xor((unsigned)(m >> 32), off, 64);
        unsigned long long o = ((unsigned long long)hi2 << 32) | lo;
        if (o < m) m = o;
      }
      if (sub == 0){
        int c = (int)(m & 0xffffffffull);
        bool val = (unsigned)(m >> 32) < 0x7f800000u;
        int dh = c/3 - 1, dw = c%3 - 1;
        int cch = min(max(h+dh, 0), HH-1), ccw = min(max(w+dw, 0), WW-1);
        selFlat[pxl][j] = val ? (cch*WW + ccw) : 0;
        selMask[pxl][j] = val ? 1.0f : 0.0f;
      }
      if ((unsigned)key == (unsigned)m) key = ~0ull;
    }
  }
  __syncthreads();

  // ---- build XYZ [32][32] + CAT cols 64..191 ----
  for (int j = t; j < 352; j += 256){ int row = j/11, c = 10 + 2*(j%11); stH2(S, OFF2_XYZ, 1, row, c, 0u); }
  if (t < 32){
    int row = t, px = row >> 2, k = row & 3;
    int bn = bn0 + px, b = bn >> 14;
    float qx = xyz1[bn*3], qy = xyz1[bn*3+1], qz = xyz1[bn*3+2];
    float mk = selMask[px][k];
    const float* p = xyz1 + ((size_t)b*NPIX + selFlat[px][k])*3;
    float ax = p[0]*mk, ay = p[1]*mk, az = p[2]*mk;
    float dx = ax-qx, dy = ay-qy, dz = az-qz;
    float e = sqrtf(dx*dx + dy*dy + dz*dz + 1e-20f);
    stH4(S, OFF2_XYZ, 1, row, 0, pack2(qx,qy), pack2(qz,ax));
    stH4(S, OFF2_XYZ, 1, row, 4, pack2(ay,az), pack2(dx,dy));
    stH2(S, OFF2_XYZ, 1, row, 8, pack2(dz,e));
  }
  if (t < 128){                              // pts1 -> CAT cols 64..127 (float4)
    int px = t >> 4, ch = (t & 15) << 2;
    int bn = bn0 + px;
    f32x4 v = *(const f32x4*)(pts1 + (size_t)bn*64 + ch);
    #pragma unroll
    for (int k = 0; k < 4; ++k){
      float mk = selMask[px][k];
      stH4(S, OFF2_CAT, 6, px*4 + k, 64 + ch, pack2(v.x*mk, v.y*mk), pack2(v.z*mk, v.w*mk));
    }
  }
  for (int j = t; j < 512; j += 256){        // f1 gather -> CAT cols 128..191 (float4)
    int row = j >> 4, ch = (j & 15) << 2;
    int px = row >> 2, k = row & 3;
    int b = (bn0 + px) >> 14;
    f32x4 v = *(const f32x4*)(f1 + ((size_t)b*NPIX + selFlat[px][k])*64 + ch);
    float mk = selMask[px][k];
    stH4(S, OFF2_CAT, 6, row, 128 + ch, pack2(v.x*mk, v.y*mk), pack2(v.z*mk, v.w*mk));
  }
  __syncthreads();

  // ---- pcenc: 32 -> 64 relu, * mask -> CAT cols 0..63 ----
  {
    const int colN = wv*16 + (l & 15);
    const float bb = pcb[colN];
    f32x4 acc[2][1];
    acc[0][0] = (f32x4){bb,bb,bb,bb}; acc[1][0] = (f32x4){bb,bb,bb,bb};
    mfmaLayer<2,1,1,1>(S, OFF2_XYZ, wp, WB_PC, WS_PC, wv, lswz, l, acc);
    #pragma unroll
    for (int mt = 0; mt < 2; ++mt){
      int row = mt*16 + ((l>>4)<<2);
      float v0 = fmaxf(acc[mt][0][0], 0.f) * selMask[(row  )>>2][(row  )&3];
      float v1 = fmaxf(acc[mt][0][1], 0.f) * selMask[(row+1)>>2][(row+1)&3];
      float v2 = fmaxf(acc[mt][0][2], 0.f) * selMask[(row+2)>>2][(row+2)&3];
      float v3 = fmaxf(acc[mt][0][3], 0.f) * selMask[(row+3)>>2][(row+3)&3];
      unsigned pa = pack2(v0, v1), pb2 = pack2(v2, v3);
      stH(S, OFF2_CAT, 6, row,   colN, (u16)pa);
      stH(S, OFF2_CAT, 6, row+1, colN, (u16)(pa>>16));
      stH(S, OFF2_CAT, 6, row+2, colN, (u16)pb2);
      stH(S, OFF2_CAT, 6, row+3, colN, (u16)(pb2>>16));
    }
    __syncthreads();
  }

  // ---- m2n1: 192 -> 128 relu -> a1 ----
  {
    const int colN0 = (wv*2)*16 + (l & 15), colN1 = (wv*2+1)*16 + (l & 15);
    const float bb0 = n0b[colN0], bb1 = n0b[colN1];
    f32x4 acc[2][2];
    #pragma unroll
    for (int mt = 0; mt < 2; ++mt){
      acc[mt][0] = (f32x4){bb0,bb0,bb0,bb0}; acc[mt][1] = (f32x4){bb1,bb1,bb1,bb1};
    }
    mfmaLayer<2,6,6,2>(S, OFF2_CAT, wp, WB_N0, WS_N0, wv, lswz, l, acc);
    #pragma unroll
    for (int mt = 0; mt < 2; ++mt){
      int row = mt*16 + ((l>>4)<<2);
      epiPair(S, OFF2_A1, 4, row,   colN0, acc[mt][0][0], acc[mt][0][1]);
      epiPair(S, OFF2_A1, 4, row+2, colN0, acc[mt][0][2], acc[mt][0][3]);
      epiPair(S, OFF2_A1, 4, row,   colN1, acc[mt][1][0], acc[mt][1][1]);
      epiPair(S, OFF2_A1, 4, row+2, colN1, acc[mt][1][2], acc[mt][1][3]);
    }
    __syncthreads();
  }

  // ---- m2n2: 128 -> 64 relu -> att fp32 (aliases a1) ----
  {
    const int colN = wv*16 + (l & 15);
    const float bb = n1b[colN];
    f32x4 acc[2][1];
    acc[0][0] = (f32x4){bb,bb,bb,bb}; acc[1][0] = (f32x4){bb,bb,bb,bb};
    mfmaLayer<2,4,4,1>(S, OFF2_A1, wp, WB_N1, WS_N1, wv, lswz, l, acc);
    __syncthreads();   // a1 reads done
    #pragma unroll
    for (int mt = 0; mt < 2; ++mt)
      #pragma unroll
      for (int r = 0; r < 4; ++r){
        int row = mt*16 + ((l>>4)<<2) + r;
        *(float*)(S + OFF2_A1 + (row*ATTS + colN)*4) = fmaxf(acc[mt][0][r], 0.f);
      }
    __syncthreads();
  }

  // ---- masked softmax over K=4 + weighted sum ----
  for (int j = t; j < 512; j += 256){
    int px = j >> 6, ch = j & 63; int bn = bn0 + px;
    float vv[4], gg[4];
    #pragma unroll
    for (int k = 0; k < 4; ++k){
      int row = px*4 + k;
      float a = *(const float*)(S + OFF2_A1 + (row*ATTS + ch)*4);
      vv[k] = (selMask[px][k] > 0.5f) ? a : -1e10f;
      gg[k] = h2f_(*(const u16*)(S + OFF2_CAT + fragByte(6, row, 128 + ch)));
    }
    float mx = fmaxf(fmaxf(vv[0], vv[1]), fmaxf(vv[2], vv[3]));
    float s = 0.f, ws = 0.f;
    #pragma unroll
    for (int k = 0; k < 4; ++k){
      float e = __expf(vv[k] - mx);
      s += e; ws = fmaf(e, gg[k], ws);
    }
    out[(size_t)bn*64 + ch] = __fdividef(ws, s);
  }
}

extern "C" void kernel_launch(void* const* d_in, const int* in_sizes, int n_in,
                              void* d_out, int out_size, void* d_ws, size_t ws_size,
                              hipStream_t stream) {
    const float* xyz1 = (const float*)d_in[0];
    const float* xyz2 = (const float*)d_in[1];
    const float* pts1 = (const float*)d_in[2];
    const float* pts2 = (const float*)d_in[3];
    const float* m1w0 = (const float*)d_in[4];
    const float* m1b0 = (const float*)d_in[5];
    const float* m1w1 = (const float*)d_in[6];
    const float* m1b1 = (const float*)d_in[7];
    const float* m1w2 = (const float*)d_in[8];
    const float* m1b2 = (const float*)d_in[9];
    const float* piw  = (const float*)d_in[10];
    const float* pib  = (const float*)d_in[11];
    const float* m2w0 = (const float*)d_in[12];
    const float* m2b0 = (const float*)d_in[13];
    const float* m2w1 = (const float*)d_in[14];
    const float* m2b1 = (const float*)d_in[15];
    const float* pcw  = (const float*)d_in[16];
    const float* pcb  = (const float*)d_in[17];
    const float* n0w  = (const float*)d_in[18];
    const float* n0b  = (const float*)d_in[19];
    const float* n1w  = (const float*)d_in[20];
    const float* n1b  = (const float*)d_in[21];

    const int B = in_sizes[0] / (NPIX * 3);
    u16*   wplanes = (u16*)d_ws;
    float* f1      = (float*)((char*)d_ws + F1_OFFSET);
    float* out     = (float*)d_out;

    hipLaunchKernelGGL(prep_weights, dim3(46), dim3(256), 0, stream,
                       m1w0, m1w1, m1w2, piw, m2w0, m2w1, pcw, n0w, n1w, wplanes);
    hipLaunchKernelGGL(stage1_mfma, dim3((B*NPIX)/8), dim3(256), 0, stream,
                       xyz1, xyz2, pts1, pts2,
                       m1b0, m1b1, m1b2, pib, m2b0, m2b1,
                       wplanes, f1);
    hipLaunchKernelGGL(stage2_mfma, dim3((B*NPIX)/8), dim3(256), 0, stream,
                       xyz1, pts1, f1, pcb, n0b, n1b,
                       wplanes, out);
}

// Round 9
// 276.166 us; speedup vs baseline: 9.2189x; 1.0823x over previous
//
#include <hip/hip_runtime.h>
#include <math.h>

#define HH 64
#define WW 256
#define NPIX (HH*WW)

typedef unsigned short u16;
typedef __attribute__((ext_vector_type(8))) short s16x8;
typedef __attribute__((ext_vector_type(8))) _Float16 h16x8;
typedef __attribute__((ext_vector_type(2))) __fp16 fp16x2;
typedef __attribute__((ext_vector_type(4))) float f32x4;
typedef __attribute__((ext_vector_type(2))) float f32x2;
typedef __attribute__((ext_vector_type(2))) unsigned u32x2;

// ---------------- f16 helpers ----------------
__device__ __forceinline__ u16 f2h_(float x){
  union { _Float16 h; u16 u; } v; v.h = (_Float16)x; return v.u;   // RTN
}
__device__ __forceinline__ float h2f_(u16 b){
  union { u16 u; _Float16 h; } v; v.u = b; return (float)v.h;
}
__device__ __forceinline__ unsigned pack2(float a, float b){        // RTZ, 1 instr
  union { fp16x2 h; unsigned u; } v; v.h = __builtin_amdgcn_cvt_pkrtz(a, b); return v.u;
}

// A-fragment LDS layout with bank swizzle: intra-tile frag = ((row&15)^kg) | (kg<<4), kg=(kcol>>3)&3
__device__ __forceinline__ int fragByte(int KS, int row, int kcol){
  int kg = (kcol >> 3) & 3;
  int frag = ((row >> 4) * KS + (kcol >> 5)) * 64 + (((row & 15) ^ kg) | (kg << 4));
  return frag * 16 + ((kcol & 7) << 1);
}
__device__ __forceinline__ void stH(char* S, int off, int KS, int row, int kcol, u16 v){
  *(u16*)(S + off + fragByte(KS, row, kcol)) = v;
}
__device__ __forceinline__ void stH2(char* S, int off, int KS, int row, int kcol, unsigned v2){
  *(unsigned*)(S + off + fragByte(KS, row, kcol)) = v2;   // kcol even
}
__device__ __forceinline__ void stH4(char* S, int off, int KS, int row, int kcol, unsigned a, unsigned b){
  *(u32x2*)(S + off + fragByte(KS, row, kcol)) = (u32x2){a, b};   // kcol % 4 == 0
}
// relu + packed-cvt epilogue for a row pair (row0, row0+1), same kcol
__device__ __forceinline__ void epiPair(char* S, int off, int KS, int row0, int kcol, float a0, float a1){
  unsigned pk = pack2(fmaxf(a0, 0.f), fmaxf(a1, 0.f));
  stH(S, off, KS, row0,     kcol, (u16)pk);
  stH(S, off, KS, row0 + 1, kcol, (u16)(pk >> 16));
}
__device__ __forceinline__ h16x8 ldWf(const u16* wp, int base, int KS, int nt, int ks, int l){
  return *(const h16x8*)(wp + base + (size_t)((nt * KS + ks) * 64 + l) * 8);
}

// weight-plane bases (u16 elems) in d_ws (single f16 plane per layer)
#define WB_W0 0
#define WB_W1 20480
#define WB_W2 28672
#define WB_PW 32768
#define WB_Q0 34816
#define WB_Q1 51200
#define WB_PC 59392
#define WB_N0 61440
#define WB_N1 86016
#define F1_OFFSET (512*1024)

// single-plane f16 MFMA layer; KSL = weight ksteps (loop), KSTR = A-tile kstep stride
template<int MT, int KSL, int KSTR, int NTW>
__device__ __forceinline__ void mfmaLayer(const char* S, int offA,
                                          const u16* wp, int wbase,
                                          int wv, int lswz, int l, f32x4 (&acc)[MT][NTW])
{
  #pragma unroll
  for (int ks = 0; ks < KSL; ++ks){
    h16x8 bh[NTW];
    #pragma unroll
    for (int j = 0; j < NTW; ++j)
      bh[j] = ldWf(wp, wbase, KSL, wv * NTW + j, ks, l);
    #pragma unroll
    for (int mt = 0; mt < MT; ++mt){
      h16x8 a = *(const h16x8*)(S + offA + ((mt * KSTR + ks) * 64 + lswz) * 16);
      #pragma unroll
      for (int j = 0; j < NTW; ++j)
        acc[mt][j] = __builtin_amdgcn_mfma_f32_16x16x32_f16(a, bh[j], acc[mt][j], 0, 0, 0);
    }
  }
}

// ---------------- weight prep: fp32 -> B-fragment f16 plane ----------------
__global__ __launch_bounds__(256)
void prep_weights(const float* __restrict__ w0, const float* __restrict__ w1,
                  const float* __restrict__ w2, const float* __restrict__ pw,
                  const float* __restrict__ q0, const float* __restrict__ q1,
                  const float* __restrict__ pcw, const float* __restrict__ n0,
                  const float* __restrict__ n1, u16* __restrict__ wp)
{
  int id = blockIdx.x * 256 + threadIdx.x;
  const float* src; int Kdim, KS, N, base, tau;
  if      (id <  2560){ src=w0;  Kdim=138; KS=5; N=128; base=WB_W0; tau=id;        }
  else if (id <  3584){ src=w1;  Kdim=128; KS=4; N=64;  base=WB_W1; tau=id-2560;   }
  else if (id <  4096){ src=w2;  Kdim=64;  KS=2; N=64;  base=WB_W2; tau=id-3584;   }
  else if (id <  4352){ src=pw;  Kdim=10;  KS=1; N=64;  base=WB_PW; tau=id-4096;   }
  else if (id <  6400){ src=q0;  Kdim=128; KS=4; N=128; base=WB_Q0; tau=id-4352;   }
  else if (id <  7424){ src=q1;  Kdim=128; KS=4; N=64;  base=WB_Q1; tau=id-6400;   }
  else if (id <  7680){ src=pcw; Kdim=10;  KS=1; N=64;  base=WB_PC; tau=id-7424;   }
  else if (id < 10752){ src=n0;  Kdim=192; KS=6; N=128; base=WB_N0; tau=id-7680;   }
  else if (id < 11776){ src=n1;  Kdim=128; KS=4; N=64;  base=WB_N1; tau=id-10752;  }
  else return;
  int nt = tau / (KS * 64); int rem = tau % (KS * 64); int ks = rem >> 6; int l = rem & 63;
  s16x8 vh;
  #pragma unroll
  for (int i = 0; i < 8; ++i){
    int k = ks * 32 + ((l >> 4) << 3) + i;
    int n = nt * 16 + (l & 15);
    float v = (k < Kdim) ? src[(size_t)k * N + n] : 0.0f;
    vh[i] = (short)f2h_(v);
  }
  *(s16x8*)(wp + base + (size_t)tau * 8) = vh;
}

#define ATTS 66   // fp32 att tile row stride (floats), breaks bank periodicity

// ---------------- stage 1: 8 px/block, 48 rows = 3 mtiles, 256 threads ----------------
// OFF_A (15360B): A0 K160 -> A1 K128 -> h2 K64 -> a1 K128 -> att fp32 [48][ATTS]
#define OFF_A    0
#define OFF_CAT  15360   // K=128: 12288B (enc cols0-63, feat cols64-127)
#define SM1_TOT  27648

__global__ __launch_bounds__(256)
void stage1_mfma(const float* __restrict__ xyz1, const float* __restrict__ xyz2,
                 const float* __restrict__ pts1, const float* __restrict__ pts2,
                 const float* __restrict__ b0, const float* __restrict__ b1,
                 const float* __restrict__ b2, const float* __restrict__ pb,
                 const float* __restrict__ q0b, const float* __restrict__ q1b,
                 const u16* __restrict__ wp, float* __restrict__ f1out)
{
  __shared__ __align__(16) char S[SM1_TOT];
  __shared__ int   selFlat[8][6];
  __shared__ float selMask[8][6];

  const int t = threadIdx.x, wv = t >> 6, l = t & 63;
  const int lswz = l ^ ((l >> 4) & 3);
  const int bn0 = blockIdx.x << 3;

  // ---- selection: half-wave per pixel (p = l>>5), 3 candidates/sublane, top-6 ----
  {
    const int p = l >> 5, sub = l & 31;
    const int pxl = (wv << 1) | p;
    const int bn = bn0 + pxl;
    const int b = bn >> 14, n = bn & 16383, h = n >> 8, w = n & 255;
    const float qx = xyz1[bn*3], qy = xyz1[bn*3+1], qz = xyz1[bn*3+2];
    unsigned long long key[3];
    #pragma unroll
    for (int i = 0; i < 3; ++i){
      int c = sub + (i << 5);
      unsigned long long kk = ~0ull;
      if (c < 75){
        int dh = c/15 - 2, dw = c%15 - 7;
        int ch = h + dh, cw = w + dw;
        bool inb = ((unsigned)ch < HH) && ((unsigned)cw < WW);
        unsigned hi = 0x7f800000u;
        if (inb){
          int fl = ch*WW + cw;
          const float* p2 = xyz2 + ((size_t)b*NPIX + fl)*3;
          float dx = p2[0]-qx, dy = p2[1]-qy, dz = p2[2]-qz;
          float d2 = dx*dx + dy*dy + dz*dz;
          if (d2 < 100.0f) hi = __float_as_uint(d2);
        }
        kk = ((unsigned long long)hi << 32) | (unsigned)c;
      }
      key[i] = kk;
    }
    for (int j = 0; j < 6; ++j){
      unsigned long long m = key[0] < key[1] ? key[0] : key[1];
      if (key[2] < m) m = key[2];
      #pragma unroll
      for (int off = 1; off < 32; off <<= 1){
        unsigned lo  = __shfl_xor((unsigned)m, off, 64);
        unsigned hi2 = __shfl_xor((unsigned)(m >> 32), off, 64);
        unsigned long long o = ((unsigned long long)hi2 << 32) | lo;
        if (o < m) m = o;
      }
      if (sub == 0){
        int c = (int)(m & 0xffffffffull);
        bool val = (unsigned)(m >> 32) < 0x7f800000u;
        int dh = c/15 - 2, dw = c%15 - 7;
        int cch = min(max(h+dh, 0), HH-1), ccw = min(max(w+dw, 0), WW-1);
        selFlat[pxl][j] = val ? (cch*WW + ccw) : 0;
        selMask[pxl][j] = val ? 1.0f : 0.0f;
      }
      unsigned midx = (unsigned)m;          // window index is unique -> 32-bit invalidation
      if ((unsigned)key[0] == midx) key[0] = ~0ull;
      if ((unsigned)key[1] == midx) key[1] = ~0ull;
      if ((unsigned)key[2] == midx) key[2] = ~0ull;
    }
  }
  __syncthreads();

  // ---- build A0 [48][160] (f16 frag layout; no XYZ tile — pienc reads A0 ks0) ----
  for (int j = t; j < 528; j += 256){ int row = j/11, c = 138 + 2*(j%11); stH2(S, OFF_A, 5, row, c, 0u); }
  if (t < 48){
    int row = t, px = row/6, k = row%6;
    int bn = bn0 + px, b = bn >> 14;
    float qx = xyz1[bn*3], qy = xyz1[bn*3+1], qz = xyz1[bn*3+2];
    float mk = selMask[px][k];
    const float* p = xyz2 + ((size_t)b*NPIX + selFlat[px][k])*3;
    float ax = p[0]*mk, ay = p[1]*mk, az = p[2]*mk;
    float dx = ax-qx, dy = ay-qy, dz = az-qz;
    float e = sqrtf(dx*dx + dy*dy + dz*dz + 1e-20f);
    stH4(S, OFF_A, 5, row, 0, pack2(qx,qy), pack2(qz,ax));
    stH4(S, OFF_A, 5, row, 4, pack2(ay,az), pack2(dx,dy));
    stH2(S, OFF_A, 5, row, 8, pack2(dz,e));
  }
  {
    int px = t >> 5, ch = (t & 31) << 1;     // pts1 cols 10..73
    int bn = bn0 + px;
    f32x2 v = *(const f32x2*)(pts1 + (size_t)bn*64 + ch);
    unsigned pk = pack2(v.x, v.y);
    #pragma unroll
    for (int k = 0; k < 6; ++k) stH2(S, OFF_A, 5, px*6 + k, 10 + ch, pk);
  }
  for (int j = t; j < 768; j += 256){        // pts2 gather cols 74..137 (float4 loads)
    int row = j >> 4, ch = (j & 15) << 2;
    int px = row/6, k = row%6;
    int b = (bn0 + px) >> 14;
    f32x4 v = *(const f32x4*)(pts2 + ((size_t)b*NPIX + selFlat[px][k])*64 + ch);
    float mk = selMask[px][k];
    stH2(S, OFF_A, 5, row, 74 + ch, pack2(v.x*mk, v.y*mk));
    stH2(S, OFF_A, 5, row, 76 + ch, pack2(v.z*mk, v.w*mk));
  }
  __syncthreads();

  // ---- L1: 160 -> 128 relu -> A1  +  pienc: A0 ks0 -> 64 relu -> enc (CAT 0..63) ----
  {
    const int colN0 = (wv*2)*16 + (l & 15), colN1 = (wv*2+1)*16 + (l & 15);
    const int colNe = wv*16 + (l & 15);
    const float bb0 = b0[colN0], bb1 = b0[colN1], be = pb[colNe];
    f32x4 acc[3][2], ae[3][1];
    #pragma unroll
    for (int mt = 0; mt < 3; ++mt){
      acc[mt][0] = (f32x4){bb0,bb0,bb0,bb0}; acc[mt][1] = (f32x4){bb1,bb1,bb1,bb1};
      ae[mt][0]  = (f32x4){be,be,be,be};
    }
    mfmaLayer<3,5,5,2>(S, OFF_A, wp, WB_W0, wv, lswz, l, acc);
    mfmaLayer<3,1,5,1>(S, OFF_A, wp, WB_PW, wv, lswz, l, ae);
    #pragma unroll
    for (int mt = 0; mt < 3; ++mt){
      int row = mt*16 + ((l>>4)<<2);
      epiPair(S, OFF_CAT, 4, row,   colNe, ae[mt][0][0], ae[mt][0][1]);
      epiPair(S, OFF_CAT, 4, row+2, colNe, ae[mt][0][2], ae[mt][0][3]);
    }
    __syncthreads();   // all A0 reads complete
    #pragma unroll
    for (int mt = 0; mt < 3; ++mt){
      int row = mt*16 + ((l>>4)<<2);
      epiPair(S, OFF_A, 4, row,   colN0, acc[mt][0][0], acc[mt][0][1]);
      epiPair(S, OFF_A, 4, row+2, colN0, acc[mt][0][2], acc[mt][0][3]);
      epiPair(S, OFF_A, 4, row,   colN1, acc[mt][1][0], acc[mt][1][1]);
      epiPair(S, OFF_A, 4, row+2, colN1, acc[mt][1][2], acc[mt][1][3]);
    }
    __syncthreads();
  }

  // ---- L2: 128 -> 64 relu -> h2 ----
  {
    const int colN = wv*16 + (l & 15);
    const float bb = b1[colN];
    f32x4 acc[3][1];
    #pragma unroll
    for (int mt = 0; mt < 3; ++mt) acc[mt][0] = (f32x4){bb,bb,bb,bb};
    mfmaLayer<3,4,4,1>(S, OFF_A, wp, WB_W1, wv, lswz, l, acc);
    __syncthreads();   // A1 reads done
    #pragma unroll
    for (int mt = 0; mt < 3; ++mt){
      int row = mt*16 + ((l>>4)<<2);
      epiPair(S, OFF_A, 2, row,   colN, acc[mt][0][0], acc[mt][0][1]);
      epiPair(S, OFF_A, 2, row+2, colN, acc[mt][0][2], acc[mt][0][3]);
    }
    __syncthreads();
  }

  // ---- L3: 64 -> 64 relu -> feat (CAT cols 64..127) ----
  {
    const int colN = wv*16 + (l & 15);
    const float bb = b2[colN];
    f32x4 acc[3][1];
    #pragma unroll
    for (int mt = 0; mt < 3; ++mt) acc[mt][0] = (f32x4){bb,bb,bb,bb};
    mfmaLayer<3,2,2,1>(S, OFF_A, wp, WB_W2, wv, lswz, l, acc);
    #pragma unroll
    for (int mt = 0; mt < 3; ++mt){
      int row = mt*16 + ((l>>4)<<2);
      epiPair(S, OFF_CAT, 4, row,   64 + colN, acc[mt][0][0], acc[mt][0][1]);
      epiPair(S, OFF_CAT, 4, row+2, 64 + colN, acc[mt][0][2], acc[mt][0][3]);
    }
    __syncthreads();   // h2 reads done + feat visible
  }

  // ---- m2c1: cat(128) -> 128 relu -> a1 (OFF_A) ----
  {
    const int colN0 = (wv*2)*16 + (l & 15), colN1 = (wv*2+1)*16 + (l & 15);
    const float bb0 = q0b[colN0], bb1 = q0b[colN1];
    f32x4 acc[3][2];
    #pragma unroll
    for (int mt = 0; mt < 3; ++mt){
      acc[mt][0] = (f32x4){bb0,bb0,bb0,bb0}; acc[mt][1] = (f32x4){bb1,bb1,bb1,bb1};
    }
    mfmaLayer<3,4,4,2>(S, OFF_CAT, wp, WB_Q0, wv, lswz, l, acc);
    #pragma unroll
    for (int mt = 0; mt < 3; ++mt){
      int row = mt*16 + ((l>>4)<<2);
      epiPair(S, OFF_A, 4, row,   colN0, acc[mt][0][0], acc[mt][0][1]);
      epiPair(S, OFF_A, 4, row+2, colN0, acc[mt][0][2], acc[mt][0][3]);
      epiPair(S, OFF_A, 4, row,   colN1, acc[mt][1][0], acc[mt][1][1]);
      epiPair(S, OFF_A, 4, row+2, colN1, acc[mt][1][2], acc[mt][1][3]);
    }
    __syncthreads();
  }

  // ---- m2c2: 128 -> 64 relu -> att fp32 (aliases a1 region) ----
  {
    const int colN = wv*16 + (l & 15);
    const float bb = q1b[colN];
    f32x4 acc[3][1];
    #pragma unroll
    for (int mt = 0; mt < 3; ++mt) acc[mt][0] = (f32x4){bb,bb,bb,bb};
    mfmaLayer<3,4,4,1>(S, OFF_A, wp, WB_Q1, wv, lswz, l, acc);
    __syncthreads();   // a1 reads done
    #pragma unroll
    for (int mt = 0; mt < 3; ++mt)
      #pragma unroll
      for (int r = 0; r < 4; ++r){
        int row = mt*16 + ((l>>4)<<2) + r;
        *(float*)(S + OFF_A + (row*ATTS + colN)*4) = fmaxf(acc[mt][0][r], 0.f);
      }
    __syncthreads();
  }

  // ---- masked softmax over K=6 + weighted sum ----
  for (int j = t; j < 512; j += 256){
    int px = j >> 6, ch = j & 63; int bn = bn0 + px;
    float vv[6], ff[6];
    #pragma unroll
    for (int k = 0; k < 6; ++k){
      int row = px*6 + k;
      float a = *(const float*)(S + OFF_A + (row*ATTS + ch)*4);
      vv[k] = (selMask[px][k] > 0.5f) ? a : -1e10f;
      ff[k] = h2f_(*(const u16*)(S + OFF_CAT + fragByte(4, row, 64 + ch)));
    }
    float mx = vv[0];
    #pragma unroll
    for (int k = 1; k < 6; ++k) mx = fmaxf(mx, vv[k]);
    float s = 0.f, ws = 0.f;
    #pragma unroll
    for (int k = 0; k < 6; ++k){
      float e = __expf(vv[k] - mx);
      s += e; ws = fmaf(e, ff[k], ws);
    }
    f1out[(size_t)bn*64 + ch] = __fdividef(ws, s);
  }
}

// ---------------- stage 2: 8 px/block, 32 rows = 2 mtiles, 256 threads ----------------
#define OFF2_CAT 0       // K=192: 12288B
#define OFF2_XYZ 12288   // K=32: 2048B
#define OFF2_A1  14336   // a1 K=128: 8192B; aliases att fp32 [32][ATTS] (8448B)
#define SM2_TOT  22784

__global__ __launch_bounds__(256)
void stage2_mfma(const float* __restrict__ xyz1, const float* __restrict__ pts1,
                 const float* __restrict__ f1,
                 const float* __restrict__ pcb, const float* __restrict__ n0b,
                 const float* __restrict__ n1b,
                 const u16* __restrict__ wp, float* __restrict__ out)
{
  __shared__ __align__(16) char S[SM2_TOT];
  __shared__ int   selFlat[8][4];
  __shared__ float selMask[8][4];

  const int t = threadIdx.x, wv = t >> 6, l = t & 63;
  const int lswz = l ^ ((l >> 4) & 3);
  const int bn0 = blockIdx.x << 3;

  // ---- selection: half-wave per pixel, 3x3 window, top-4 ----
  {
    const int p = l >> 5, sub = l & 31;
    const int pxl = (wv << 1) | p;
    const int bn = bn0 + pxl;
    const int b = bn >> 14, n = bn & 16383, h = n >> 8, w = n & 255;
    const float qx = xyz1[bn*3], qy = xyz1[bn*3+1], qz = xyz1[bn*3+2];
    unsigned long long key = ~0ull;
    if (sub < 9){
      int dh = sub/3 - 1, dw = sub%3 - 1;
      int ch = h + dh, cw = w + dw;
      bool inb = ((unsigned)ch < HH) && ((unsigned)cw < WW);
      unsigned hi = 0x7f800000u;
      if (inb){
        int fl = ch*WW + cw;
        const float* p2 = xyz1 + ((size_t)b*NPIX + fl)*3;
        float dx = p2[0]-qx, dy = p2[1]-qy, dz = p2[2]-qz;
        float d2 = dx*dx + dy*dy + dz*dz;
        if (d2 < 10.0f) hi = __float_as_uint(d2);
      }
      key = ((unsigned long long)hi << 32) | (unsigned)sub;
    }
    for (int j = 0; j < 4; ++j){
      unsigned long long m = key;
      #pragma unroll
      for (int off = 1; off < 32; off <<= 1){
        unsigned lo  = __shfl_xor((unsigned)m, off, 64);
        unsigned hi2 = __shfl_xor((unsigned)(m >> 32), off, 64);
        unsigned long long o = ((unsigned long long)hi2 << 32) | lo;
        if (o < m) m = o;
      }
      if (sub == 0){
        int c = (int)(m & 0xffffffffull);
        bool val = (unsigned)(m >> 32) < 0x7f800000u;
        int dh = c/3 - 1, dw = c%3 - 1;
        int cch = min(max(h+dh, 0), HH-1), ccw = min(max(w+dw, 0), WW-1);
        selFlat[pxl][j] = val ? (cch*WW + ccw) : 0;
        selMask[pxl][j] = val ? 1.0f : 0.0f;
      }
      if ((unsigned)key == (unsigned)m) key = ~0ull;
    }
  }
  __syncthreads();

  // ---- build XYZ [32][32] + CAT cols 64..191 ----
  for (int j = t; j < 352; j += 256){ int row = j/11, c = 10 + 2*(j%11); stH2(S, OFF2_XYZ, 1, row, c, 0u); }
  if (t < 32){
    int row = t, px = row >> 2, k = row & 3;
    int bn = bn0 + px, b = bn >> 14;
    float qx = xyz1[bn*3], qy = xyz1[bn*3+1], qz = xyz1[bn*3+2];
    float mk = selMask[px][k];
    const float* p = xyz1 + ((size_t)b*NPIX + selFlat[px][k])*3;
    float ax = p[0]*mk, ay = p[1]*mk, az = p[2]*mk;
    float dx = ax-qx, dy = ay-qy, dz = az-qz;
    float e = sqrtf(dx*dx + dy*dy + dz*dz + 1e-20f);
    stH4(S, OFF2_XYZ, 1, row, 0, pack2(qx,qy), pack2(qz,ax));
    stH4(S, OFF2_XYZ, 1, row, 4, pack2(ay,az), pack2(dx,dy));
    stH2(S, OFF2_XYZ, 1, row, 8, pack2(dz,e));
  }
  if (t < 128){                              // pts1 -> CAT cols 64..127 (float4)
    int px = t >> 4, ch = (t & 15) << 2;
    int bn = bn0 + px;
    f32x4 v = *(const f32x4*)(pts1 + (size_t)bn*64 + ch);
    #pragma unroll
    for (int k = 0; k < 4; ++k){
      float mk = selMask[px][k];
      stH4(S, OFF2_CAT, 6, px*4 + k, 64 + ch, pack2(v.x*mk, v.y*mk), pack2(v.z*mk, v.w*mk));
    }
  }
  for (int j = t; j < 512; j += 256){        // f1 gather -> CAT cols 128..191 (float4)
    int row = j >> 4, ch = (j & 15) << 2;
    int px = row >> 2, k = row & 3;
    int b = (bn0 + px) >> 14;
    f32x4 v = *(const f32x4*)(f1 + ((size_t)b*NPIX + selFlat[px][k])*64 + ch);
    float mk = selMask[px][k];
    stH4(S, OFF2_CAT, 6, row, 128 + ch, pack2(v.x*mk, v.y*mk), pack2(v.z*mk, v.w*mk));
  }
  __syncthreads();

  // ---- pcenc: 32 -> 64 relu, * mask -> CAT cols 0..63 ----
  {
    const int colN = wv*16 + (l & 15);
    const float bb = pcb[colN];
    f32x4 acc[2][1];
    acc[0][0] = (f32x4){bb,bb,bb,bb}; acc[1][0] = (f32x4){bb,bb,bb,bb};
    mfmaLayer<2,1,1,1>(S, OFF2_XYZ, wp, WB_PC, wv, lswz, l, acc);
    #pragma unroll
    for (int mt = 0; mt < 2; ++mt){
      int row = mt*16 + ((l>>4)<<2);
      float v0 = fmaxf(acc[mt][0][0], 0.f) * selMask[(row  )>>2][(row  )&3];
      float v1 = fmaxf(acc[mt][0][1], 0.f) * selMask[(row+1)>>2][(row+1)&3];
      float v2 = fmaxf(acc[mt][0][2], 0.f) * selMask[(row+2)>>2][(row+2)&3];
      float v3 = fmaxf(acc[mt][0][3], 0.f) * selMask[(row+3)>>2][(row+3)&3];
      unsigned pa = pack2(v0, v1), pb2 = pack2(v2, v3);
      stH(S, OFF2_CAT, 6, row,   colN, (u16)pa);
      stH(S, OFF2_CAT, 6, row+1, colN, (u16)(pa>>16));
      stH(S, OFF2_CAT, 6, row+2, colN, (u16)pb2);
      stH(S, OFF2_CAT, 6, row+3, colN, (u16)(pb2>>16));
    }
    __syncthreads();
  }

  // ---- m2n1: 192 -> 128 relu -> a1 ----
  {
    const int colN0 = (wv*2)*16 + (l & 15), colN1 = (wv*2+1)*16 + (l & 15);
    const float bb0 = n0b[colN0], bb1 = n0b[colN1];
    f32x4 acc[2][2];
    #pragma unroll
    for (int mt = 0; mt < 2; ++mt){
      acc[mt][0] = (f32x4){bb0,bb0,bb0,bb0}; acc[mt][1] = (f32x4){bb1,bb1,bb1,bb1};
    }
    mfmaLayer<2,6,6,2>(S, OFF2_CAT, wp, WB_N0, wv, lswz, l, acc);
    #pragma unroll
    for (int mt = 0; mt < 2; ++mt){
      int row = mt*16 + ((l>>4)<<2);
      epiPair(S, OFF2_A1, 4, row,   colN0, acc[mt][0][0], acc[mt][0][1]);
      epiPair(S, OFF2_A1, 4, row+2, colN0, acc[mt][0][2], acc[mt][0][3]);
      epiPair(S, OFF2_A1, 4, row,   colN1, acc[mt][1][0], acc[mt][1][1]);
      epiPair(S, OFF2_A1, 4, row+2, colN1, acc[mt][1][2], acc[mt][1][3]);
    }
    __syncthreads();
  }

  // ---- m2n2: 128 -> 64 relu -> att fp32 (aliases a1) ----
  {
    const int colN = wv*16 + (l & 15);
    const float bb = n1b[colN];
    f32x4 acc[2][1];
    acc[0][0] = (f32x4){bb,bb,bb,bb}; acc[1][0] = (f32x4){bb,bb,bb,bb};
    mfmaLayer<2,4,4,1>(S, OFF2_A1, wp, WB_N1, wv, lswz, l, acc);
    __syncthreads();   // a1 reads done
    #pragma unroll
    for (int mt = 0; mt < 2; ++mt)
      #pragma unroll
      for (int r = 0; r < 4; ++r){
        int row = mt*16 + ((l>>4)<<2) + r;
        *(float*)(S + OFF2_A1 + (row*ATTS + colN)*4) = fmaxf(acc[mt][0][r], 0.f);
      }
    __syncthreads();
  }

  // ---- masked softmax over K=4 + weighted sum ----
  for (int j = t; j < 512; j += 256){
    int px = j >> 6, ch = j & 63; int bn = bn0 + px;
    float vv[4], gg[4];
    #pragma unroll
    for (int k = 0; k < 4; ++k){
      int row = px*4 + k;
      float a = *(const float*)(S + OFF2_A1 + (row*ATTS + ch)*4);
      vv[k] = (selMask[px][k] > 0.5f) ? a : -1e10f;
      gg[k] = h2f_(*(const u16*)(S + OFF2_CAT + fragByte(6, row, 128 + ch)));
    }
    float mx = fmaxf(fmaxf(vv[0], vv[1]), fmaxf(vv[2], vv[3]));
    float s = 0.f, ws = 0.f;
    #pragma unroll
    for (int k = 0; k < 4; ++k){
      float e = __expf(vv[k] - mx);
      s += e; ws = fmaf(e, gg[k], ws);
    }
    out[(size_t)bn*64 + ch] = __fdividef(ws, s);
  }
}

extern "C" void kernel_launch(void* const* d_in, const int* in_sizes, int n_in,
                              void* d_out, int out_size, void* d_ws, size_t ws_size,
                              hipStream_t stream) {
    const float* xyz1 = (const float*)d_in[0];
    const float* xyz2 = (const float*)d_in[1];
    const float* pts1 = (const float*)d_in[2];
    const float* pts2 = (const float*)d_in[3];
    const float* m1w0 = (const float*)d_in[4];
    const float* m1b0 = (const float*)d_in[5];
    const float* m1w1 = (const float*)d_in[6];
    const float* m1b1 = (const float*)d_in[7];
    const float* m1w2 = (const float*)d_in[8];
    const float* m1b2 = (const float*)d_in[9];
    const float* piw  = (const float*)d_in[10];
    const float* pib  = (const float*)d_in[11];
    const float* m2w0 = (const float*)d_in[12];
    const float* m2b0 = (const float*)d_in[13];
    const float* m2w1 = (const float*)d_in[14];
    const float* m2b1 = (const float*)d_in[15];
    const float* pcw  = (const float*)d_in[16];
    const float* pcb  = (const float*)d_in[17];
    const float* n0w  = (const float*)d_in[18];
    const float* n0b  = (const float*)d_in[19];
    const float* n1w  = (const float*)d_in[20];
    const float* n1b  = (const float*)d_in[21];

    const int B = in_sizes[0] / (NPIX * 3);
    u16*   wplanes = (u16*)d_ws;
    float* f1      = (float*)((char*)d_ws + F1_OFFSET);
    float* out     = (float*)d_out;

    hipLaunchKernelGGL(prep_weights, dim3(46), dim3(256), 0, stream,
                       m1w0, m1w1, m1w2, piw, m2w0, m2w1, pcw, n0w, n1w, wplanes);
    hipLaunchKernelGGL(stage1_mfma, dim3((B*NPIX)/8), dim3(256), 0, stream,
                       xyz1, xyz2, pts1, pts2,
                       m1b0, m1b1, m1b2, pib, m2b0, m2b1,
                       wplanes, f1);
    hipLaunchKernelGGL(stage2_mfma, dim3((B*NPIX)/8), dim3(256), 0, stream,
                       xyz1, pts1, f1, pcb, n0b, n1b,
                       wplanes, out);
}

// Round 10
// 267.497 us; speedup vs baseline: 9.5177x; 1.0324x over previous
//
#include <hip/hip_runtime.h>
#include <math.h>

#define HH 64
#define WW 256
#define NPIX (HH*WW)

typedef unsigned short u16;
typedef __attribute__((ext_vector_type(8))) short s16x8;
typedef __attribute__((ext_vector_type(8))) _Float16 h16x8;
typedef __attribute__((ext_vector_type(2))) __fp16 fp16x2;
typedef __attribute__((ext_vector_type(4))) float f32x4;
typedef __attribute__((ext_vector_type(2))) float f32x2;
typedef __attribute__((ext_vector_type(2))) unsigned u32x2;

// ---------------- f16 helpers ----------------
__device__ __forceinline__ u16 f2h_(float x){
  union { _Float16 h; u16 u; } v; v.h = (_Float16)x; return v.u;   // RTN
}
__device__ __forceinline__ float h2f_(u16 b){
  union { u16 u; _Float16 h; } v; v.u = b; return (float)v.h;
}
__device__ __forceinline__ unsigned pack2(float a, float b){        // RTZ, 1 instr
  union { fp16x2 h; unsigned u; } v; v.h = __builtin_amdgcn_cvt_pkrtz(a, b); return v.u;
}

// A-fragment LDS layout with bank swizzle: intra-tile frag = ((row&15)^kg) | (kg<<4), kg=(kcol>>3)&3
__device__ __forceinline__ int fragByte(int KS, int row, int kcol){
  int kg = (kcol >> 3) & 3;
  int frag = ((row >> 4) * KS + (kcol >> 5)) * 64 + (((row & 15) ^ kg) | (kg << 4));
  return frag * 16 + ((kcol & 7) << 1);
}
__device__ __forceinline__ void stH(char* S, int off, int KS, int row, int kcol, u16 v){
  *(u16*)(S + off + fragByte(KS, row, kcol)) = v;
}
__device__ __forceinline__ void stH2(char* S, int off, int KS, int row, int kcol, unsigned v2){
  *(unsigned*)(S + off + fragByte(KS, row, kcol)) = v2;   // kcol even
}
__device__ __forceinline__ void stH4(char* S, int off, int KS, int row, int kcol, unsigned a, unsigned b){
  *(u32x2*)(S + off + fragByte(KS, row, kcol)) = (u32x2){a, b};   // kcol % 4 == 0
}
// relu + packed-cvt epilogue for 4 rows rb..rb+3 (rb 4-aligned in-tile), same kcol.
// rows map to frag slots base + (i^kg)*16 — one base computation for 4 stores.
__device__ __forceinline__ void epiQuad(char* S, int off, int KS, int rb, int kcol, f32x4 a){
  int kg = (kcol >> 3) & 3;
  char* base = S + off + ((((rb >> 4) * KS + (kcol >> 5)) * 64 + (rb & 15) + (kg << 4)) << 4)
                 + ((kcol & 7) << 1);
  unsigned p0 = pack2(fmaxf(a[0], 0.f), fmaxf(a[1], 0.f));
  unsigned p1 = pack2(fmaxf(a[2], 0.f), fmaxf(a[3], 0.f));
  *(u16*)(base + ((0^kg) << 4)) = (u16)p0;
  *(u16*)(base + ((1^kg) << 4)) = (u16)(p0 >> 16);
  *(u16*)(base + ((2^kg) << 4)) = (u16)p1;
  *(u16*)(base + ((3^kg) << 4)) = (u16)(p1 >> 16);
}
// same, with per-row post-relu mask multiply
__device__ __forceinline__ void epiQuadM(char* S, int off, int KS, int rb, int kcol, f32x4 a, const float* mk){
  int kg = (kcol >> 3) & 3;
  char* base = S + off + ((((rb >> 4) * KS + (kcol >> 5)) * 64 + (rb & 15) + (kg << 4)) << 4)
                 + ((kcol & 7) << 1);
  unsigned p0 = pack2(fmaxf(a[0], 0.f)*mk[0], fmaxf(a[1], 0.f)*mk[1]);
  unsigned p1 = pack2(fmaxf(a[2], 0.f)*mk[2], fmaxf(a[3], 0.f)*mk[3]);
  *(u16*)(base + ((0^kg) << 4)) = (u16)p0;
  *(u16*)(base + ((1^kg) << 4)) = (u16)(p0 >> 16);
  *(u16*)(base + ((2^kg) << 4)) = (u16)p1;
  *(u16*)(base + ((3^kg) << 4)) = (u16)(p1 >> 16);
}
__device__ __forceinline__ h16x8 ldWf(const u16* wp, int base, int KS, int nt, int ks, int l){
  return *(const h16x8*)(wp + base + (size_t)((nt * KS + ks) * 64 + l) * 8);
}

// weight-plane bases (u16 elems) in d_ws (single f16 plane per layer)
#define WB_W0 0
#define WB_W1 20480
#define WB_W2 28672
#define WB_PW 32768
#define WB_Q0 34816
#define WB_Q1 51200
#define WB_PC 59392
#define WB_N0 61440
#define WB_N1 86016
#define F1_OFFSET (512*1024)

// single-plane f16 MFMA layer; KSL = weight ksteps (loop), KSTR = A-tile kstep stride
template<int MT, int KSL, int KSTR, int NTW>
__device__ __forceinline__ void mfmaLayer(const char* S, int offA,
                                          const u16* wp, int wbase,
                                          int wv, int lswz, int l, f32x4 (&acc)[MT][NTW])
{
  #pragma unroll
  for (int ks = 0; ks < KSL; ++ks){
    h16x8 bh[NTW];
    #pragma unroll
    for (int j = 0; j < NTW; ++j)
      bh[j] = ldWf(wp, wbase, KSL, wv * NTW + j, ks, l);
    #pragma unroll
    for (int mt = 0; mt < MT; ++mt){
      h16x8 a = *(const h16x8*)(S + offA + ((mt * KSTR + ks) * 64 + lswz) * 16);
      #pragma unroll
      for (int j = 0; j < NTW; ++j)
        acc[mt][j] = __builtin_amdgcn_mfma_f32_16x16x32_f16(a, bh[j], acc[mt][j], 0, 0, 0);
    }
  }
}

// ---------------- weight prep: fp32 -> B-fragment f16 plane ----------------
__global__ __launch_bounds__(256)
void prep_weights(const float* __restrict__ w0, const float* __restrict__ w1,
                  const float* __restrict__ w2, const float* __restrict__ pw,
                  const float* __restrict__ q0, const float* __restrict__ q1,
                  const float* __restrict__ pcw, const float* __restrict__ n0,
                  const float* __restrict__ n1, u16* __restrict__ wp)
{
  int id = blockIdx.x * 256 + threadIdx.x;
  const float* src; int Kdim, KS, N, base, tau;
  if      (id <  2560){ src=w0;  Kdim=138; KS=5; N=128; base=WB_W0; tau=id;        }
  else if (id <  3584){ src=w1;  Kdim=128; KS=4; N=64;  base=WB_W1; tau=id-2560;   }
  else if (id <  4096){ src=w2;  Kdim=64;  KS=2; N=64;  base=WB_W2; tau=id-3584;   }
  else if (id <  4352){ src=pw;  Kdim=10;  KS=1; N=64;  base=WB_PW; tau=id-4096;   }
  else if (id <  6400){ src=q0;  Kdim=128; KS=4; N=128; base=WB_Q0; tau=id-4352;   }
  else if (id <  7424){ src=q1;  Kdim=128; KS=4; N=64;  base=WB_Q1; tau=id-6400;   }
  else if (id <  7680){ src=pcw; Kdim=10;  KS=1; N=64;  base=WB_PC; tau=id-7424;   }
  else if (id < 10752){ src=n0;  Kdim=192; KS=6; N=128; base=WB_N0; tau=id-7680;   }
  else if (id < 11776){ src=n1;  Kdim=128; KS=4; N=64;  base=WB_N1; tau=id-10752;  }
  else return;
  int nt = tau / (KS * 64); int rem = tau % (KS * 64); int ks = rem >> 6; int l = rem & 63;
  s16x8 vh;
  #pragma unroll
  for (int i = 0; i < 8; ++i){
    int k = ks * 32 + ((l >> 4) << 3) + i;
    int n = nt * 16 + (l & 15);
    float v = (k < Kdim) ? src[(size_t)k * N + n] : 0.0f;
    vh[i] = (short)f2h_(v);
  }
  *(s16x8*)(wp + base + (size_t)tau * 8) = vh;
}

#define ATTS 66   // fp32 att tile row stride (floats), breaks bank periodicity

// ---------------- stage 1: 8 px/block, 48 rows = 3 mtiles, 256 threads ----------------
// OFF_A (15360B): A0 K160 -> A1 K128 -> h2 K64 -> a1 K128 -> att fp32 [48][ATTS]
#define OFF_A    0
#define OFF_CAT  15360   // K=128: 12288B (enc cols0-63, feat cols64-127)
#define SM1_TOT  27648

__global__ __launch_bounds__(256)
void stage1_mfma(const float* __restrict__ xyz1, const float* __restrict__ xyz2,
                 const float* __restrict__ pts1, const float* __restrict__ pts2,
                 const float* __restrict__ b0, const float* __restrict__ b1,
                 const float* __restrict__ b2, const float* __restrict__ pb,
                 const float* __restrict__ q0b, const float* __restrict__ q1b,
                 const u16* __restrict__ wp, float* __restrict__ f1out)
{
  __shared__ __align__(16) char S[SM1_TOT];
  __shared__ int   selFlat[8][6];
  __shared__ __align__(16) float selMask[8][6];

  const int t = threadIdx.x, wv = t >> 6, l = t & 63;
  const int lswz = l ^ ((l >> 4) & 3);
  const int bn0 = blockIdx.x << 3;

  // ---- selection: half-wave per pixel (p = l>>5), 3 candidates/sublane, top-6 ----
  // f32 butterfly-min + ballot claim; exact jax top_k tie-break (smaller window idx on equal d2)
  {
    const int p = l >> 5, sub = l & 31;
    const int pxl = (wv << 1) | p;
    const int bn = bn0 + pxl;
    const int b = bn >> 14, n = bn & 16383, h = n >> 8, w = n & 255;
    const float qx = xyz1[bn*3], qy = xyz1[bn*3+1], qz = xyz1[bn*3+2];
    float d3[3];
    #pragma unroll
    for (int i = 0; i < 3; ++i){
      int c = sub + (i << 5);
      float dd = __builtin_inff();
      if (c < 75){
        int dh = c/15 - 2, dw = c%15 - 7;
        int ch = h + dh, cw = w + dw;
        if (((unsigned)ch < HH) && ((unsigned)cw < WW)){
          const float* p2 = xyz2 + ((size_t)b*NPIX + ch*WW + cw)*3;
          float dx = p2[0]-qx, dy = p2[1]-qy, dz = p2[2]-qz;
          float d2 = dx*dx + dy*dy + dz*dz;
          if (d2 < 100.0f) dd = d2;
        }
      }
      d3[i] = dd;
    }
    for (int j = 0; j < 6; ++j){
      float m = fminf(fminf(d3[0], d3[1]), d3[2]);
      #pragma unroll
      for (int off = 1; off < 32; off <<= 1)
        m = fminf(m, __shfl_xor(m, off, 64));
      unsigned h0 = (unsigned)(__ballot(d3[0] == m) >> (p << 5));
      unsigned h1 = (unsigned)(__ballot(d3[1] == m) >> (p << 5));
      unsigned h2b = (unsigned)(__ballot(d3[2] == m) >> (p << 5));
      int slot   = h0 ? 0 : (h1 ? 1 : 2);
      unsigned hb = h0 ? h0 : (h1 ? h1 : h2b);
      hb = hb ? hb : 1u;                       // denormal-flush safety
      int osub = __ffs(hb) - 1;
      bool valid = (m < 3.0e38f);
      if (sub == 0){
        int c = osub + (slot << 5);
        int dh = c/15 - 2, dw = c%15 - 7;
        int cch = min(max(h+dh, 0), HH-1), ccw = min(max(w+dw, 0), WW-1);
        selFlat[pxl][j] = valid ? (cch*WW + ccw) : 0;
        selMask[pxl][j] = valid ? 1.0f : 0.0f;
      }
      if (sub == osub) d3[slot] = __builtin_inff();
    }
  }
  __syncthreads();

  // ---- build A0 [48][160] (f16 frag layout; no XYZ tile — pienc reads A0 ks0) ----
  for (int j = t; j < 528; j += 256){ int row = j/11, c = 138 + 2*(j%11); stH2(S, OFF_A, 5, row, c, 0u); }
  if (t < 48){
    int row = t, px = row/6, k = row%6;
    int bn = bn0 + px, b = bn >> 14;
    float qx = xyz1[bn*3], qy = xyz1[bn*3+1], qz = xyz1[bn*3+2];
    float mk = selMask[px][k];
    const float* p = xyz2 + ((size_t)b*NPIX + selFlat[px][k])*3;
    float ax = p[0]*mk, ay = p[1]*mk, az = p[2]*mk;
    float dx = ax-qx, dy = ay-qy, dz = az-qz;
    float e = sqrtf(dx*dx + dy*dy + dz*dz + 1e-20f);
    stH4(S, OFF_A, 5, row, 0, pack2(qx,qy), pack2(qz,ax));
    stH4(S, OFF_A, 5, row, 4, pack2(ay,az), pack2(dx,dy));
    stH2(S, OFF_A, 5, row, 8, pack2(dz,e));
  }
  {
    int px = t >> 5, ch = (t & 31) << 1;     // pts1 cols 10..73
    int bn = bn0 + px;
    f32x2 v = *(const f32x2*)(pts1 + (size_t)bn*64 + ch);
    unsigned pk = pack2(v.x, v.y);
    #pragma unroll
    for (int k = 0; k < 6; ++k) stH2(S, OFF_A, 5, px*6 + k, 10 + ch, pk);
  }
  for (int j = t; j < 768; j += 256){        // pts2 gather cols 74..137 (float4 loads)
    int row = j >> 4, ch = (j & 15) << 2;
    int px = row/6, k = row%6;
    int b = (bn0 + px) >> 14;
    f32x4 v = *(const f32x4*)(pts2 + ((size_t)b*NPIX + selFlat[px][k])*64 + ch);
    float mk = selMask[px][k];
    stH2(S, OFF_A, 5, row, 74 + ch, pack2(v.x*mk, v.y*mk));
    stH2(S, OFF_A, 5, row, 76 + ch, pack2(v.z*mk, v.w*mk));
  }
  __syncthreads();

  // ---- L1: 160 -> 128 relu -> A1  +  pienc: A0 ks0 -> 64 relu -> enc (CAT 0..63) ----
  {
    const int colN0 = (wv*2)*16 + (l & 15), colN1 = (wv*2+1)*16 + (l & 15);
    const int colNe = wv*16 + (l & 15);
    const float bb0 = b0[colN0], bb1 = b0[colN1], be = pb[colNe];
    f32x4 acc[3][2], ae[3][1];
    #pragma unroll
    for (int mt = 0; mt < 3; ++mt){
      acc[mt][0] = (f32x4){bb0,bb0,bb0,bb0}; acc[mt][1] = (f32x4){bb1,bb1,bb1,bb1};
      ae[mt][0]  = (f32x4){be,be,be,be};
    }
    mfmaLayer<3,5,5,2>(S, OFF_A, wp, WB_W0, wv, lswz, l, acc);
    mfmaLayer<3,1,5,1>(S, OFF_A, wp, WB_PW, wv, lswz, l, ae);
    #pragma unroll
    for (int mt = 0; mt < 3; ++mt)
      epiQuad(S, OFF_CAT, 4, mt*16 + ((l>>4)<<2), colNe, ae[mt][0]);
    __syncthreads();   // all A0 reads complete
    #pragma unroll
    for (int mt = 0; mt < 3; ++mt){
      int rb = mt*16 + ((l>>4)<<2);
      epiQuad(S, OFF_A, 4, rb, colN0, acc[mt][0]);
      epiQuad(S, OFF_A, 4, rb, colN1, acc[mt][1]);
    }
    __syncthreads();
  }

  // ---- L2: 128 -> 64 relu -> h2 ----
  {
    const int colN = wv*16 + (l & 15);
    const float bb = b1[colN];
    f32x4 acc[3][1];
    #pragma unroll
    for (int mt = 0; mt < 3; ++mt) acc[mt][0] = (f32x4){bb,bb,bb,bb};
    mfmaLayer<3,4,4,1>(S, OFF_A, wp, WB_W1, wv, lswz, l, acc);
    __syncthreads();   // A1 reads done
    #pragma unroll
    for (int mt = 0; mt < 3; ++mt)
      epiQuad(S, OFF_A, 2, mt*16 + ((l>>4)<<2), colN, acc[mt][0]);
    __syncthreads();
  }

  // ---- L3: 64 -> 64 relu -> feat (CAT cols 64..127) ----
  {
    const int colN = wv*16 + (l & 15);
    const float bb = b2[colN];
    f32x4 acc[3][1];
    #pragma unroll
    for (int mt = 0; mt < 3; ++mt) acc[mt][0] = (f32x4){bb,bb,bb,bb};
    mfmaLayer<3,2,2,1>(S, OFF_A, wp, WB_W2, wv, lswz, l, acc);
    #pragma unroll
    for (int mt = 0; mt < 3; ++mt)
      epiQuad(S, OFF_CAT, 4, mt*16 + ((l>>4)<<2), 64 + colN, acc[mt][0]);
    __syncthreads();   // h2 reads done + feat visible
  }

  // ---- m2c1: cat(128) -> 128 relu -> a1 (OFF_A) ----
  {
    const int colN0 = (wv*2)*16 + (l & 15), colN1 = (wv*2+1)*16 + (l & 15);
    const float bb0 = q0b[colN0], bb1 = q0b[colN1];
    f32x4 acc[3][2];
    #pragma unroll
    for (int mt = 0; mt < 3; ++mt){
      acc[mt][0] = (f32x4){bb0,bb0,bb0,bb0}; acc[mt][1] = (f32x4){bb1,bb1,bb1,bb1};
    }
    mfmaLayer<3,4,4,2>(S, OFF_CAT, wp, WB_Q0, wv, lswz, l, acc);
    #pragma unroll
    for (int mt = 0; mt < 3; ++mt){
      int rb = mt*16 + ((l>>4)<<2);
      epiQuad(S, OFF_A, 4, rb, colN0, acc[mt][0]);
      epiQuad(S, OFF_A, 4, rb, colN1, acc[mt][1]);
    }
    __syncthreads();
  }

  // ---- m2c2: 128 -> 64 relu -> att fp32 (aliases a1 region) ----
  {
    const int colN = wv*16 + (l & 15);
    const float bb = q1b[colN];
    f32x4 acc[3][1];
    #pragma unroll
    for (int mt = 0; mt < 3; ++mt) acc[mt][0] = (f32x4){bb,bb,bb,bb};
    mfmaLayer<3,4,4,1>(S, OFF_A, wp, WB_Q1, wv, lswz, l, acc);
    __syncthreads();   // a1 reads done
    #pragma unroll
    for (int mt = 0; mt < 3; ++mt){
      int rb = mt*16 + ((l>>4)<<2);
      float* ap = (float*)(S + OFF_A + (rb*ATTS + colN)*4);
      #pragma unroll
      for (int r = 0; r < 4; ++r)
        ap[r*ATTS] = fmaxf(acc[mt][0][r], 0.f);
    }
    __syncthreads();
  }

  // ---- masked softmax over K=6 + weighted sum ----
  for (int j = t; j < 512; j += 256){
    int px = j >> 6, ch = j & 63; int bn = bn0 + px;
    float vv[6], ff[6];
    #pragma unroll
    for (int k = 0; k < 6; ++k){
      int row = px*6 + k;
      float a = *(const float*)(S + OFF_A + (row*ATTS + ch)*4);
      vv[k] = (selMask[px][k] > 0.5f) ? a : -1e10f;
      ff[k] = h2f_(*(const u16*)(S + OFF_CAT + fragByte(4, row, 64 + ch)));
    }
    float mx = vv[0];
    #pragma unroll
    for (int k = 1; k < 6; ++k) mx = fmaxf(mx, vv[k]);
    float s = 0.f, ws = 0.f;
    #pragma unroll
    for (int k = 0; k < 6; ++k){
      float e = __expf(vv[k] - mx);
      s += e; ws = fmaf(e, ff[k], ws);
    }
    f1out[(size_t)bn*64 + ch] = __fdividef(ws, s);
  }
}

// ---------------- stage 2: 8 px/block, 32 rows = 2 mtiles, 256 threads ----------------
#define OFF2_CAT 0       // K=192: 12288B
#define OFF2_XYZ 12288   // K=32: 2048B
#define OFF2_A1  14336   // a1 K=128: 8192B; aliases att fp32 [32][ATTS] (8448B)
#define SM2_TOT  22784

__global__ __launch_bounds__(256)
void stage2_mfma(const float* __restrict__ xyz1, const float* __restrict__ pts1,
                 const float* __restrict__ f1,
                 const float* __restrict__ pcb, const float* __restrict__ n0b,
                 const float* __restrict__ n1b,
                 const u16* __restrict__ wp, float* __restrict__ out)
{
  __shared__ __align__(16) char S[SM2_TOT];
  __shared__ int   selFlat[8][4];
  __shared__ __align__(16) float selMask[8][4];

  const int t = threadIdx.x, wv = t >> 6, l = t & 63;
  const int lswz = l ^ ((l >> 4) & 3);
  const int bn0 = blockIdx.x << 3;

  // ---- selection: half-wave per pixel, 3x3 window, top-4 (f32 ballot-claim) ----
  {
    const int p = l >> 5, sub = l & 31;
    const int pxl = (wv << 1) | p;
    const int bn = bn0 + pxl;
    const int b = bn >> 14, n = bn & 16383, h = n >> 8, w = n & 255;
    const float qx = xyz1[bn*3], qy = xyz1[bn*3+1], qz = xyz1[bn*3+2];
    float dd = __builtin_inff();
    if (sub < 9){
      int dh = sub/3 - 1, dw = sub%3 - 1;
      int ch = h + dh, cw = w + dw;
      if (((unsigned)ch < HH) && ((unsigned)cw < WW)){
        const float* p2 = xyz1 + ((size_t)b*NPIX + ch*WW + cw)*3;
        float dx = p2[0]-qx, dy = p2[1]-qy, dz = p2[2]-qz;
        float d2 = dx*dx + dy*dy + dz*dz;
        if (d2 < 10.0f) dd = d2;
      }
    }
    for (int j = 0; j < 4; ++j){
      float m = dd;
      #pragma unroll
      for (int off = 1; off < 32; off <<= 1)
        m = fminf(m, __shfl_xor(m, off, 64));
      unsigned hb = (unsigned)(__ballot(dd == m) >> (p << 5));
      hb = hb ? hb : 1u;
      int osub = __ffs(hb) - 1;
      bool valid = (m < 3.0e38f);
      if (sub == 0){
        int dh = osub/3 - 1, dw = osub%3 - 1;
        int cch = min(max(h+dh, 0), HH-1), ccw = min(max(w+dw, 0), WW-1);
        selFlat[pxl][j] = valid ? (cch*WW + ccw) : 0;
        selMask[pxl][j] = valid ? 1.0f : 0.0f;
      }
      if (sub == osub) dd = __builtin_inff();
    }
  }
  __syncthreads();

  // ---- build XYZ [32][32] + CAT cols 64..191 ----
  for (int j = t; j < 352; j += 256){ int row = j/11, c = 10 + 2*(j%11); stH2(S, OFF2_XYZ, 1, row, c, 0u); }
  if (t < 32){
    int row = t, px = row >> 2, k = row & 3;
    int bn = bn0 + px, b = bn >> 14;
    float qx = xyz1[bn*3], qy = xyz1[bn*3+1], qz = xyz1[bn*3+2];
    float mk = selMask[px][k];
    const float* p = xyz1 + ((size_t)b*NPIX + selFlat[px][k])*3;
    float ax = p[0]*mk, ay = p[1]*mk, az = p[2]*mk;
    float dx = ax-qx, dy = ay-qy, dz = az-qz;
    float e = sqrtf(dx*dx + dy*dy + dz*dz + 1e-20f);
    stH4(S, OFF2_XYZ, 1, row, 0, pack2(qx,qy), pack2(qz,ax));
    stH4(S, OFF2_XYZ, 1, row, 4, pack2(ay,az), pack2(dx,dy));
    stH2(S, OFF2_XYZ, 1, row, 8, pack2(dz,e));
  }
  if (t < 128){                              // pts1 -> CAT cols 64..127 (float4)
    int px = t >> 4, ch = (t & 15) << 2;
    int bn = bn0 + px;
    f32x4 v = *(const f32x4*)(pts1 + (size_t)bn*64 + ch);
    #pragma unroll
    for (int k = 0; k < 4; ++k){
      float mk = selMask[px][k];
      stH4(S, OFF2_CAT, 6, px*4 + k, 64 + ch, pack2(v.x*mk, v.y*mk), pack2(v.z*mk, v.w*mk));
    }
  }
  for (int j = t; j < 512; j += 256){        // f1 gather -> CAT cols 128..191 (float4)
    int row = j >> 4, ch = (j & 15) << 2;
    int px = row >> 2, k = row & 3;
    int b = (bn0 + px) >> 14;
    f32x4 v = *(const f32x4*)(f1 + ((size_t)b*NPIX + selFlat[px][k])*64 + ch);
    float mk = selMask[px][k];
    stH4(S, OFF2_CAT, 6, row, 128 + ch, pack2(v.x*mk, v.y*mk), pack2(v.z*mk, v.w*mk));
  }
  __syncthreads();

  // ---- pcenc: 32 -> 64 relu, * mask -> CAT cols 0..63 ----
  {
    const int colN = wv*16 + (l & 15);
    const float bb = pcb[colN];
    f32x4 acc[2][1];
    acc[0][0] = (f32x4){bb,bb,bb,bb}; acc[1][0] = (f32x4){bb,bb,bb,bb};
    mfmaLayer<2,1,1,1>(S, OFF2_XYZ, wp, WB_PC, wv, lswz, l, acc);
    #pragma unroll
    for (int mt = 0; mt < 2; ++mt){
      int rb = mt*16 + ((l>>4)<<2);          // rb 4-aligned => one px group
      epiQuadM(S, OFF2_CAT, 6, rb, colN, acc[mt][0], &selMask[rb>>2][0]);
    }
    __syncthreads();
  }

  // ---- m2n1: 192 -> 128 relu -> a1 ----
  {
    const int colN0 = (wv*2)*16 + (l & 15), colN1 = (wv*2+1)*16 + (l & 15);
    const float bb0 = n0b[colN0], bb1 = n0b[colN1];
    f32x4 acc[2][2];
    #pragma unroll
    for (int mt = 0; mt < 2; ++mt){
      acc[mt][0] = (f32x4){bb0,bb0,bb0,bb0}; acc[mt][1] = (f32x4){bb1,bb1,bb1,bb1};
    }
    mfmaLayer<2,6,6,2>(S, OFF2_CAT, wp, WB_N0, wv, lswz, l, acc);
    #pragma unroll
    for (int mt = 0; mt < 2; ++mt){
      int rb = mt*16 + ((l>>4)<<2);
      epiQuad(S, OFF2_A1, 4, rb, colN0, acc[mt][0]);
      epiQuad(S, OFF2_A1, 4, rb, colN1, acc[mt][1]);
    }
    __syncthreads();
  }

  // ---- m2n2: 128 -> 64 relu -> att fp32 (aliases a1) ----
  {
    const int colN = wv*16 + (l & 15);
    const float bb = n1b[colN];
    f32x4 acc[2][1];
    acc[0][0] = (f32x4){bb,bb,bb,bb}; acc[1][0] = (f32x4){bb,bb,bb,bb};
    mfmaLayer<2,4,4,1>(S, OFF2_A1, wp, WB_N1, wv, lswz, l, acc);
    __syncthreads();   // a1 reads done
    #pragma unroll
    for (int mt = 0; mt < 2; ++mt){
      int rb = mt*16 + ((l>>4)<<2);
      float* ap = (float*)(S + OFF2_A1 + (rb*ATTS + colN)*4);
      #pragma unroll
      for (int r = 0; r < 4; ++r)
        ap[r*ATTS] = fmaxf(acc[mt][0][r], 0.f);
    }
    __syncthreads();
  }

  // ---- masked softmax over K=4 + weighted sum ----
  for (int j = t; j < 512; j += 256){
    int px = j >> 6, ch = j & 63; int bn = bn0 + px;
    float vv[4], gg[4];
    #pragma unroll
    for (int k = 0; k < 4; ++k){
      int row = px*4 + k;
      float a = *(const float*)(S + OFF2_A1 + (row*ATTS + ch)*4);
      vv[k] = (selMask[px][k] > 0.5f) ? a : -1e10f;
      gg[k] = h2f_(*(const u16*)(S + OFF2_CAT + fragByte(6, row, 128 + ch)));
    }
    float mx = fmaxf(fmaxf(vv[0], vv[1]), fmaxf(vv[2], vv[3]));
    float s = 0.f, ws = 0.f;
    #pragma unroll
    for (int k = 0; k < 4; ++k){
      float e = __expf(vv[k] - mx);
      s += e; ws = fmaf(e, gg[k], ws);
    }
    out[(size_t)bn*64 + ch] = __fdividef(ws, s);
  }
}

extern "C" void kernel_launch(void* const* d_in, const int* in_sizes, int n_in,
                              void* d_out, int out_size, void* d_ws, size_t ws_size,
                              hipStream_t stream) {
    const float* xyz1 = (const float*)d_in[0];
    const float* xyz2 = (const float*)d_in[1];
    const float* pts1 = (const float*)d_in[2];
    const float* pts2 = (const float*)d_in[3];
    const float* m1w0 = (const float*)d_in[4];
    const float* m1b0 = (const float*)d_in[5];
    const float* m1w1 = (const float*)d_in[6];
    const float* m1b1 = (const float*)d_in[7];
    const float* m1w2 = (const float*)d_in[8];
    const float* m1b2 = (const float*)d_in[9];
    const float* piw  = (const float*)d_in[10];
    const float* pib  = (const float*)d_in[11];
    const float* m2w0 = (const float*)d_in[12];
    const float* m2b0 = (const float*)d_in[13];
    const float* m2w1 = (const float*)d_in[14];
    const float* m2b1 = (const float*)d_in[15];
    const float* pcw  = (const float*)d_in[16];
    const float* pcb  = (const float*)d_in[17];
    const float* n0w  = (const float*)d_in[18];
    const float* n0b  = (const float*)d_in[19];
    const float* n1w  = (const float*)d_in[20];
    const float* n1b  = (const float*)d_in[21];

    const int B = in_sizes[0] / (NPIX * 3);
    u16*   wplanes = (u16*)d_ws;
    float* f1      = (float*)((char*)d_ws + F1_OFFSET);
    float* out     = (float*)d_out;

    hipLaunchKernelGGL(prep_weights, dim3(46), dim3(256), 0, stream,
                       m1w0, m1w1, m1w2, piw, m2w0, m2w1, pcw, n0w, n1w, wplanes);
    hipLaunchKernelGGL(stage1_mfma, dim3((B*NPIX)/8), dim3(256), 0, stream,
                       xyz1, xyz2, pts1, pts2,
                       m1b0, m1b1, m1b2, pib, m2b0, m2b1,
                       wplanes, f1);
    hipLaunchKernelGGL(stage2_mfma, dim3((B*NPIX)/8), dim3(256), 0, stream,
                       xyz1, pts1, f1, pcb, n0b, n1b,
                       wplanes, out);
}